// Round 5
// baseline (10053.232 us; speedup 1.0000x reference)
//
#include <hip/hip_runtime.h>

#define NB   32
#define C    64
#define T    512
#define V    25
#define KP   3
#define CO   64
#define H    4
#define DKD  16
#define DVD  16
#define BN_EPS 1e-5f
#define LN_EPS 1e-6f

// ---------------------------------------------------------------------------
// scn union-LDS layout (float offsets into s_u[7396] = 29584 B):
//   phase P1 : PW  [0    .. 4992)   pw[192][26]
//   phase P2 : QN  [4992 .. 6642)   qn[25][66]     (pw still live, disjoint)
//   phase P3 : Q   [0    .. 1625)   q[25][65]      (pw dead)
//              K   [1632 .. 3257)   k[25][65]
//              VV  [3264 .. 4889)   vv[25][65]
//   phase P4 : ATT [4896 .. 7396)   att[4][25][25] (qn dead)
//   phase P5 : XH  [0    .. 1650)   xh[25][66]     (q,k dead)
// Total LDS = s_inp 6656 + mu/rstd 200 + 29584 = ~36.4 KB.
// __launch_bounds__(256,3): 3 blocks/CU, VGPR cap ~168 — (256,4) forced
// VGPR=64 and spilled row[25]/qrow[16]/r_agg[7] to scratch (11.6 GB/dispatch
// of HBM traffic, R4 post-mortem). 3 waves/SIMD with no spill > 4 with spill.
// ---------------------------------------------------------------------------
#define OFF_PW  0
#define OFF_QN  4992
#define OFF_Q   0
#define OFF_K   1632
#define OFF_V   3264
#define OFF_ATT 4896
#define OFF_XH  0

__global__ __launch_bounds__(256, 3) void scn_kernel(
    const float* __restrict__ x, const float* __restrict__ A,
    const float* __restrict__ bn1_g, const float* __restrict__ bn1_b,
    const float* __restrict__ bn1_m, const float* __restrict__ bn1_v,
    const float* __restrict__ pconv_w, const float* __restrict__ pconv_b,
    const float* __restrict__ wq, const float* __restrict__ wk,
    const float* __restrict__ wv, const float* __restrict__ fc_w,
    const float* __restrict__ ln_g, const float* __restrict__ ln_b,
    const float* __restrict__ gate_w,
    const float* __restrict__ bn2_g, const float* __restrict__ bn2_b,
    const float* __restrict__ bn2_m, const float* __restrict__ bn2_v,
    float* __restrict__ f_out)
{
    const int nt  = blockIdx.x;
    const int n   = nt / T;
    const int t   = nt - n * T;
    const int tid = threadIdx.x;

    __shared__ float s_inp[C][26];          // bn1(x)[c][v], stride 26
    __shared__ float s_mu[V], s_rstd[V];
    __shared__ float s_u[7396];             // union region

    float r_agg[7];                         // agg[c][v] for i = tid + j*256

    // ---- P0: load x slice with bn1 applied ----
    for (int i = tid; i < C * V; i += 256) {
        int c = i / V, v = i - c * V;
        float s1 = bn1_g[c] * rsqrtf(bn1_v[c] + BN_EPS);
        float b1 = bn1_b[c] - bn1_m[c] * s1;
        s_inp[c][v] = x[((n * C + c) * T + t) * V + v] * s1 + b1;
    }
    __syncthreads();

    // ---- P1: pointwise partconv -> PW ; LN stats ----
    for (int i = tid; i < KP * CO * V; i += 256) {
        int o = i / V, v = i - o * V;
        float acc = pconv_b[o];
        const float* wrow = pconv_w + o * C;
        #pragma unroll 8
        for (int ci = 0; ci < C; ++ci) acc += wrow[ci] * s_inp[ci][v];
        s_u[OFF_PW + o * 26 + v] = acc;
    }
    if (tid < V) {
        float mu = 0.f;
        for (int c = 0; c < C; ++c) mu += s_inp[c][tid];
        mu *= (1.f / C);
        float var = 0.f;
        for (int c = 0; c < C; ++c) { float d = s_inp[c][tid] - mu; var += d * d; }
        var *= (1.f / C);
        s_mu[tid]   = mu;
        s_rstd[tid] = rsqrtf(var + LN_EPS);
    }
    __syncthreads();

    // ---- P2: qn = LN(fa) -> QN ; graph aggregation -> r_agg ----
    for (int i = tid; i < V * C; i += 256) {
        int v = i / C, c = i - v * C;
        s_u[OFF_QN + v * 66 + c] =
            (s_inp[c][v] - s_mu[v]) * s_rstd[v] * ln_g[c] + ln_b[c];
    }
    #pragma unroll
    for (int j = 0; j < 7; ++j) {
        int i = tid + j * 256;
        if (i < CO * V) {
            int c = i / V, w = i - c * V;
            float acc = 0.f;
            for (int k = 0; k < KP; ++k) {
                const float* pwr = &s_u[OFF_PW + (k * CO + c) * 26];
                const float* Ak  = A + k * V * V;
                #pragma unroll
                for (int v = 0; v < V; ++v) acc += pwr[v] * Ak[v * V + w];
            }
            r_agg[j] = acc;
        }
    }
    __syncthreads();

    // ---- P3: projections q = qn@wq, k = fa@wk, vv = fa@wv ----
    for (int i = tid; i < 3 * V * C; i += 256) {
        int which = i / (V * C);
        int rem   = i - which * (V * C);
        int v = rem / C, j = rem - v * C;
        float acc = 0.f;
        if (which == 0) {
            #pragma unroll 8
            for (int c = 0; c < C; ++c) acc += s_u[OFF_QN + v * 66 + c] * wq[c * C + j];
            s_u[OFF_Q + v * 65 + j] = acc;
        } else if (which == 1) {
            #pragma unroll 8
            for (int c = 0; c < C; ++c) acc += s_inp[c][v] * wk[c * C + j];
            s_u[OFF_K + v * 65 + j] = acc;
        } else {
            #pragma unroll 8
            for (int c = 0; c < C; ++c) acc += s_inp[c][v] * wv[c * C + j];
            s_u[OFF_V + v * 65 + j] = acc;
        }
    }
    __syncthreads();

    // ---- P4: attention scores + softmax -> ATT ----
    if (tid < H * V) {
        int h = tid / V, qv = tid - h * V;
        float qrow[DKD];
        #pragma unroll
        for (int d = 0; d < DKD; ++d) qrow[d] = s_u[OFF_Q + qv * 65 + h * DKD + d];
        float row[V];
        float mx = -1e30f;
        #pragma unroll
        for (int kv = 0; kv < V; ++kv) {
            float s = 0.f;
            #pragma unroll
            for (int d = 0; d < DKD; ++d)
                s += qrow[d] * s_u[OFF_K + kv * 65 + h * DKD + d];
            s *= 0.25f;                      // 1/sqrt(DK)
            row[kv] = s;
            mx = fmaxf(mx, s);
        }
        float sum = 0.f;
        #pragma unroll
        for (int kv = 0; kv < V; ++kv) { float e = __expf(row[kv] - mx); row[kv] = e; sum += e; }
        float inv = 1.f / sum;
        #pragma unroll
        for (int kv = 0; kv < V; ++kv)
            s_u[OFF_ATT + (h * V + qv) * V + kv] = row[kv] * inv;
    }
    __syncthreads();

    // ---- P5: xh = att @ vv -> XH ----
    for (int i = tid; i < V * C; i += 256) {
        int qv = i / C, j = i - qv * C;
        int h = j / DVD;
        float acc = 0.f;
        #pragma unroll
        for (int kv = 0; kv < V; ++kv)
            acc += s_u[OFF_ATT + (h * V + qv) * V + kv] * s_u[OFF_V + kv * 65 + j];
        s_u[OFF_XH + qv * 66 + j] = acc;
    }
    __syncthreads();

    // ---- P6: fc + residual ; gated fuse with r_agg ; bn2 ; relu ; store ----
    const float gate = gate_w[0];
    #pragma unroll
    for (int j = 0; j < 7; ++j) {
        int i = tid + j * 256;
        if (i < C * V) {
            int c = i / V, v = i - c * V;
            float acc = 0.f;
            #pragma unroll 8
            for (int d = 0; d < H * DVD; ++d)
                acc += s_u[OFF_XH + v * 66 + d] * fc_w[d * CO + c];
            float fa_out = acc + s_inp[c][v];              // residual (fa)
            float fv = (fa_out * gate + r_agg[j]) * 0.5f;
            float s2 = bn2_g[c] * rsqrtf(bn2_v[c] + BN_EPS);
            float b2 = bn2_b[c] - bn2_m[c] * s2;
            fv = fv * s2 + b2;
            f_out[((n * C + c) * T + t) * V + v] = fmaxf(fv, 0.f);
        }
    }
}

// ---------------------------------------------------------------------------
// Kernel 2: temporal conv (9,1) pad 4 + bias + bn3 + residual relu
// TB=4 time-steps per block; channel-split (2 passes of 32 ci) keeps LDS at
// 39.9 KB. Validated in R4: ~750 µs (was 2775). Unchanged.
// ---------------------------------------------------------------------------
#define TBT 4
#define CIH 32

__global__ __launch_bounds__(256, 4) void tcn_kernel(
    const float* __restrict__ f, const float* __restrict__ x,
    const float* __restrict__ tconv_w, const float* __restrict__ tconv_b,
    const float* __restrict__ bn3_g, const float* __restrict__ bn3_b,
    const float* __restrict__ bn3_m, const float* __restrict__ bn3_v,
    float* __restrict__ out)
{
    const int bid  = blockIdx.x;
    const int n    = bid / (T / TBT);
    const int t0   = (bid - n * (T / TBT)) * TBT;
    const int tid  = threadIdx.x;

    __shared__ float s_f[CIH][TBT + 8][26];   // 39936 B

    float acc[7][TBT];
    #pragma unroll
    for (int j = 0; j < 7; ++j) {
        int p = tid + j * 256;
        if (p < CO * V) {
            float b = tconv_b[p / V];
            #pragma unroll
            for (int tb = 0; tb < TBT; ++tb) acc[j][tb] = b;
        }
    }

    for (int phase = 0; phase < 2; ++phase) {
        const int cb = phase * CIH;
        // stage f window [cb..cb+32) x [t0-4 .. t0+TBT+4) x V
        for (int i = tid; i < CIH * (TBT + 8) * V; i += 256) {
            int ci  = i / ((TBT + 8) * V);
            int rem = i - ci * ((TBT + 8) * V);
            int sl  = rem / V, v = rem - sl * V;
            int tt  = t0 + sl - 4;
            float val = 0.f;
            if (tt >= 0 && tt < T)
                val = f[((n * C + cb + ci) * T + tt) * V + v];
            s_f[ci][sl][v] = val;
        }
        __syncthreads();

        #pragma unroll
        for (int j = 0; j < 7; ++j) {
            int p = tid + j * 256;
            if (p < CO * V) {
                int co = p / V, v = p - co * V;
                for (int ci = 0; ci < CIH; ++ci) {
                    const float* wp = tconv_w + ((co * C) + cb + ci) * 9;
                    float w[9];
                    #pragma unroll
                    for (int d = 0; d < 9; ++d) w[d] = wp[d];
                    float fv[TBT + 8];
                    #pragma unroll
                    for (int sl = 0; sl < TBT + 8; ++sl) fv[sl] = s_f[ci][sl][v];
                    #pragma unroll
                    for (int tb = 0; tb < TBT; ++tb) {
                        float a = acc[j][tb];
                        #pragma unroll
                        for (int d = 0; d < 9; ++d) a += w[d] * fv[tb + d];
                        acc[j][tb] = a;
                    }
                }
            }
        }
        __syncthreads();
    }

    #pragma unroll
    for (int j = 0; j < 7; ++j) {
        int p = tid + j * 256;
        if (p < CO * V) {
            int co = p / V, v = p - co * V;
            float s3 = bn3_g[co] * rsqrtf(bn3_v[co] + BN_EPS);
            float b3 = bn3_b[co] - bn3_m[co] * s3;
            #pragma unroll
            for (int tb = 0; tb < TBT; ++tb) {
                int tt = t0 + tb;
                float y = acc[j][tb] * s3 + b3;
                y += x[((n * C + co) * T + tt) * V + v];
                out[((n * C + co) * T + tt) * V + v] = fmaxf(y, 0.f);
            }
        }
    }
}

extern "C" void kernel_launch(void* const* d_in, const int* in_sizes, int n_in,
                              void* d_out, int out_size, void* d_ws, size_t ws_size,
                              hipStream_t stream) {
    const float* x       = (const float*)d_in[0];
    const float* A       = (const float*)d_in[1];
    const float* bn1_g   = (const float*)d_in[2];
    const float* bn1_b   = (const float*)d_in[3];
    const float* bn1_m   = (const float*)d_in[4];
    const float* bn1_v   = (const float*)d_in[5];
    const float* pconv_w = (const float*)d_in[6];
    const float* pconv_b = (const float*)d_in[7];
    const float* wq      = (const float*)d_in[8];
    const float* wk      = (const float*)d_in[9];
    const float* wv      = (const float*)d_in[10];
    const float* fc_w    = (const float*)d_in[11];
    const float* ln_g    = (const float*)d_in[12];
    const float* ln_b    = (const float*)d_in[13];
    const float* gate_w  = (const float*)d_in[14];
    const float* bn2_g   = (const float*)d_in[15];
    const float* bn2_b   = (const float*)d_in[16];
    const float* bn2_m   = (const float*)d_in[17];
    const float* bn2_v   = (const float*)d_in[18];
    const float* tconv_w = (const float*)d_in[19];
    const float* tconv_b = (const float*)d_in[20];
    const float* bn3_g   = (const float*)d_in[21];
    const float* bn3_b   = (const float*)d_in[22];
    const float* bn3_m   = (const float*)d_in[23];
    const float* bn3_v   = (const float*)d_in[24];

    float* f_buf = (float*)d_ws;   // N*C*T*V floats = 104.9 MB
    float* outp  = (float*)d_out;

    scn_kernel<<<dim3(NB * T), dim3(256), 0, stream>>>(
        x, A, bn1_g, bn1_b, bn1_m, bn1_v, pconv_w, pconv_b, wq, wk, wv, fc_w,
        ln_g, ln_b, gate_w, bn2_g, bn2_b, bn2_m, bn2_v, f_buf);
    tcn_kernel<<<dim3(NB * (T / TBT)), dim3(256), 0, stream>>>(
        f_buf, x, tconv_w, tconv_b, bn3_g, bn3_b, bn3_m, bn3_v, outp);
}

// Round 6
// 2797.037 us; speedup vs baseline: 3.5942x; 3.5942x over previous
//
#include <hip/hip_runtime.h>

#define NB   32
#define C    64
#define T    512
#define V    25
#define KP   3
#define CO   64
#define H    4
#define DKD  16
#define DVD  16
#define BN_EPS 1e-5f
#define LN_EPS 1e-6f

// ---------------------------------------------------------------------------
// scn union-LDS layout (float offsets into s_u[7396] = 29584 B):
//   phase P1 : PW  [0    .. 4992)   pw[192][26]
//   phase P2 : QN  [4992 .. 6642)   qn[25][66]     (pw still live, disjoint)
//   phase P3 : Q   [0    .. 1625)   q[25][65]      (pw dead)
//              K   [1632 .. 3257)   k[25][65]
//              VV  [3264 .. 4889)   vv[25][65]
//   phase P4 : ATT [4896 .. 7396)   att[4][25][25] (qn dead)
//   phase P5 : XH  [0    .. 1650)   xh[25][66]     (q,k dead)
// Total LDS = s_inp 6656 + mu/rstd 200 + 29584 = ~36.4 KB -> 3-4 blocks/CU.
//
// NOTE on __launch_bounds__: plain (256), NO min-waves arg. R4 (256,4) and
// R5 (256,3) made the AMDGPU allocator chase 8/6 waves-per-EU (VGPR 64/84)
// and spill ~50-70 regs/thread -> 10-12 GB of scratch HBM traffic per
// dispatch, 2.4x SLOWER than the 83KB-LDS baseline. Occupancy is LDS-bound
// at 3 blocks/CU regardless; the hint only buys spills. (R5 post-mortem.)
// ---------------------------------------------------------------------------
#define OFF_PW  0
#define OFF_QN  4992
#define OFF_Q   0
#define OFF_K   1632
#define OFF_V   3264
#define OFF_ATT 4896
#define OFF_XH  0

__global__ __launch_bounds__(256) void scn_kernel(
    const float* __restrict__ x, const float* __restrict__ A,
    const float* __restrict__ bn1_g, const float* __restrict__ bn1_b,
    const float* __restrict__ bn1_m, const float* __restrict__ bn1_v,
    const float* __restrict__ pconv_w, const float* __restrict__ pconv_b,
    const float* __restrict__ wq, const float* __restrict__ wk,
    const float* __restrict__ wv, const float* __restrict__ fc_w,
    const float* __restrict__ ln_g, const float* __restrict__ ln_b,
    const float* __restrict__ gate_w,
    const float* __restrict__ bn2_g, const float* __restrict__ bn2_b,
    const float* __restrict__ bn2_m, const float* __restrict__ bn2_v,
    float* __restrict__ f_out)
{
    const int nt  = blockIdx.x;
    const int n   = nt / T;
    const int t   = nt - n * T;
    const int tid = threadIdx.x;

    __shared__ float s_inp[C][26];          // bn1(x)[c][v], stride 26
    __shared__ float s_mu[V], s_rstd[V];
    __shared__ float s_u[7396];             // union region

    float r_agg[7];                         // agg[c][v] for i = tid + j*256

    // ---- P0: load x slice with bn1 applied ----
    for (int i = tid; i < C * V; i += 256) {
        int c = i / V, v = i - c * V;
        float s1 = bn1_g[c] * rsqrtf(bn1_v[c] + BN_EPS);
        float b1 = bn1_b[c] - bn1_m[c] * s1;
        s_inp[c][v] = x[((n * C + c) * T + t) * V + v] * s1 + b1;
    }
    __syncthreads();

    // ---- P1: pointwise partconv -> PW ; LN stats ----
    for (int i = tid; i < KP * CO * V; i += 256) {
        int o = i / V, v = i - o * V;
        float acc = pconv_b[o];
        const float* wrow = pconv_w + o * C;
        #pragma unroll 8
        for (int ci = 0; ci < C; ++ci) acc += wrow[ci] * s_inp[ci][v];
        s_u[OFF_PW + o * 26 + v] = acc;
    }
    if (tid < V) {
        float mu = 0.f;
        for (int c = 0; c < C; ++c) mu += s_inp[c][tid];
        mu *= (1.f / C);
        float var = 0.f;
        for (int c = 0; c < C; ++c) { float d = s_inp[c][tid] - mu; var += d * d; }
        var *= (1.f / C);
        s_mu[tid]   = mu;
        s_rstd[tid] = rsqrtf(var + LN_EPS);
    }
    __syncthreads();

    // ---- P2: qn = LN(fa) -> QN ; graph aggregation -> r_agg ----
    for (int i = tid; i < V * C; i += 256) {
        int v = i / C, c = i - v * C;
        s_u[OFF_QN + v * 66 + c] =
            (s_inp[c][v] - s_mu[v]) * s_rstd[v] * ln_g[c] + ln_b[c];
    }
    #pragma unroll
    for (int j = 0; j < 7; ++j) {
        int i = tid + j * 256;
        if (i < CO * V) {
            int c = i / V, w = i - c * V;
            float acc = 0.f;
            for (int k = 0; k < KP; ++k) {
                const float* pwr = &s_u[OFF_PW + (k * CO + c) * 26];
                const float* Ak  = A + k * V * V;
                #pragma unroll
                for (int v = 0; v < V; ++v) acc += pwr[v] * Ak[v * V + w];
            }
            r_agg[j] = acc;
        }
    }
    __syncthreads();

    // ---- P3: projections q = qn@wq, k = fa@wk, vv = fa@wv ----
    for (int i = tid; i < 3 * V * C; i += 256) {
        int which = i / (V * C);
        int rem   = i - which * (V * C);
        int v = rem / C, j = rem - v * C;
        float acc = 0.f;
        if (which == 0) {
            #pragma unroll 8
            for (int c = 0; c < C; ++c) acc += s_u[OFF_QN + v * 66 + c] * wq[c * C + j];
            s_u[OFF_Q + v * 65 + j] = acc;
        } else if (which == 1) {
            #pragma unroll 8
            for (int c = 0; c < C; ++c) acc += s_inp[c][v] * wk[c * C + j];
            s_u[OFF_K + v * 65 + j] = acc;
        } else {
            #pragma unroll 8
            for (int c = 0; c < C; ++c) acc += s_inp[c][v] * wv[c * C + j];
            s_u[OFF_V + v * 65 + j] = acc;
        }
    }
    __syncthreads();

    // ---- P4: attention scores + softmax -> ATT ----
    if (tid < H * V) {
        int h = tid / V, qv = tid - h * V;
        float qrow[DKD];
        #pragma unroll
        for (int d = 0; d < DKD; ++d) qrow[d] = s_u[OFF_Q + qv * 65 + h * DKD + d];
        float row[V];
        float mx = -1e30f;
        #pragma unroll
        for (int kv = 0; kv < V; ++kv) {
            float s = 0.f;
            #pragma unroll
            for (int d = 0; d < DKD; ++d)
                s += qrow[d] * s_u[OFF_K + kv * 65 + h * DKD + d];
            s *= 0.25f;                      // 1/sqrt(DK)
            row[kv] = s;
            mx = fmaxf(mx, s);
        }
        float sum = 0.f;
        #pragma unroll
        for (int kv = 0; kv < V; ++kv) { float e = __expf(row[kv] - mx); row[kv] = e; sum += e; }
        float inv = 1.f / sum;
        #pragma unroll
        for (int kv = 0; kv < V; ++kv)
            s_u[OFF_ATT + (h * V + qv) * V + kv] = row[kv] * inv;
    }
    __syncthreads();

    // ---- P5: xh = att @ vv -> XH ----
    for (int i = tid; i < V * C; i += 256) {
        int qv = i / C, j = i - qv * C;
        int h = j / DVD;
        float acc = 0.f;
        #pragma unroll
        for (int kv = 0; kv < V; ++kv)
            acc += s_u[OFF_ATT + (h * V + qv) * V + kv] * s_u[OFF_V + kv * 65 + j];
        s_u[OFF_XH + qv * 66 + j] = acc;
    }
    __syncthreads();

    // ---- P6: fc + residual ; gated fuse with r_agg ; bn2 ; relu ; store ----
    const float gate = gate_w[0];
    #pragma unroll
    for (int j = 0; j < 7; ++j) {
        int i = tid + j * 256;
        if (i < C * V) {
            int c = i / V, v = i - c * V;
            float acc = 0.f;
            #pragma unroll 8
            for (int d = 0; d < H * DVD; ++d)
                acc += s_u[OFF_XH + v * 66 + d] * fc_w[d * CO + c];
            float fa_out = acc + s_inp[c][v];              // residual (fa)
            float fv = (fa_out * gate + r_agg[j]) * 0.5f;
            float s2 = bn2_g[c] * rsqrtf(bn2_v[c] + BN_EPS);
            float b2 = bn2_b[c] - bn2_m[c] * s2;
            fv = fv * s2 + b2;
            f_out[((n * C + c) * T + t) * V + v] = fmaxf(fv, 0.f);
        }
    }
}

// ---------------------------------------------------------------------------
// Kernel 2: temporal conv (9,1) pad 4 + bias + bn3 + residual relu
// TB=4 time-steps per block; channel-split (2 passes of 32 ci), 39.9 KB LDS.
// Plain __launch_bounds__(256) — same spill rationale as scn (R5 post-mortem).
// ---------------------------------------------------------------------------
#define TBT 4
#define CIH 32

__global__ __launch_bounds__(256) void tcn_kernel(
    const float* __restrict__ f, const float* __restrict__ x,
    const float* __restrict__ tconv_w, const float* __restrict__ tconv_b,
    const float* __restrict__ bn3_g, const float* __restrict__ bn3_b,
    const float* __restrict__ bn3_m, const float* __restrict__ bn3_v,
    float* __restrict__ out)
{
    const int bid  = blockIdx.x;
    const int n    = bid / (T / TBT);
    const int t0   = (bid - n * (T / TBT)) * TBT;
    const int tid  = threadIdx.x;

    __shared__ float s_f[CIH][TBT + 8][26];   // 39936 B

    float acc[7][TBT];
    #pragma unroll
    for (int j = 0; j < 7; ++j) {
        int p = tid + j * 256;
        if (p < CO * V) {
            float b = tconv_b[p / V];
            #pragma unroll
            for (int tb = 0; tb < TBT; ++tb) acc[j][tb] = b;
        }
    }

    for (int phase = 0; phase < 2; ++phase) {
        const int cb = phase * CIH;
        // stage f window [cb..cb+32) x [t0-4 .. t0+TBT+4) x V
        for (int i = tid; i < CIH * (TBT + 8) * V; i += 256) {
            int ci  = i / ((TBT + 8) * V);
            int rem = i - ci * ((TBT + 8) * V);
            int sl  = rem / V, v = rem - sl * V;
            int tt  = t0 + sl - 4;
            float val = 0.f;
            if (tt >= 0 && tt < T)
                val = f[((n * C + cb + ci) * T + tt) * V + v];
            s_f[ci][sl][v] = val;
        }
        __syncthreads();

        #pragma unroll
        for (int j = 0; j < 7; ++j) {
            int p = tid + j * 256;
            if (p < CO * V) {
                int co = p / V, v = p - co * V;
                for (int ci = 0; ci < CIH; ++ci) {
                    const float* wp = tconv_w + ((co * C) + cb + ci) * 9;
                    float w[9];
                    #pragma unroll
                    for (int d = 0; d < 9; ++d) w[d] = wp[d];
                    float fv[TBT + 8];
                    #pragma unroll
                    for (int sl = 0; sl < TBT + 8; ++sl) fv[sl] = s_f[ci][sl][v];
                    #pragma unroll
                    for (int tb = 0; tb < TBT; ++tb) {
                        float a = acc[j][tb];
                        #pragma unroll
                        for (int d = 0; d < 9; ++d) a += w[d] * fv[tb + d];
                        acc[j][tb] = a;
                    }
                }
            }
        }
        __syncthreads();
    }

    #pragma unroll
    for (int j = 0; j < 7; ++j) {
        int p = tid + j * 256;
        if (p < CO * V) {
            int co = p / V, v = p - co * V;
            float s3 = bn3_g[co] * rsqrtf(bn3_v[co] + BN_EPS);
            float b3 = bn3_b[co] - bn3_m[co] * s3;
            #pragma unroll
            for (int tb = 0; tb < TBT; ++tb) {
                int tt = t0 + tb;
                float y = acc[j][tb] * s3 + b3;
                y += x[((n * C + co) * T + tt) * V + v];
                out[((n * C + co) * T + tt) * V + v] = fmaxf(y, 0.f);
            }
        }
    }
}

extern "C" void kernel_launch(void* const* d_in, const int* in_sizes, int n_in,
                              void* d_out, int out_size, void* d_ws, size_t ws_size,
                              hipStream_t stream) {
    const float* x       = (const float*)d_in[0];
    const float* A       = (const float*)d_in[1];
    const float* bn1_g   = (const float*)d_in[2];
    const float* bn1_b   = (const float*)d_in[3];
    const float* bn1_m   = (const float*)d_in[4];
    const float* bn1_v   = (const float*)d_in[5];
    const float* pconv_w = (const float*)d_in[6];
    const float* pconv_b = (const float*)d_in[7];
    const float* wq      = (const float*)d_in[8];
    const float* wk      = (const float*)d_in[9];
    const float* wv      = (const float*)d_in[10];
    const float* fc_w    = (const float*)d_in[11];
    const float* ln_g    = (const float*)d_in[12];
    const float* ln_b    = (const float*)d_in[13];
    const float* gate_w  = (const float*)d_in[14];
    const float* bn2_g   = (const float*)d_in[15];
    const float* bn2_b   = (const float*)d_in[16];
    const float* bn2_m   = (const float*)d_in[17];
    const float* bn2_v   = (const float*)d_in[18];
    const float* tconv_w = (const float*)d_in[19];
    const float* tconv_b = (const float*)d_in[20];
    const float* bn3_g   = (const float*)d_in[21];
    const float* bn3_b   = (const float*)d_in[22];
    const float* bn3_m   = (const float*)d_in[23];
    const float* bn3_v   = (const float*)d_in[24];

    float* f_buf = (float*)d_ws;   // N*C*T*V floats = 104.9 MB
    float* outp  = (float*)d_out;

    scn_kernel<<<dim3(NB * T), dim3(256), 0, stream>>>(
        x, A, bn1_g, bn1_b, bn1_m, bn1_v, pconv_w, pconv_b, wq, wk, wv, fc_w,
        ln_g, ln_b, gate_w, bn2_g, bn2_b, bn2_m, bn2_v, f_buf);
    tcn_kernel<<<dim3(NB * (T / TBT)), dim3(256), 0, stream>>>(
        f_buf, x, tconv_w, tconv_b, bn3_g, bn3_b, bn3_m, bn3_v, outp);
}

// Round 8
// 1137.304 us; speedup vs baseline: 8.8395x; 2.4594x over previous
//
#include <hip/hip_runtime.h>

#define NB   32
#define C    64
#define T    512
#define V    25
#define KP   3
#define CO   64
#define H    4
#define DKD  16
#define BN_EPS 1e-5f
#define LN_EPS 1e-6f

typedef float f32x4 __attribute__((ext_vector_type(4)));
typedef short bf16x8 __attribute__((ext_vector_type(8)));
typedef unsigned short u16;
#define MFMA(a,b,c) __builtin_amdgcn_mfma_f32_16x16x32_bf16((a),(b),(c),0,0,0)

__device__ __forceinline__ u16 f2bf(float x) {
    union { float f; unsigned u; } v; v.f = x;
    unsigned r = (v.u + 0x7FFFu + ((v.u >> 16) & 1u)) >> 16;
    return (u16)r;
}
__device__ __forceinline__ float bf2f(u16 h) {
    union { unsigned u; float f; } v; v.u = ((unsigned)h) << 16;
    return v.f;
}

// ---------------------------------------------------------------------------
// ws layout (bytes):
//   [0, 52428800)            f intermediate, bf16 (N*C*T*V)
//   WOFF = 52428800:
//     AKT  +0      bf16 [3][32][40]   AkT[k][w][v] = A[k][v][w] (zero-pad)
//     WP2  +7680   bf16 [64][192]     Wp2[c][k*64+ci] = pconv_w[k*64+c][ci]
//     WQT  +32256  bf16 [64][64]      WqT[j][c] = wq[c][j]
//     WKT  +40448, WVT +48640         same for wk, wv
//     FCT  +56832  bf16 [64][64]      FcT[c][d] = fc_w[d][c]
//     BAGG +65024  f32  [64][25]      bias fed through A-aggregation
// ---------------------------------------------------------------------------
#define WOFF 52428800ull

__global__ __launch_bounds__(256) void prep_kernel(
    const float* __restrict__ A, const float* __restrict__ pconv_w,
    const float* __restrict__ pconv_b,
    const float* __restrict__ wq, const float* __restrict__ wk,
    const float* __restrict__ wv, const float* __restrict__ fc_w,
    u16* __restrict__ akt, u16* __restrict__ wp2,
    u16* __restrict__ wqt, u16* __restrict__ wkt, u16* __restrict__ wvt,
    u16* __restrict__ fct, float* __restrict__ bagg)
{
    const int stride = gridDim.x * 256;
    for (int i = blockIdx.x * 256 + threadIdx.x; i < 34112; i += stride) {
        if (i < 3840) {                       // AkT
            int k = i / 1280, r = i - k * 1280, w = r / 40, v = r - w * 40;
            float val = (w < V && v < V) ? A[k * V * V + v * V + w] : 0.f;
            akt[i] = f2bf(val);
        } else if (i < 16128) {               // Wp2
            int i2 = i - 3840;
            int c = i2 / 192, kk = i2 - c * 192, k = kk / 64, ci = kk - k * 64;
            wp2[i2] = f2bf(pconv_w[(k * 64 + c) * 64 + ci]);
        } else if (i < 20224) {               // WqT
            int i2 = i - 16128; int j = i2 / 64, c = i2 - j * 64;
            wqt[i2] = f2bf(wq[c * 64 + j]);
        } else if (i < 24320) {               // WkT
            int i2 = i - 20224; int j = i2 / 64, c = i2 - j * 64;
            wkt[i2] = f2bf(wk[c * 64 + j]);
        } else if (i < 28416) {               // WvT
            int i2 = i - 24320; int j = i2 / 64, c = i2 - j * 64;
            wvt[i2] = f2bf(wv[c * 64 + j]);
        } else if (i < 32512) {               // FcT
            int i2 = i - 28416; int c = i2 / 64, d = i2 - c * 64;
            fct[i2] = f2bf(fc_w[d * 64 + c]);
        } else {                              // bias_agg
            int i2 = i - 32512; int c = i2 / 25, w = i2 - c * 25;
            float s = 0.f;
            for (int k = 0; k < KP; ++k) {
                float cs = 0.f;
                for (int v = 0; v < V; ++v) cs += A[k * V * V + v * V + w];
                s += pconv_b[k * 64 + c] * cs;
            }
            bagg[i2] = s;
        }
    }
}

// ---------------------------------------------------------------------------
// scn: per-(n,t) block. MFMA 16x16x32 bf16 for all GEMM phases:
//   y[k,ci,w] = inp @ A_k              (A-op: s_inpV LDS, B-op: AkT global)
//   agg[c,w]  = Wp2 @ y  (+bias_agg)   (K=192)
//   k,v       = WkT/WvT @ inpT ; q = WqT @ qnT
//   fc        = FcT @ xhT  -> fused epilogue -> f (bf16)
// VALU fp32: bn1 load, LN stats, attention softmax, att@vv.
// Frag layouts (HW-verified guide): A row=lane&15,k=(lane>>4)*8+j;
// B col=lane&15,same k; D col=lane&15,row=(lane>>4)*4+reg.
// LDS 50936 B -> 3 blocks/CU. Plain launch_bounds (R5: min-waves hint => spills).
// ---------------------------------------------------------------------------
#define OFF_INP   0        // f32 [64][25]
#define OFF_INPV  6400     // bf16 [64][40]  (later XHT bf16 [32][72])
#define OFF_XHT   6400
#define OFF_INPT  11520    // bf16 [32][72]  (later ATT bf16 [4][25][26])
#define OFF_ATT   11520
#define OFF_QNT   16128    // bf16 [32][72]
#define OFF_YT    20736    // bf16 [32][200]
#define OFF_AGG   33536    // f32 [64][25]
#define OFF_Q     39936    // bf16 [25][72]
#define OFF_K     43536
#define OFF_VV    47136
#define OFF_MU    50736    // f32 [25]
#define OFF_RSTD  50836    // f32 [25]
#define LDS_BYTES 50936

#define LDSF(off) ((float*)(s_raw + (off)))
#define LDSH(off) ((u16*)(s_raw + (off)))
#define LDSV8(b)  (*(const bf16x8*)(s_raw + (b)))

__global__ __launch_bounds__(256) void scn_kernel(
    const float* __restrict__ x,
    const float* __restrict__ bn1_g, const float* __restrict__ bn1_b,
    const float* __restrict__ bn1_m, const float* __restrict__ bn1_v,
    const u16* __restrict__ akt, const u16* __restrict__ wp2,
    const u16* __restrict__ wqt, const u16* __restrict__ wkt,
    const u16* __restrict__ wvt, const u16* __restrict__ fct,
    const float* __restrict__ bagg,
    const float* __restrict__ ln_g, const float* __restrict__ ln_b,
    const float* __restrict__ gate_w,
    const float* __restrict__ bn2_g, const float* __restrict__ bn2_b,
    const float* __restrict__ bn2_m, const float* __restrict__ bn2_v,
    u16* __restrict__ f_out)
{
    const int nt   = blockIdx.x;
    const int n    = nt >> 9;          // /T
    const int t    = nt & 511;
    const int tid  = threadIdx.x;
    const int lane = tid & 63;
    const int wid  = tid >> 6;
    const int r0   = lane & 15;
    const int g    = lane >> 4;

    __shared__ __align__(16) unsigned char s_raw[LDS_BYTES];

    const float gate = gate_w[0];

    // ---- P0: bn1(x) -> s_inp f32, s_inpV bf16 [c][v], s_inpT bf16 [v][c] ----
    #pragma unroll
    for (int it = 0; it < 7; ++it) {
        int i = tid + it * 256;
        if (i < 1600) {
            int c = i / 25, v = i - c * 25;
            float s1 = bn1_g[c] * rsqrtf(bn1_v[c] + BN_EPS);
            float b1 = bn1_b[c] - bn1_m[c] * s1;
            float f = x[((n * 64 + c) * 512 + t) * 25 + v] * s1 + b1;
            LDSF(OFF_INP)[c * 25 + v] = f;
            u16 hb = f2bf(f);
            LDSH(OFF_INPV)[c * 40 + v] = hb;
            LDSH(OFF_INPT)[v * 72 + c] = hb;
        }
    }
    for (int i = tid; i < 960; i += 256) {   // zero K-pad cols of inpV
        int c = i / 15, vz = 25 + (i - c * 15);
        LDSH(OFF_INPV)[c * 40 + vz] = 0;
    }
    __syncthreads();

    // ---- Phase A: LN stats (wave0 lanes<25) + y-GEMM + k,v projections ----
    if (tid < 25) {
        float mu = 0.f;
        for (int c = 0; c < 64; ++c) mu += LDSF(OFF_INP)[c * 25 + tid];
        mu *= (1.f / 64.f);
        float var = 0.f;
        for (int c = 0; c < 64; ++c) {
            float d = LDSF(OFF_INP)[c * 25 + tid] - mu; var += d * d;
        }
        LDSF(OFF_MU)[tid]   = mu;
        LDSF(OFF_RSTD)[tid] = rsqrtf(var * (1.f / 64.f) + LN_EPS);
    }
    // y-GEMM: 24 tiles (k,mt,nt), 6 per wave, K=32 (1 mfma each)
    #pragma unroll
    for (int ii = 0; ii < 6; ++ii) {
        int idx = wid * 6 + ii;
        int k = idx >> 3, rem = idx & 7, mt = rem >> 1, ntt = rem & 1;
        bf16x8 a = LDSV8(OFF_INPV + ((mt * 16 + r0) * 40 + g * 8) * 2);
        bf16x8 b = *(const bf16x8*)(&akt[(k * 32 + ntt * 16 + r0) * 40 + g * 8]);
        f32x4 acc = {0.f, 0.f, 0.f, 0.f};
        acc = MFMA(a, b, acc);
        int w = ntt * 16 + r0, cb = mt * 16 + g * 4;
        #pragma unroll
        for (int r = 0; r < 4; ++r)
            LDSH(OFF_YT)[w * 200 + k * 64 + cb + r] = f2bf(acc[r]);
    }
    // k,v projections: M=64(j) N=32(v) K=64
    #pragma unroll
    for (int pr = 0; pr < 2; ++pr) {
        const u16* W = pr ? wvt : wkt;
        const int offD = pr ? OFF_VV : OFF_K;
        #pragma unroll
        for (int ii = 0; ii < 2; ++ii) {
            int idx = wid * 2 + ii, mt = idx >> 1, ntt = idx & 1;
            f32x4 acc = {0.f, 0.f, 0.f, 0.f};
            #pragma unroll
            for (int ks = 0; ks < 2; ++ks) {
                bf16x8 a = *(const bf16x8*)(&W[(mt * 16 + r0) * 64 + ks * 32 + g * 8]);
                bf16x8 b = LDSV8(OFF_INPT + ((ntt * 16 + r0) * 72 + ks * 32 + g * 8) * 2);
                acc = MFMA(a, b, acc);
            }
            int v = ntt * 16 + r0;
            if (v < 25) {
                int jb = mt * 16 + g * 4;
                #pragma unroll
                for (int r = 0; r < 4; ++r)
                    LDSH(offD)[v * 72 + jb + r] = f2bf(acc[r]);
            }
        }
    }
    __syncthreads();

    // ---- Phase B: qn = LN(inp) -> s_qnT bf16 [v][c] ----
    #pragma unroll
    for (int it = 0; it < 7; ++it) {
        int i = tid + it * 256;
        if (i < 1600) {
            int v = i >> 6, c = i & 63;
            float f = LDSF(OFF_INP)[c * 25 + v];
            float q = (f - LDSF(OFF_MU)[v]) * LDSF(OFF_RSTD)[v] * ln_g[c] + ln_b[c];
            LDSH(OFF_QNT)[v * 72 + c] = f2bf(q);
        }
    }
    __syncthreads();

    // ---- Phase C: agg-GEMM (K=192) + q projection ----
    #pragma unroll
    for (int ii = 0; ii < 2; ++ii) {
        int idx = wid * 2 + ii, mt = idx >> 1, ntt = idx & 1;
        f32x4 acc = {0.f, 0.f, 0.f, 0.f};
        #pragma unroll
        for (int ks = 0; ks < 6; ++ks) {
            bf16x8 a = *(const bf16x8*)(&wp2[(mt * 16 + r0) * 192 + ks * 32 + g * 8]);
            bf16x8 b = LDSV8(OFF_YT + ((ntt * 16 + r0) * 200 + ks * 32 + g * 8) * 2);
            acc = MFMA(a, b, acc);
        }
        int w = ntt * 16 + r0;
        if (w < 25) {
            int cb = mt * 16 + g * 4;
            #pragma unroll
            for (int r = 0; r < 4; ++r) {
                int c = cb + r;
                LDSF(OFF_AGG)[c * 25 + w] = acc[r] + bagg[c * 25 + w];
            }
        }
    }
    #pragma unroll
    for (int ii = 0; ii < 2; ++ii) {
        int idx = wid * 2 + ii, mt = idx >> 1, ntt = idx & 1;
        f32x4 acc = {0.f, 0.f, 0.f, 0.f};
        #pragma unroll
        for (int ks = 0; ks < 2; ++ks) {
            bf16x8 a = *(const bf16x8*)(&wqt[(mt * 16 + r0) * 64 + ks * 32 + g * 8]);
            bf16x8 b = LDSV8(OFF_QNT + ((ntt * 16 + r0) * 72 + ks * 32 + g * 8) * 2);
            acc = MFMA(a, b, acc);
        }
        int v = ntt * 16 + r0;
        if (v < 25) {
            int jb = mt * 16 + g * 4;
            #pragma unroll
            for (int r = 0; r < 4; ++r)
                LDSH(OFF_Q)[v * 72 + jb + r] = f2bf(acc[r]);
        }
    }
    __syncthreads();

    // ---- Phase D: attention scores + softmax (VALU, 100 threads) ----
    if (tid < 100) {
        int h = tid / 25, qv = tid - h * 25;
        float qf[16];
        {
            bf16x8 qa = LDSV8(OFF_Q + (qv * 72 + h * 16) * 2);
            bf16x8 qb = LDSV8(OFF_Q + (qv * 72 + h * 16) * 2 + 16);
            #pragma unroll
            for (int j = 0; j < 8; ++j) {
                qf[j]     = bf2f((u16)qa[j]);
                qf[8 + j] = bf2f((u16)qb[j]);
            }
        }
        float row[25]; float mx = -1e30f;
        for (int kv = 0; kv < 25; ++kv) {
            bf16x8 ka = LDSV8(OFF_K + (kv * 72 + h * 16) * 2);
            bf16x8 kb = LDSV8(OFF_K + (kv * 72 + h * 16) * 2 + 16);
            float s = 0.f;
            #pragma unroll
            for (int j = 0; j < 8; ++j)
                s += qf[j] * bf2f((u16)ka[j]) + qf[8 + j] * bf2f((u16)kb[j]);
            s *= 0.25f;
            row[kv] = s; mx = fmaxf(mx, s);
        }
        float sum = 0.f;
        for (int kv = 0; kv < 25; ++kv) { float e = __expf(row[kv] - mx); row[kv] = e; sum += e; }
        float inv = 1.f / sum;
        for (int kv = 0; kv < 25; ++kv)
            LDSH(OFF_ATT)[(h * 25 + qv) * 26 + kv] = f2bf(row[kv] * inv);
    }
    __syncthreads();

    // ---- Phase E: xh = att @ vv -> s_xhT bf16 [v][d] ----
    #pragma unroll
    for (int it = 0; it < 7; ++it) {
        int i = tid + it * 256;
        if (i < 1600) {
            int v = i >> 6, j = i & 63, h = j >> 4;
            const u16* attp = LDSH(OFF_ATT) + (h * 25 + v) * 26;
            const u16* vp   = LDSH(OFF_VV) + j;
            float acc = 0.f;
            #pragma unroll
            for (int kv = 0; kv < 25; ++kv)
                acc += bf2f(attp[kv]) * bf2f(vp[kv * 72]);
            LDSH(OFF_XHT)[v * 72 + j] = f2bf(acc);
        }
    }
    __syncthreads();

    // ---- Phase F: fc-GEMM + fused epilogue -> f bf16 ----
    #pragma unroll
    for (int ii = 0; ii < 2; ++ii) {
        int idx = wid * 2 + ii, mt = idx >> 1, ntt = idx & 1;
        f32x4 acc = {0.f, 0.f, 0.f, 0.f};
        #pragma unroll
        for (int ks = 0; ks < 2; ++ks) {
            bf16x8 a = *(const bf16x8*)(&fct[(mt * 16 + r0) * 64 + ks * 32 + g * 8]);
            bf16x8 b = LDSV8(OFF_XHT + ((ntt * 16 + r0) * 72 + ks * 32 + g * 8) * 2);
            acc = MFMA(a, b, acc);
        }
        int v = ntt * 16 + r0;
        if (v < 25) {
            int cb = mt * 16 + g * 4;
            #pragma unroll
            for (int r = 0; r < 4; ++r) {
                int c = cb + r;
                float fa_out = acc[r] + LDSF(OFF_INP)[c * 25 + v];
                float fv = (fa_out * gate + LDSF(OFF_AGG)[c * 25 + v]) * 0.5f;
                float s2 = bn2_g[c] * rsqrtf(bn2_v[c] + BN_EPS);
                float b2 = bn2_b[c] - bn2_m[c] * s2;
                fv = fmaxf(fv * s2 + b2, 0.f);
                f_out[((n * 64 + c) * 512 + t) * 25 + v] = f2bf(fv);
            }
        }
    }
}

// ---------------------------------------------------------------------------
// tcn: unchanged structure (R6-validated ~470us); f input now bf16.
// ---------------------------------------------------------------------------
#define TBT 4
#define CIH 32

__global__ __launch_bounds__(256) void tcn_kernel(
    const u16* __restrict__ f, const float* __restrict__ x,
    const float* __restrict__ tconv_w, const float* __restrict__ tconv_b,
    const float* __restrict__ bn3_g, const float* __restrict__ bn3_b,
    const float* __restrict__ bn3_m, const float* __restrict__ bn3_v,
    float* __restrict__ out)
{
    const int bid  = blockIdx.x;
    const int n    = bid / (T / TBT);
    const int t0   = (bid - n * (T / TBT)) * TBT;
    const int tid  = threadIdx.x;

    __shared__ float s_f[CIH][TBT + 8][26];   // 39936 B

    float acc[7][TBT];
    #pragma unroll
    for (int j = 0; j < 7; ++j) {
        int p = tid + j * 256;
        if (p < CO * V) {
            float b = tconv_b[p / V];
            #pragma unroll
            for (int tb = 0; tb < TBT; ++tb) acc[j][tb] = b;
        }
    }

    for (int phase = 0; phase < 2; ++phase) {
        const int cb = phase * CIH;
        for (int i = tid; i < CIH * (TBT + 8) * V; i += 256) {
            int ci  = i / ((TBT + 8) * V);
            int rem = i - ci * ((TBT + 8) * V);
            int sl  = rem / V, v = rem - sl * V;
            int tt  = t0 + sl - 4;
            float val = 0.f;
            if (tt >= 0 && tt < T)
                val = bf2f(f[((n * C + cb + ci) * T + tt) * V + v]);
            s_f[ci][sl][v] = val;
        }
        __syncthreads();

        #pragma unroll
        for (int j = 0; j < 7; ++j) {
            int p = tid + j * 256;
            if (p < CO * V) {
                int co = p / V, v = p - co * V;
                for (int ci = 0; ci < CIH; ++ci) {
                    const float* wp = tconv_w + ((co * C) + cb + ci) * 9;
                    float w[9];
                    #pragma unroll
                    for (int d = 0; d < 9; ++d) w[d] = wp[d];
                    float fv[TBT + 8];
                    #pragma unroll
                    for (int sl = 0; sl < TBT + 8; ++sl) fv[sl] = s_f[ci][sl][v];
                    #pragma unroll
                    for (int tb = 0; tb < TBT; ++tb) {
                        float a = acc[j][tb];
                        #pragma unroll
                        for (int d = 0; d < 9; ++d) a += w[d] * fv[tb + d];
                        acc[j][tb] = a;
                    }
                }
            }
        }
        __syncthreads();
    }

    #pragma unroll
    for (int j = 0; j < 7; ++j) {
        int p = tid + j * 256;
        if (p < CO * V) {
            int co = p / V, v = p - co * V;
            float s3 = bn3_g[co] * rsqrtf(bn3_v[co] + BN_EPS);
            float b3 = bn3_b[co] - bn3_m[co] * s3;
            #pragma unroll
            for (int tb = 0; tb < TBT; ++tb) {
                int tt = t0 + tb;
                float y = acc[j][tb] * s3 + b3;
                y += x[((n * C + co) * T + tt) * V + v];
                out[((n * C + co) * T + tt) * V + v] = fmaxf(y, 0.f);
            }
        }
    }
}

extern "C" void kernel_launch(void* const* d_in, const int* in_sizes, int n_in,
                              void* d_out, int out_size, void* d_ws, size_t ws_size,
                              hipStream_t stream) {
    const float* x       = (const float*)d_in[0];
    const float* A       = (const float*)d_in[1];
    const float* bn1_g   = (const float*)d_in[2];
    const float* bn1_b   = (const float*)d_in[3];
    const float* bn1_m   = (const float*)d_in[4];
    const float* bn1_v   = (const float*)d_in[5];
    const float* pconv_w = (const float*)d_in[6];
    const float* pconv_b = (const float*)d_in[7];
    const float* wq      = (const float*)d_in[8];
    const float* wk      = (const float*)d_in[9];
    const float* wv      = (const float*)d_in[10];
    const float* fc_w    = (const float*)d_in[11];
    const float* ln_g    = (const float*)d_in[12];
    const float* ln_b    = (const float*)d_in[13];
    const float* gate_w  = (const float*)d_in[14];
    const float* bn2_g   = (const float*)d_in[15];
    const float* bn2_b   = (const float*)d_in[16];
    const float* bn2_m   = (const float*)d_in[17];
    const float* bn2_v   = (const float*)d_in[18];
    const float* tconv_w = (const float*)d_in[19];
    const float* tconv_b = (const float*)d_in[20];
    const float* bn3_g   = (const float*)d_in[21];
    const float* bn3_b   = (const float*)d_in[22];
    const float* bn3_m   = (const float*)d_in[23];
    const float* bn3_v   = (const float*)d_in[24];

    char* ws = (char*)d_ws;
    u16*   f_bf = (u16*)ws;
    u16*   akt  = (u16*)(ws + WOFF);
    u16*   wp2  = (u16*)(ws + WOFF + 7680);
    u16*   wqt  = (u16*)(ws + WOFF + 32256);
    u16*   wkt  = (u16*)(ws + WOFF + 40448);
    u16*   wvt  = (u16*)(ws + WOFF + 48640);
    u16*   fct  = (u16*)(ws + WOFF + 56832);
    float* bagg = (float*)(ws + WOFF + 65024);
    float* outp = (float*)d_out;

    prep_kernel<<<dim3(64), dim3(256), 0, stream>>>(
        A, pconv_w, pconv_b, wq, wk, wv, fc_w,
        akt, wp2, wqt, wkt, wvt, fct, bagg);
    scn_kernel<<<dim3(NB * T), dim3(256), 0, stream>>>(
        x, bn1_g, bn1_b, bn1_m, bn1_v, akt, wp2, wqt, wkt, wvt, fct, bagg,
        ln_g, ln_b, gate_w, bn2_g, bn2_b, bn2_m, bn2_v, f_bf);
    tcn_kernel<<<dim3(NB * (T / TBT)), dim3(256), 0, stream>>>(
        f_bf, x, tconv_w, tconv_b, bn3_g, bn3_b, bn3_m, bn3_v, outp);
}

// Round 9
// 687.046 us; speedup vs baseline: 14.6325x; 1.6554x over previous
//
#include <hip/hip_runtime.h>

#define NB   32
#define C    64
#define T    512
#define V    25
#define KP   3
#define CO   64
#define H    4
#define DKD  16
#define BN_EPS 1e-5f
#define LN_EPS 1e-6f

typedef float f32x4 __attribute__((ext_vector_type(4)));
typedef short bf16x8 __attribute__((ext_vector_type(8)));
typedef unsigned short u16;
#define MFMA(a,b,c) __builtin_amdgcn_mfma_f32_16x16x32_bf16((a),(b),(c),0,0,0)

__device__ __forceinline__ u16 f2bf(float x) {
    union { float f; unsigned u; } v; v.f = x;
    unsigned r = (v.u + 0x7FFFu + ((v.u >> 16) & 1u)) >> 16;
    return (u16)r;
}
__device__ __forceinline__ float bf2f(u16 h) {
    union { unsigned u; float f; } v; v.u = ((unsigned)h) << 16;
    return v.f;
}

// ---------------------------------------------------------------------------
// ws layout (bytes):
//   [0, 52428800)            f intermediate, bf16 (N*C*T*V)
//   WOFF = 52428800:
//     AKT  +0      bf16 [3][32][40]   AkT[k][w][v] = A[k][v][w] (zero-pad)
//     WP2  +7680   bf16 [64][192]     Wp2[c][k*64+ci] = pconv_w[k*64+c][ci]
//     WQT  +32256  bf16 [64][64]      WqT[j][c] = wq[c][j]
//     WKT  +40448, WVT +48640         same for wk, wv
//     FCT  +56832  bf16 [64][64]      FcT[c][d] = fc_w[d][c]
//     BAGG +65024  f32  [64][25]      bias fed through A-aggregation
//     WTC  +71424  bf16 [64][9][64]   Wtc[co][dt][ci] = tconv_w[co][ci][dt]
// ---------------------------------------------------------------------------
#define WOFF 52428800ull

__global__ __launch_bounds__(256) void prep_kernel(
    const float* __restrict__ A, const float* __restrict__ pconv_w,
    const float* __restrict__ pconv_b,
    const float* __restrict__ wq, const float* __restrict__ wk,
    const float* __restrict__ wv, const float* __restrict__ fc_w,
    const float* __restrict__ tconv_w,
    u16* __restrict__ akt, u16* __restrict__ wp2,
    u16* __restrict__ wqt, u16* __restrict__ wkt, u16* __restrict__ wvt,
    u16* __restrict__ fct, float* __restrict__ bagg, u16* __restrict__ wtc)
{
    const int stride = gridDim.x * 256;
    for (int i = blockIdx.x * 256 + threadIdx.x; i < 70976; i += stride) {
        if (i < 3840) {                       // AkT
            int k = i / 1280, r = i - k * 1280, w = r / 40, v = r - w * 40;
            float val = (w < V && v < V) ? A[k * V * V + v * V + w] : 0.f;
            akt[i] = f2bf(val);
        } else if (i < 16128) {               // Wp2
            int i2 = i - 3840;
            int c = i2 / 192, kk = i2 - c * 192, k = kk / 64, ci = kk - k * 64;
            wp2[i2] = f2bf(pconv_w[(k * 64 + c) * 64 + ci]);
        } else if (i < 20224) {               // WqT
            int i2 = i - 16128; int j = i2 / 64, c = i2 - j * 64;
            wqt[i2] = f2bf(wq[c * 64 + j]);
        } else if (i < 24320) {               // WkT
            int i2 = i - 20224; int j = i2 / 64, c = i2 - j * 64;
            wkt[i2] = f2bf(wk[c * 64 + j]);
        } else if (i < 28416) {               // WvT
            int i2 = i - 24320; int j = i2 / 64, c = i2 - j * 64;
            wvt[i2] = f2bf(wv[c * 64 + j]);
        } else if (i < 32512) {               // FcT
            int i2 = i - 28416; int c = i2 / 64, d = i2 - c * 64;
            fct[i2] = f2bf(fc_w[d * 64 + c]);
        } else if (i < 34112) {               // bias_agg
            int i2 = i - 32512; int c = i2 / 25, w = i2 - c * 25;
            float s = 0.f;
            for (int k = 0; k < KP; ++k) {
                float cs = 0.f;
                for (int v = 0; v < V; ++v) cs += A[k * V * V + v * V + w];
                s += pconv_b[k * 64 + c] * cs;
            }
            bagg[i2] = s;
        } else {                              // Wtc (tcn weights, (dt,ci)-major)
            int i2 = i - 34112;
            int co = i2 / 576, rem = i2 - co * 576, dt = rem / 64, ci = rem - dt * 64;
            wtc[i2] = f2bf(tconv_w[(co * 64 + ci) * 9 + dt]);
        }
    }
}

// ---------------------------------------------------------------------------
// scn: per-(n,t) block, MFMA for all GEMM phases (R8-validated, ~260us).
// ---------------------------------------------------------------------------
#define OFF_INP   0        // f32 [64][25]
#define OFF_INPV  6400     // bf16 [64][40]  (later XHT bf16 [32][72])
#define OFF_XHT   6400
#define OFF_INPT  11520    // bf16 [32][72]  (later ATT bf16 [4][25][26])
#define OFF_ATT   11520
#define OFF_QNT   16128    // bf16 [32][72]
#define OFF_YT    20736    // bf16 [32][200]
#define OFF_AGG   33536    // f32 [64][25]
#define OFF_Q     39936    // bf16 [25][72]
#define OFF_K     43536
#define OFF_VV    47136
#define OFF_MU    50736    // f32 [25]
#define OFF_RSTD  50836    // f32 [25]
#define LDS_BYTES 50936

#define LDSF(off) ((float*)(s_raw + (off)))
#define LDSH(off) ((u16*)(s_raw + (off)))
#define LDSV8(b)  (*(const bf16x8*)(s_raw + (b)))

__global__ __launch_bounds__(256) void scn_kernel(
    const float* __restrict__ x,
    const float* __restrict__ bn1_g, const float* __restrict__ bn1_b,
    const float* __restrict__ bn1_m, const float* __restrict__ bn1_v,
    const u16* __restrict__ akt, const u16* __restrict__ wp2,
    const u16* __restrict__ wqt, const u16* __restrict__ wkt,
    const u16* __restrict__ wvt, const u16* __restrict__ fct,
    const float* __restrict__ bagg,
    const float* __restrict__ ln_g, const float* __restrict__ ln_b,
    const float* __restrict__ gate_w,
    const float* __restrict__ bn2_g, const float* __restrict__ bn2_b,
    const float* __restrict__ bn2_m, const float* __restrict__ bn2_v,
    u16* __restrict__ f_out)
{
    const int nt   = blockIdx.x;
    const int n    = nt >> 9;          // /T
    const int t    = nt & 511;
    const int tid  = threadIdx.x;
    const int lane = tid & 63;
    const int wid  = tid >> 6;
    const int r0   = lane & 15;
    const int g    = lane >> 4;

    __shared__ __align__(16) unsigned char s_raw[LDS_BYTES];

    const float gate = gate_w[0];

    // ---- P0: bn1(x) -> s_inp f32, s_inpV bf16 [c][v], s_inpT bf16 [v][c] ----
    #pragma unroll
    for (int it = 0; it < 7; ++it) {
        int i = tid + it * 256;
        if (i < 1600) {
            int c = i / 25, v = i - c * 25;
            float s1 = bn1_g[c] * rsqrtf(bn1_v[c] + BN_EPS);
            float b1 = bn1_b[c] - bn1_m[c] * s1;
            float f = x[((n * 64 + c) * 512 + t) * 25 + v] * s1 + b1;
            LDSF(OFF_INP)[c * 25 + v] = f;
            u16 hb = f2bf(f);
            LDSH(OFF_INPV)[c * 40 + v] = hb;
            LDSH(OFF_INPT)[v * 72 + c] = hb;
        }
    }
    for (int i = tid; i < 960; i += 256) {   // zero K-pad cols of inpV
        int c = i / 15, vz = 25 + (i - c * 15);
        LDSH(OFF_INPV)[c * 40 + vz] = 0;
    }
    __syncthreads();

    // ---- Phase A: LN stats (wave0 lanes<25) + y-GEMM + k,v projections ----
    if (tid < 25) {
        float mu = 0.f;
        for (int c = 0; c < 64; ++c) mu += LDSF(OFF_INP)[c * 25 + tid];
        mu *= (1.f / 64.f);
        float var = 0.f;
        for (int c = 0; c < 64; ++c) {
            float d = LDSF(OFF_INP)[c * 25 + tid] - mu; var += d * d;
        }
        LDSF(OFF_MU)[tid]   = mu;
        LDSF(OFF_RSTD)[tid] = rsqrtf(var * (1.f / 64.f) + LN_EPS);
    }
    // y-GEMM: 24 tiles (k,mt,nt), 6 per wave, K=32 (1 mfma each)
    #pragma unroll
    for (int ii = 0; ii < 6; ++ii) {
        int idx = wid * 6 + ii;
        int k = idx >> 3, rem = idx & 7, mt = rem >> 1, ntt = rem & 1;
        bf16x8 a = LDSV8(OFF_INPV + ((mt * 16 + r0) * 40 + g * 8) * 2);
        bf16x8 b = *(const bf16x8*)(&akt[(k * 32 + ntt * 16 + r0) * 40 + g * 8]);
        f32x4 acc = {0.f, 0.f, 0.f, 0.f};
        acc = MFMA(a, b, acc);
        int w = ntt * 16 + r0, cb = mt * 16 + g * 4;
        #pragma unroll
        for (int r = 0; r < 4; ++r)
            LDSH(OFF_YT)[w * 200 + k * 64 + cb + r] = f2bf(acc[r]);
    }
    // k,v projections: M=64(j) N=32(v) K=64
    #pragma unroll
    for (int pr = 0; pr < 2; ++pr) {
        const u16* W = pr ? wvt : wkt;
        const int offD = pr ? OFF_VV : OFF_K;
        #pragma unroll
        for (int ii = 0; ii < 2; ++ii) {
            int idx = wid * 2 + ii, mt = idx >> 1, ntt = idx & 1;
            f32x4 acc = {0.f, 0.f, 0.f, 0.f};
            #pragma unroll
            for (int ks = 0; ks < 2; ++ks) {
                bf16x8 a = *(const bf16x8*)(&W[(mt * 16 + r0) * 64 + ks * 32 + g * 8]);
                bf16x8 b = LDSV8(OFF_INPT + ((ntt * 16 + r0) * 72 + ks * 32 + g * 8) * 2);
                acc = MFMA(a, b, acc);
            }
            int v = ntt * 16 + r0;
            if (v < 25) {
                int jb = mt * 16 + g * 4;
                #pragma unroll
                for (int r = 0; r < 4; ++r)
                    LDSH(offD)[v * 72 + jb + r] = f2bf(acc[r]);
            }
        }
    }
    __syncthreads();

    // ---- Phase B: qn = LN(inp) -> s_qnT bf16 [v][c] ----
    #pragma unroll
    for (int it = 0; it < 7; ++it) {
        int i = tid + it * 256;
        if (i < 1600) {
            int v = i >> 6, c = i & 63;
            float f = LDSF(OFF_INP)[c * 25 + v];
            float q = (f - LDSF(OFF_MU)[v]) * LDSF(OFF_RSTD)[v] * ln_g[c] + ln_b[c];
            LDSH(OFF_QNT)[v * 72 + c] = f2bf(q);
        }
    }
    __syncthreads();

    // ---- Phase C: agg-GEMM (K=192) + q projection ----
    #pragma unroll
    for (int ii = 0; ii < 2; ++ii) {
        int idx = wid * 2 + ii, mt = idx >> 1, ntt = idx & 1;
        f32x4 acc = {0.f, 0.f, 0.f, 0.f};
        #pragma unroll
        for (int ks = 0; ks < 6; ++ks) {
            bf16x8 a = *(const bf16x8*)(&wp2[(mt * 16 + r0) * 192 + ks * 32 + g * 8]);
            bf16x8 b = LDSV8(OFF_YT + ((ntt * 16 + r0) * 200 + ks * 32 + g * 8) * 2);
            acc = MFMA(a, b, acc);
        }
        int w = ntt * 16 + r0;
        if (w < 25) {
            int cb = mt * 16 + g * 4;
            #pragma unroll
            for (int r = 0; r < 4; ++r) {
                int c = cb + r;
                LDSF(OFF_AGG)[c * 25 + w] = acc[r] + bagg[c * 25 + w];
            }
        }
    }
    #pragma unroll
    for (int ii = 0; ii < 2; ++ii) {
        int idx = wid * 2 + ii, mt = idx >> 1, ntt = idx & 1;
        f32x4 acc = {0.f, 0.f, 0.f, 0.f};
        #pragma unroll
        for (int ks = 0; ks < 2; ++ks) {
            bf16x8 a = *(const bf16x8*)(&wqt[(mt * 16 + r0) * 64 + ks * 32 + g * 8]);
            bf16x8 b = LDSV8(OFF_QNT + ((ntt * 16 + r0) * 72 + ks * 32 + g * 8) * 2);
            acc = MFMA(a, b, acc);
        }
        int v = ntt * 16 + r0;
        if (v < 25) {
            int jb = mt * 16 + g * 4;
            #pragma unroll
            for (int r = 0; r < 4; ++r)
                LDSH(OFF_Q)[v * 72 + jb + r] = f2bf(acc[r]);
        }
    }
    __syncthreads();

    // ---- Phase D: attention scores + softmax (VALU, 100 threads) ----
    if (tid < 100) {
        int h = tid / 25, qv = tid - h * 25;
        float qf[16];
        {
            bf16x8 qa = LDSV8(OFF_Q + (qv * 72 + h * 16) * 2);
            bf16x8 qb = LDSV8(OFF_Q + (qv * 72 + h * 16) * 2 + 16);
            #pragma unroll
            for (int j = 0; j < 8; ++j) {
                qf[j]     = bf2f((u16)qa[j]);
                qf[8 + j] = bf2f((u16)qb[j]);
            }
        }
        float row[25]; float mx = -1e30f;
        for (int kv = 0; kv < 25; ++kv) {
            bf16x8 ka = LDSV8(OFF_K + (kv * 72 + h * 16) * 2);
            bf16x8 kb = LDSV8(OFF_K + (kv * 72 + h * 16) * 2 + 16);
            float s = 0.f;
            #pragma unroll
            for (int j = 0; j < 8; ++j)
                s += qf[j] * bf2f((u16)ka[j]) + qf[8 + j] * bf2f((u16)kb[j]);
            s *= 0.25f;
            row[kv] = s; mx = fmaxf(mx, s);
        }
        float sum = 0.f;
        for (int kv = 0; kv < 25; ++kv) { float e = __expf(row[kv] - mx); row[kv] = e; sum += e; }
        float inv = 1.f / sum;
        for (int kv = 0; kv < 25; ++kv)
            LDSH(OFF_ATT)[(h * 25 + qv) * 26 + kv] = f2bf(row[kv] * inv);
    }
    __syncthreads();

    // ---- Phase E: xh = att @ vv -> s_xhT bf16 [v][d] ----
    #pragma unroll
    for (int it = 0; it < 7; ++it) {
        int i = tid + it * 256;
        if (i < 1600) {
            int v = i >> 6, j = i & 63, h = j >> 4;
            const u16* attp = LDSH(OFF_ATT) + (h * 25 + v) * 26;
            const u16* vp   = LDSH(OFF_VV) + j;
            float acc = 0.f;
            #pragma unroll
            for (int kv = 0; kv < 25; ++kv)
                acc += bf2f(attp[kv]) * bf2f(vp[kv * 72]);
            LDSH(OFF_XHT)[v * 72 + j] = f2bf(acc);
        }
    }
    __syncthreads();

    // ---- Phase F: fc-GEMM + fused epilogue -> f bf16 ----
    #pragma unroll
    for (int ii = 0; ii < 2; ++ii) {
        int idx = wid * 2 + ii, mt = idx >> 1, ntt = idx & 1;
        f32x4 acc = {0.f, 0.f, 0.f, 0.f};
        #pragma unroll
        for (int ks = 0; ks < 2; ++ks) {
            bf16x8 a = *(const bf16x8*)(&fct[(mt * 16 + r0) * 64 + ks * 32 + g * 8]);
            bf16x8 b = LDSV8(OFF_XHT + ((ntt * 16 + r0) * 72 + ks * 32 + g * 8) * 2);
            acc = MFMA(a, b, acc);
        }
        int v = ntt * 16 + r0;
        if (v < 25) {
            int cb = mt * 16 + g * 4;
            #pragma unroll
            for (int r = 0; r < 4; ++r) {
                int c = cb + r;
                float fa_out = acc[r] + LDSF(OFF_INP)[c * 25 + v];
                float fv = (fa_out * gate + LDSF(OFF_AGG)[c * 25 + v]) * 0.5f;
                float s2 = bn2_g[c] * rsqrtf(bn2_v[c] + BN_EPS);
                float b2 = bn2_b[c] - bn2_m[c] * s2;
                fv = fmaxf(fv * s2 + b2, 0.f);
                f_out[((n * 64 + c) * 512 + t) * 25 + v] = f2bf(fv);
            }
        }
    }
}

// ---------------------------------------------------------------------------
// tcn_mfma: temporal conv as implicit GEMM on matrix cores.
//   out[co, (tb,v)] = sum_{dt, ci} Wtc[co][dt][ci] * f[ci][t0+tb+dt-4][v]
// K ordered (dt, ci): each K=32 MFMA slice has FIXED dt -> B-operand is the
// staged f window with a t-shift (no im2col copy). Per block: one n, 16
// t-steps, M=64 co, N=400 cols (25 n-tiles), K=576 (9 dt x 2 ci-phases).
// f staged [t'][v][ci] with ci-stride padded to 34 (17-bank step: lanes 0..15
// hit distinct banks, G4/m136). A-frags (W) read from L2 into 9 regs, reused
// over 25 n-tiles. LDS 40800 B -> 3 blocks/CU. acc: 25 x f32x4 = 100 VGPR.
// ---------------------------------------------------------------------------
#define FB_STRIDE 34

__global__ __launch_bounds__(256) void tcn_mfma(
    const u16* __restrict__ f, const float* __restrict__ x,
    const u16* __restrict__ wtc, const float* __restrict__ tconv_b,
    const float* __restrict__ bn3_g, const float* __restrict__ bn3_b,
    const float* __restrict__ bn3_m, const float* __restrict__ bn3_v,
    float* __restrict__ out)
{
    const int bid  = blockIdx.x;
    const int n    = bid >> 5;          // 32 t-tiles per n
    const int t0   = (bid & 31) * 16;
    const int tid  = threadIdx.x;
    const int lane = tid & 63;
    const int wid  = tid >> 6;
    const int r0   = lane & 15;
    const int g    = lane >> 4;
    const int co_base = wid * 16;

    __shared__ __align__(16) u16 s_fB[24 * 25 * FB_STRIDE];   // 40800 B

    f32x4 acc[25];
    #pragma unroll
    for (int i = 0; i < 25; ++i) acc[i] = (f32x4){0.f, 0.f, 0.f, 0.f};

    for (int ph = 0; ph < 2; ++ph) {
        const int ci0 = ph * 32;
        __syncthreads();
        // stage f window: s_fB[t'][v][ci] = f[n][ci0+ci][t0+t'-4][v]
        for (int i = tid; i < 19200; i += 256) {
            int ci = i / 600, rem = i - ci * 600;
            int tp = rem / 25, v = rem - tp * 25;
            int tg = t0 + tp - 4;
            u16 val = 0;
            if (tg >= 0 && tg < 512)
                val = f[((n * 64 + ci0 + ci) * 512 + tg) * 25 + v];
            s_fB[(tp * 25 + v) * FB_STRIDE + ci] = val;
        }
        __syncthreads();

        // A-frags: Wtc[co_base+r0][dt][ci0 + g*8 .. +7], 9 regs, L2-resident
        bf16x8 aF[9];
        #pragma unroll
        for (int dt = 0; dt < 9; ++dt)
            aF[dt] = *(const bf16x8*)(&wtc[((co_base + r0) * 9 + dt) * 64 + ci0 + g * 8]);

        #pragma unroll
        for (int nt2 = 0; nt2 < 25; ++nt2) {
            int c0 = nt2 * 16 + r0;
            int tb = c0 / 25, v = c0 - tb * 25;
            #pragma unroll
            for (int dt = 0; dt < 9; ++dt) {
                bf16x8 bF = *(const bf16x8*)(&s_fB[((tb + dt) * 25 + v) * FB_STRIDE + g * 8]);
                acc[nt2] = MFMA(aF[dt], bF, acc[nt2]);
            }
        }
    }

    // epilogue: bn3 + bias + residual + relu
    float s3v[4], pre[4];
    #pragma unroll
    for (int r = 0; r < 4; ++r) {
        int co = co_base + g * 4 + r;
        float s3 = bn3_g[co] * rsqrtf(bn3_v[co] + BN_EPS);
        float b3 = bn3_b[co] - bn3_m[co] * s3;
        s3v[r] = s3;
        pre[r] = tconv_b[co] * s3 + b3;
    }
    #pragma unroll
    for (int nt2 = 0; nt2 < 25; ++nt2) {
        int c0 = nt2 * 16 + r0;
        int tb = c0 / 25, v = c0 - tb * 25;
        #pragma unroll
        for (int r = 0; r < 4; ++r) {
            int co = co_base + g * 4 + r;
            int idx = ((n * 64 + co) * 512 + t0 + tb) * 25 + v;
            float y = acc[nt2][r] * s3v[r] + pre[r] + x[idx];
            out[idx] = fmaxf(y, 0.f);
        }
    }
}

extern "C" void kernel_launch(void* const* d_in, const int* in_sizes, int n_in,
                              void* d_out, int out_size, void* d_ws, size_t ws_size,
                              hipStream_t stream) {
    const float* x       = (const float*)d_in[0];
    const float* A       = (const float*)d_in[1];
    const float* bn1_g   = (const float*)d_in[2];
    const float* bn1_b   = (const float*)d_in[3];
    const float* bn1_m   = (const float*)d_in[4];
    const float* bn1_v   = (const float*)d_in[5];
    const float* pconv_w = (const float*)d_in[6];
    const float* pconv_b = (const float*)d_in[7];
    const float* wq      = (const float*)d_in[8];
    const float* wk      = (const float*)d_in[9];
    const float* wv      = (const float*)d_in[10];
    const float* fc_w    = (const float*)d_in[11];
    const float* ln_g    = (const float*)d_in[12];
    const float* ln_b    = (const float*)d_in[13];
    const float* gate_w  = (const float*)d_in[14];
    const float* bn2_g   = (const float*)d_in[15];
    const float* bn2_b   = (const float*)d_in[16];
    const float* bn2_m   = (const float*)d_in[17];
    const float* bn2_v   = (const float*)d_in[18];
    const float* tconv_w = (const float*)d_in[19];
    const float* tconv_b = (const float*)d_in[20];
    const float* bn3_g   = (const float*)d_in[21];
    const float* bn3_b   = (const float*)d_in[22];
    const float* bn3_m   = (const float*)d_in[23];
    const float* bn3_v   = (const float*)d_in[24];

    char* ws = (char*)d_ws;
    u16*   f_bf = (u16*)ws;
    u16*   akt  = (u16*)(ws + WOFF);
    u16*   wp2  = (u16*)(ws + WOFF + 7680);
    u16*   wqt  = (u16*)(ws + WOFF + 32256);
    u16*   wkt  = (u16*)(ws + WOFF + 40448);
    u16*   wvt  = (u16*)(ws + WOFF + 48640);
    u16*   fct  = (u16*)(ws + WOFF + 56832);
    float* bagg = (float*)(ws + WOFF + 65024);
    u16*   wtc  = (u16*)(ws + WOFF + 71424);
    float* outp = (float*)d_out;

    prep_kernel<<<dim3(64), dim3(256), 0, stream>>>(
        A, pconv_w, pconv_b, wq, wk, wv, fc_w, tconv_w,
        akt, wp2, wqt, wkt, wvt, fct, bagg, wtc);
    scn_kernel<<<dim3(NB * T), dim3(256), 0, stream>>>(
        x, bn1_g, bn1_b, bn1_m, bn1_v, akt, wp2, wqt, wkt, wvt, fct, bagg,
        ln_g, ln_b, gate_w, bn2_g, bn2_b, bn2_m, bn2_v, f_bf);
    tcn_mfma<<<dim3(NB * 32), dim3(256), 0, stream>>>(
        f_bf, x, wtc, tconv_b, bn3_g, bn3_b, bn3_m, bn3_v, outp);
}

// Round 11
// 663.212 us; speedup vs baseline: 15.1584x; 1.0359x over previous
//
#include <hip/hip_runtime.h>

#define NB   32
#define C    64
#define T    512
#define V    25
#define KP   3
#define CO   64
#define H    4
#define BN_EPS 1e-5f
#define LN_EPS 1e-6f

typedef float f32x4 __attribute__((ext_vector_type(4)));
typedef short bf16x8 __attribute__((ext_vector_type(8)));
typedef unsigned short u16;
#define MFMA(a,b,c) __builtin_amdgcn_mfma_f32_16x16x32_bf16((a),(b),(c),0,0,0)

__device__ __forceinline__ u16 f2bf(float x) {
    union { float f; unsigned u; } v; v.f = x;
    unsigned r = (v.u + 0x7FFFu + ((v.u >> 16) & 1u)) >> 16;
    return (u16)r;
}
__device__ __forceinline__ float bf2f(u16 h) {
    union { unsigned u; float f; } v; v.u = ((unsigned)h) << 16;
    return v.f;
}

#define WOFF 52428800ull

__global__ __launch_bounds__(256) void prep_kernel(
    const float* __restrict__ A, const float* __restrict__ pconv_w,
    const float* __restrict__ pconv_b,
    const float* __restrict__ wq, const float* __restrict__ wk,
    const float* __restrict__ wv, const float* __restrict__ fc_w,
    const float* __restrict__ tconv_w,
    u16* __restrict__ akt, u16* __restrict__ wp2,
    u16* __restrict__ wqt, u16* __restrict__ wkt, u16* __restrict__ wvt,
    u16* __restrict__ fct, float* __restrict__ bagg, u16* __restrict__ wtc)
{
    const int stride = gridDim.x * 256;
    for (int i = blockIdx.x * 256 + threadIdx.x; i < 70976; i += stride) {
        if (i < 3840) {                       // AkT
            int k = i / 1280, r = i - k * 1280, w = r / 40, v = r - w * 40;
            float val = (w < V && v < V) ? A[k * V * V + v * V + w] : 0.f;
            akt[i] = f2bf(val);
        } else if (i < 16128) {               // Wp2
            int i2 = i - 3840;
            int c = i2 / 192, kk = i2 - c * 192, k = kk / 64, ci = kk - k * 64;
            wp2[i2] = f2bf(pconv_w[(k * 64 + c) * 64 + ci]);
        } else if (i < 20224) {               // WqT
            int i2 = i - 16128; int j = i2 / 64, c = i2 - j * 64;
            wqt[i2] = f2bf(wq[c * 64 + j]);
        } else if (i < 24320) {               // WkT
            int i2 = i - 20224; int j = i2 / 64, c = i2 - j * 64;
            wkt[i2] = f2bf(wk[c * 64 + j]);
        } else if (i < 28416) {               // WvT
            int i2 = i - 24320; int j = i2 / 64, c = i2 - j * 64;
            wvt[i2] = f2bf(wv[c * 64 + j]);
        } else if (i < 32512) {               // FcT
            int i2 = i - 28416; int c = i2 / 64, d = i2 - c * 64;
            fct[i2] = f2bf(fc_w[d * 64 + c]);
        } else if (i < 34112) {               // bias_agg
            int i2 = i - 32512; int c = i2 / 25, w = i2 - c * 25;
            float s = 0.f;
            for (int k = 0; k < KP; ++k) {
                float cs = 0.f;
                for (int v = 0; v < V; ++v) cs += A[k * V * V + v * V + w];
                s += pconv_b[k * 64 + c] * cs;
            }
            bagg[i2] = s;
        } else {                              // Wtc
            int i2 = i - 34112;
            int co = i2 / 576, rem = i2 - co * 576, dt = rem / 64, ci = rem - dt * 64;
            wtc[i2] = f2bf(tconv_w[(co * 64 + ci) * 9 + dt]);
        }
    }
}

// ---------------------------------------------------------------------------
// scn: R10 structure, but attention compute BISECTED back to VALU (R9-
// validated logic) reading the new Q2/K2/VVT layouts, touching only real
// elements (d<16, kv<25). MFMA kept for: y-GEMM, k/v/q projections, agg
// (in registers), fc. If this passes -> bug was in R10's MFMA D1/E.
// ---------------------------------------------------------------------------
#define OFF_INP   0
#define OFF_INPV  6400
#define OFF_XHT   6400
#define OFF_INPT  11520
#define OFF_ATT   11520
#define OFF_QNT   15120
#define OFF_Q2    18720
#define OFF_K2    25520
#define OFF_VVT   32320
#define OFF_YT    36928
#define OFF_S     36928
#define OFF_MU    49728
#define OFF_RSTD  49828
#define OFF_LNS   49928
#define LDS_BYTES 51528

#define LDSF(off) ((float*)(s_raw + (off)))
#define LDSH(off) ((u16*)(s_raw + (off)))
#define LDSV8(b)  (*(const bf16x8*)(s_raw + (b)))

__global__ __launch_bounds__(256) void scn_kernel(
    const float* __restrict__ x,
    const float* __restrict__ bn1_g, const float* __restrict__ bn1_b,
    const float* __restrict__ bn1_m, const float* __restrict__ bn1_v,
    const u16* __restrict__ akt, const u16* __restrict__ wp2,
    const u16* __restrict__ wqt, const u16* __restrict__ wkt,
    const u16* __restrict__ wvt, const u16* __restrict__ fct,
    const float* __restrict__ bagg,
    const float* __restrict__ ln_g, const float* __restrict__ ln_b,
    const float* __restrict__ gate_w,
    const float* __restrict__ bn2_g, const float* __restrict__ bn2_b,
    const float* __restrict__ bn2_m, const float* __restrict__ bn2_v,
    u16* __restrict__ f_out)
{
    const int nt   = blockIdx.x;
    const int n    = nt >> 9;
    const int t    = nt & 511;
    const int tid  = threadIdx.x;
    const int lane = tid & 63;
    const int wid  = tid >> 6;
    const int r0   = lane & 15;
    const int g    = lane >> 4;

    __shared__ __align__(16) unsigned char s_raw[LDS_BYTES];

    const float gate = gate_w[0];

    // ---- P0: bn1(x) -> INP f32, INPV bf16 [c][40], INPT bf16 [v][72] ----
    #pragma unroll
    for (int it = 0; it < 7; ++it) {
        int i = tid + it * 256;
        if (i < 1600) {
            int c = i / 25, v = i - c * 25;
            float s1 = bn1_g[c] * rsqrtf(bn1_v[c] + BN_EPS);
            float b1 = bn1_b[c] - bn1_m[c] * s1;
            float f = x[((n * 64 + c) * 512 + t) * 25 + v] * s1 + b1;
            LDSF(OFF_INP)[c * 25 + v] = f;
            u16 hb = f2bf(f);
            LDSH(OFF_INPV)[c * 40 + v] = hb;
            LDSH(OFF_INPT)[v * 72 + c] = hb;
        }
    }
    for (int i = tid; i < 960; i += 256) {     // zero v-pad of INPV
        int c = i / 15, vz = 25 + (i - c * 15);
        LDSH(OFF_INPV)[c * 40 + vz] = 0;
    }
    {   // zero Q2+K2+VVT pads
        bf16x8 z = {0,0,0,0,0,0,0,0};
        for (int i = tid; i < 1138; i += 256)
            *(bf16x8*)(s_raw + OFF_Q2 + i * 16) = z;
    }
    __syncthreads();

    // ---- Phase A: y-GEMM, k/v projections (MFMA), LN partials ----
    #pragma unroll
    for (int ii = 0; ii < 6; ++ii) {
        int idx = wid * 6 + ii;
        int k = idx >> 3, rem = idx & 7, mt = rem >> 1, ntt = rem & 1;
        bf16x8 a = LDSV8(OFF_INPV + ((mt * 16 + r0) * 40 + g * 8) * 2);
        bf16x8 b = *(const bf16x8*)(&akt[(k * 32 + ntt * 16 + r0) * 40 + g * 8]);
        f32x4 acc = {0.f, 0.f, 0.f, 0.f};
        acc = MFMA(a, b, acc);
        int w = ntt * 16 + r0, cb = mt * 16 + g * 4;
        #pragma unroll
        for (int r = 0; r < 4; ++r)
            LDSH(OFF_YT)[w * 200 + k * 64 + cb + r] = f2bf(acc[r]);
    }
    // k-proj: D[v][j] -> K2[v][jo]
    #pragma unroll
    for (int ii = 0; ii < 2; ++ii) {
        int idx = wid * 2 + ii, mt = idx >> 2, ntt = idx & 3;
        f32x4 acc = {0.f, 0.f, 0.f, 0.f};
        #pragma unroll
        for (int ks = 0; ks < 2; ++ks) {
            bf16x8 a = LDSV8(OFF_INPT + ((mt * 16 + r0) * 72 + ks * 32 + g * 8) * 2);
            bf16x8 b = *(const bf16x8*)(&wkt[(ntt * 16 + r0) * 64 + ks * 32 + g * 8]);
            acc = MFMA(a, b, acc);
        }
        int j = ntt * 16 + r0, jo = (j >> 4) * 32 + (j & 15);
        #pragma unroll
        for (int r = 0; r < 4; ++r) {
            int v = mt * 16 + g * 4 + r;
            if (v < 25) LDSH(OFF_K2)[v * 136 + jo] = f2bf(acc[r]);
        }
    }
    // v-proj: D[v][j] -> VVT[j][v]
    #pragma unroll
    for (int ii = 0; ii < 2; ++ii) {
        int idx = wid * 2 + ii, mt = idx >> 2, ntt = idx & 3;
        f32x4 acc = {0.f, 0.f, 0.f, 0.f};
        #pragma unroll
        for (int ks = 0; ks < 2; ++ks) {
            bf16x8 a = LDSV8(OFF_INPT + ((mt * 16 + r0) * 72 + ks * 32 + g * 8) * 2);
            bf16x8 b = *(const bf16x8*)(&wvt[(ntt * 16 + r0) * 64 + ks * 32 + g * 8]);
            acc = MFMA(a, b, acc);
        }
        int j = ntt * 16 + r0;
        #pragma unroll
        for (int r = 0; r < 4; ++r) {
            int v = mt * 16 + g * 4 + r;
            if (v < 25) LDSH(OFF_VVT)[j * 36 + v] = f2bf(acc[r]);
        }
    }
    // LN partials
    if (tid < 200) {
        int v = tid >> 3, p = tid & 7;
        float s1 = 0.f, s2 = 0.f;
        #pragma unroll
        for (int cc = 0; cc < 8; ++cc) {
            float xv = LDSF(OFF_INP)[(p * 8 + cc) * 25 + v];
            s1 += xv; s2 += xv * xv;
        }
        LDSF(OFF_LNS)[(v * 8 + p) * 2]     = s1;
        LDSF(OFF_LNS)[(v * 8 + p) * 2 + 1] = s2;
    }
    __syncthreads();

    // ---- B0: LN reduce ----
    if (tid < 25) {
        float s1 = 0.f, s2 = 0.f;
        #pragma unroll
        for (int p = 0; p < 8; ++p) {
            s1 += LDSF(OFF_LNS)[(tid * 8 + p) * 2];
            s2 += LDSF(OFF_LNS)[(tid * 8 + p) * 2 + 1];
        }
        float mu = s1 * (1.f / 64.f);
        float var = s2 * (1.f / 64.f) - mu * mu;
        LDSF(OFF_MU)[tid]   = mu;
        LDSF(OFF_RSTD)[tid] = rsqrtf(var + LN_EPS);
    }
    __syncthreads();

    // ---- B1: qn = LN(inp) -> QNT [v][72] ----
    #pragma unroll
    for (int it = 0; it < 7; ++it) {
        int i = tid + it * 256;
        if (i < 1600) {
            int v = i >> 6, c = i & 63;
            float f = LDSF(OFF_INP)[c * 25 + v];
            float q = (f - LDSF(OFF_MU)[v]) * LDSF(OFF_RSTD)[v] * ln_g[c] + ln_b[c];
            LDSH(OFF_QNT)[v * 72 + c] = f2bf(q);
        }
    }
    __syncthreads();

    // ---- Phase C: agg-GEMM (K=192 -> REGISTERS) + q projection ----
    f32x4 agg_reg[2];
    #pragma unroll
    for (int ii = 0; ii < 2; ++ii) {
        int idx = wid * 2 + ii, mt = idx >> 1, ntt = idx & 1;
        f32x4 acc = {0.f, 0.f, 0.f, 0.f};
        #pragma unroll
        for (int ks = 0; ks < 6; ++ks) {
            bf16x8 a = *(const bf16x8*)(&wp2[(mt * 16 + r0) * 192 + ks * 32 + g * 8]);
            bf16x8 b = LDSV8(OFF_YT + ((ntt * 16 + r0) * 200 + ks * 32 + g * 8) * 2);
            acc = MFMA(a, b, acc);
        }
        int w = ntt * 16 + r0, cb = mt * 16 + g * 4;
        if (w < 25) {
            #pragma unroll
            for (int r = 0; r < 4; ++r) acc[r] += bagg[(cb + r) * 25 + w];
        }
        agg_reg[ii] = acc;
    }
    #pragma unroll
    for (int ii = 0; ii < 2; ++ii) {            // q-proj -> Q2
        int idx = wid * 2 + ii, mt = idx >> 2, ntt = idx & 3;
        f32x4 acc = {0.f, 0.f, 0.f, 0.f};
        #pragma unroll
        for (int ks = 0; ks < 2; ++ks) {
            bf16x8 a = LDSV8(OFF_QNT + ((mt * 16 + r0) * 72 + ks * 32 + g * 8) * 2);
            bf16x8 b = *(const bf16x8*)(&wqt[(ntt * 16 + r0) * 64 + ks * 32 + g * 8]);
            acc = MFMA(a, b, acc);
        }
        int j = ntt * 16 + r0, jo = (j >> 4) * 32 + (j & 15);
        #pragma unroll
        for (int r = 0; r < 4; ++r) {
            int v = mt * 16 + g * 4 + r;
            if (v < 25) LDSH(OFF_Q2)[v * 136 + jo] = f2bf(acc[r]);
        }
    }
    __syncthreads();

    // ---- D1 (VALU bisect): S[h][qv][kv] raw dot, d<16 only -> S f32 ----
    if (tid < 100) {
        int h = tid / 25, qv = tid - h * 25;
        float qf[16];
        #pragma unroll
        for (int d = 0; d < 16; ++d)
            qf[d] = bf2f(LDSH(OFF_Q2)[qv * 136 + h * 32 + d]);
        #pragma unroll
        for (int kv = 0; kv < 25; ++kv) {
            float s = 0.f;
            #pragma unroll
            for (int d = 0; d < 16; ++d)
                s += qf[d] * bf2f(LDSH(OFF_K2)[kv * 136 + h * 32 + d]);
            LDSF(OFF_S)[(h * 25 + qv) * 26 + kv] = s;
        }
    }
    __syncthreads();

    // ---- D2: softmax (100 threads) -> ATT bf16 [4][32][40] ----
    if (tid < 100) {
        int h = tid / 25, qv = tid - h * 25;
        const float* srow = LDSF(OFF_S) + (h * 25 + qv) * 26;
        float row[25]; float mx = -1e30f;
        #pragma unroll
        for (int kv = 0; kv < 25; ++kv) {
            float s = srow[kv] * 0.25f;
            row[kv] = s; mx = fmaxf(mx, s);
        }
        float sum = 0.f;
        #pragma unroll
        for (int kv = 0; kv < 25; ++kv) { float e = __expf(row[kv] - mx); row[kv] = e; sum += e; }
        float inv = 1.f / sum;
        #pragma unroll
        for (int kv = 0; kv < 25; ++kv)
            LDSH(OFF_ATT)[(h * 32 + qv) * 40 + kv] = f2bf(row[kv] * inv);
    }
    __syncthreads();

    // ---- E (VALU bisect): xh[v][j] = sum_kv att[h][v][kv] * VVT[j][kv] ----
    #pragma unroll
    for (int it = 0; it < 7; ++it) {
        int i = tid + it * 256;
        if (i < 1600) {
            int v = i >> 6, j = i & 63, h = j >> 4;
            const u16* attp = LDSH(OFF_ATT) + (h * 32 + v) * 40;
            const u16* vp   = LDSH(OFF_VVT) + j * 36;
            float acc = 0.f;
            #pragma unroll
            for (int kv = 0; kv < 25; ++kv)
                acc += bf2f(attp[kv]) * bf2f(vp[kv]);
            LDSH(OFF_XHT)[v * 72 + j] = f2bf(acc);
        }
    }
    __syncthreads();

    // ---- F: fc-GEMM + fused epilogue (agg from registers) -> f bf16 ----
    #pragma unroll
    for (int ii = 0; ii < 2; ++ii) {
        int idx = wid * 2 + ii, mt = idx >> 1, ntt = idx & 1;
        f32x4 acc = {0.f, 0.f, 0.f, 0.f};
        #pragma unroll
        for (int ks = 0; ks < 2; ++ks) {
            bf16x8 a = *(const bf16x8*)(&fct[(mt * 16 + r0) * 64 + ks * 32 + g * 8]);
            bf16x8 b = LDSV8(OFF_XHT + ((ntt * 16 + r0) * 72 + ks * 32 + g * 8) * 2);
            acc = MFMA(a, b, acc);
        }
        int v = ntt * 16 + r0;
        if (v < 25) {
            int cb = mt * 16 + g * 4;
            #pragma unroll
            for (int r = 0; r < 4; ++r) {
                int c = cb + r;
                float fa_out = acc[r] + LDSF(OFF_INP)[c * 25 + v];
                float fv = (fa_out * gate + agg_reg[ii][r]) * 0.5f;
                float s2 = bn2_g[c] * rsqrtf(bn2_v[c] + BN_EPS);
                float b2 = bn2_b[c] - bn2_m[c] * s2;
                fv = fmaxf(fv * s2 + b2, 0.f);
                f_out[((n * 64 + c) * 512 + t) * 25 + v] = f2bf(fv);
            }
        }
    }
}

// ---------------------------------------------------------------------------
// tcn_mfma: unchanged (R9-validated, ~230us).
// ---------------------------------------------------------------------------
#define FB_STRIDE 34

__global__ __launch_bounds__(256) void tcn_mfma(
    const u16* __restrict__ f, const float* __restrict__ x,
    const u16* __restrict__ wtc, const float* __restrict__ tconv_b,
    const float* __restrict__ bn3_g, const float* __restrict__ bn3_b,
    const float* __restrict__ bn3_m, const float* __restrict__ bn3_v,
    float* __restrict__ out)
{
    const int bid  = blockIdx.x;
    const int n    = bid >> 5;
    const int t0   = (bid & 31) * 16;
    const int tid  = threadIdx.x;
    const int lane = tid & 63;
    const int wid  = tid >> 6;
    const int r0   = lane & 15;
    const int g    = lane >> 4;
    const int co_base = wid * 16;

    __shared__ __align__(16) u16 s_fB[24 * 25 * FB_STRIDE];

    f32x4 acc[25];
    #pragma unroll
    for (int i = 0; i < 25; ++i) acc[i] = (f32x4){0.f, 0.f, 0.f, 0.f};

    for (int ph = 0; ph < 2; ++ph) {
        const int ci0 = ph * 32;
        __syncthreads();
        for (int i = tid; i < 19200; i += 256) {
            int ci = i / 600, rem = i - ci * 600;
            int tp = rem / 25, v = rem - tp * 25;
            int tg = t0 + tp - 4;
            u16 val = 0;
            if (tg >= 0 && tg < 512)
                val = f[((n * 64 + ci0 + ci) * 512 + tg) * 25 + v];
            s_fB[(tp * 25 + v) * FB_STRIDE + ci] = val;
        }
        __syncthreads();

        bf16x8 aF[9];
        #pragma unroll
        for (int dt = 0; dt < 9; ++dt)
            aF[dt] = *(const bf16x8*)(&wtc[((co_base + r0) * 9 + dt) * 64 + ci0 + g * 8]);

        #pragma unroll
        for (int nt2 = 0; nt2 < 25; ++nt2) {
            int c0 = nt2 * 16 + r0;
            int tb = c0 / 25, v = c0 - tb * 25;
            #pragma unroll
            for (int dt = 0; dt < 9; ++dt) {
                bf16x8 bF = *(const bf16x8*)(&s_fB[((tb + dt) * 25 + v) * FB_STRIDE + g * 8]);
                acc[nt2] = MFMA(aF[dt], bF, acc[nt2]);
            }
        }
    }

    float s3v[4], pre[4];
    #pragma unroll
    for (int r = 0; r < 4; ++r) {
        int co = co_base + g * 4 + r;
        float s3 = bn3_g[co] * rsqrtf(bn3_v[co] + BN_EPS);
        float b3 = bn3_b[co] - bn3_m[co] * s3;
        s3v[r] = s3;
        pre[r] = tconv_b[co] * s3 + b3;
    }
    #pragma unroll
    for (int nt2 = 0; nt2 < 25; ++nt2) {
        int c0 = nt2 * 16 + r0;
        int tb = c0 / 25, v = c0 - tb * 25;
        #pragma unroll
        for (int r = 0; r < 4; ++r) {
            int co = co_base + g * 4 + r;
            int idx = ((n * 64 + co) * 512 + t0 + tb) * 25 + v;
            float y = acc[nt2][r] * s3v[r] + pre[r] + x[idx];
            out[idx] = fmaxf(y, 0.f);
        }
    }
}

extern "C" void kernel_launch(void* const* d_in, const int* in_sizes, int n_in,
                              void* d_out, int out_size, void* d_ws, size_t ws_size,
                              hipStream_t stream) {
    const float* x       = (const float*)d_in[0];
    const float* A       = (const float*)d_in[1];
    const float* bn1_g   = (const float*)d_in[2];
    const float* bn1_b   = (const float*)d_in[3];
    const float* bn1_m   = (const float*)d_in[4];
    const float* bn1_v   = (const float*)d_in[5];
    const float* pconv_w = (const float*)d_in[6];
    const float* pconv_b = (const float*)d_in[7];
    const float* wq      = (const float*)d_in[8];
    const float* wk      = (const float*)d_in[9];
    const float* wv      = (const float*)d_in[10];
    const float* fc_w    = (const float*)d_in[11];
    const float* ln_g    = (const float*)d_in[12];
    const float* ln_b    = (const float*)d_in[13];
    const float* gate_w  = (const float*)d_in[14];
    const float* bn2_g   = (const float*)d_in[15];
    const float* bn2_b   = (const float*)d_in[16];
    const float* bn2_m   = (const float*)d_in[17];
    const float* bn2_v   = (const float*)d_in[18];
    const float* tconv_w = (const float*)d_in[19];
    const float* tconv_b = (const float*)d_in[20];
    const float* bn3_g   = (const float*)d_in[21];
    const float* bn3_b   = (const float*)d_in[22];
    const float* bn3_m   = (const float*)d_in[23];
    const float* bn3_v   = (const float*)d_in[24];

    char* ws = (char*)d_ws;
    u16*   f_bf = (u16*)ws;
    u16*   akt  = (u16*)(ws + WOFF);
    u16*   wp2  = (u16*)(ws + WOFF + 7680);
    u16*   wqt  = (u16*)(ws + WOFF + 32256);
    u16*   wkt  = (u16*)(ws + WOFF + 40448);
    u16*   wvt  = (u16*)(ws + WOFF + 48640);
    u16*   fct  = (u16*)(ws + WOFF + 56832);
    float* bagg = (float*)(ws + WOFF + 65024);
    u16*   wtc  = (u16*)(ws + WOFF + 71424);
    float* outp = (float*)d_out;

    prep_kernel<<<dim3(64), dim3(256), 0, stream>>>(
        A, pconv_w, pconv_b, wq, wk, wv, fc_w, tconv_w,
        akt, wp2, wqt, wkt, wvt, fct, bagg, wtc);
    scn_kernel<<<dim3(NB * T), dim3(256), 0, stream>>>(
        x, bn1_g, bn1_b, bn1_m, bn1_v, akt, wp2, wqt, wkt, wvt, fct, bagg,
        ln_g, ln_b, gate_w, bn2_g, bn2_b, bn2_m, bn2_v, f_bf);
    tcn_mfma<<<dim3(NB * 32), dim3(256), 0, stream>>>(
        f_bf, x, wtc, tconv_b, bn3_g, bn3_b, bn3_m, bn3_v, outp);
}

// Round 13
// 568.408 us; speedup vs baseline: 17.6867x; 1.1668x over previous
//
#include <hip/hip_runtime.h>

#define NB   32
#define C    64
#define T    512
#define V    25
#define KP   3
#define CO   64
#define H    4
#define BN_EPS 1e-5f
#define LN_EPS 1e-6f

typedef float f32x4 __attribute__((ext_vector_type(4)));
typedef short bf16x8 __attribute__((ext_vector_type(8)));
typedef unsigned short u16;
typedef unsigned int u32;
typedef u32 u32x2 __attribute__((ext_vector_type(2)));
#define MFMA(a,b,c) __builtin_amdgcn_mfma_f32_16x16x32_bf16((a),(b),(c),0,0,0)

__device__ __forceinline__ u16 f2bf(float x) {
    union { float f; unsigned u; } v; v.f = x;
    unsigned r = (v.u + 0x7FFFu + ((v.u >> 16) & 1u)) >> 16;
    return (u16)r;
}
__device__ __forceinline__ float bf2f(u16 h) {
    union { unsigned u; float f; } v; v.u = ((unsigned)h) << 16;
    return v.f;
}

// ---------------------------------------------------------------------------
// ws layout (bytes):
//   [0, 52428800)            f intermediate, bf16, layout [n][t][v][c]  (R12:
//                            was [n][c][t][v]; new layout -> vectorized tcn
//                            staging + packed scn F-stores)
//   WOFF = 52428800: prepped weights (unchanged from R9/R11)
// ---------------------------------------------------------------------------
#define WOFF 52428800ull

__global__ __launch_bounds__(256) void prep_kernel(
    const float* __restrict__ A, const float* __restrict__ pconv_w,
    const float* __restrict__ pconv_b,
    const float* __restrict__ wq, const float* __restrict__ wk,
    const float* __restrict__ wv, const float* __restrict__ fc_w,
    const float* __restrict__ tconv_w,
    u16* __restrict__ akt, u16* __restrict__ wp2,
    u16* __restrict__ wqt, u16* __restrict__ wkt, u16* __restrict__ wvt,
    u16* __restrict__ fct, float* __restrict__ bagg, u16* __restrict__ wtc)
{
    const int stride = gridDim.x * 256;
    for (int i = blockIdx.x * 256 + threadIdx.x; i < 70976; i += stride) {
        if (i < 3840) {                       // AkT
            int k = i / 1280, r = i - k * 1280, w = r / 40, v = r - w * 40;
            float val = (w < V && v < V) ? A[k * V * V + v * V + w] : 0.f;
            akt[i] = f2bf(val);
        } else if (i < 16128) {               // Wp2
            int i2 = i - 3840;
            int c = i2 / 192, kk = i2 - c * 192, k = kk / 64, ci = kk - k * 64;
            wp2[i2] = f2bf(pconv_w[(k * 64 + c) * 64 + ci]);
        } else if (i < 20224) {               // WqT
            int i2 = i - 16128; int j = i2 / 64, c = i2 - j * 64;
            wqt[i2] = f2bf(wq[c * 64 + j]);
        } else if (i < 24320) {               // WkT
            int i2 = i - 20224; int j = i2 / 64, c = i2 - j * 64;
            wkt[i2] = f2bf(wk[c * 64 + j]);
        } else if (i < 28416) {               // WvT
            int i2 = i - 24320; int j = i2 / 64, c = i2 - j * 64;
            wvt[i2] = f2bf(wv[c * 64 + j]);
        } else if (i < 32512) {               // FcT
            int i2 = i - 28416; int c = i2 / 64, d = i2 - c * 64;
            fct[i2] = f2bf(fc_w[d * 64 + c]);
        } else if (i < 34112) {               // bias_agg
            int i2 = i - 32512; int c = i2 / 25, w = i2 - c * 25;
            float s = 0.f;
            for (int k = 0; k < KP; ++k) {
                float cs = 0.f;
                for (int v = 0; v < V; ++v) cs += A[k * V * V + v * V + w];
                s += pconv_b[k * 64 + c] * cs;
            }
            bagg[i2] = s;
        } else {                              // Wtc
            int i2 = i - 34112;
            int co = i2 / 576, rem = i2 - co * 576, dt = rem / 64, ci = rem - dt * 64;
            wtc[i2] = f2bf(tconv_w[(co * 64 + ci) * 9 + dt]);
        }
    }
}

// ---------------------------------------------------------------------------
// scn: R11-validated structure. R12 deltas: (1) V-proj stores f32 -> VVTF
// (stride 29, conflict-free), (2) D2 writes normalized P in-place into S
// (f32), (3) Phase E reads f32 att & vv -> pure 25-FMA loop, no cvts,
// (4) F-store packs 4 bf16 into one 8B store, new f layout [n][t][v][c],
// (5) zero-fill dropped (VALU D1/E touch only real slots).
// LDS 54344 B -> 3 blocks/CU. Plain launch_bounds (R5: min-waves => spills).
// ---------------------------------------------------------------------------
#define OFF_INP   0        // f32 [64][25]
#define OFF_INPV  6400     // bf16 [64][40]     (P0 -> A) / XHT (E -> F)
#define OFF_XHT   6400     // bf16 [25][72]
#define OFF_INPT  11520    // bf16 [25][72]     (P0 -> A)
#define OFF_QNT   15120    // bf16 [25][72]     (B1 -> C)
#define OFF_Q2    18720    // bf16 [25][136]    (C -> D1)
#define OFF_K2    25520    // bf16 [25][136]    (A -> D1)
#define OFF_VVTF  32320    // f32  [64][29]     (A -> E)
#define OFF_YT    39744    // bf16 [32][200]    (A -> C) / S f32 [4][25][26]
#define OFF_S     39744
#define OFF_MU    52544
#define OFF_RSTD  52644
#define OFF_LNS   52744    // f32 [25][8][2]
#define LDS_BYTES 54344

#define LDSF(off) ((float*)(s_raw + (off)))
#define LDSH(off) ((u16*)(s_raw + (off)))
#define LDSV8(b)  (*(const bf16x8*)(s_raw + (b)))

__global__ __launch_bounds__(256) void scn_kernel(
    const float* __restrict__ x,
    const float* __restrict__ bn1_g, const float* __restrict__ bn1_b,
    const float* __restrict__ bn1_m, const float* __restrict__ bn1_v,
    const u16* __restrict__ akt, const u16* __restrict__ wp2,
    const u16* __restrict__ wqt, const u16* __restrict__ wkt,
    const u16* __restrict__ wvt, const u16* __restrict__ fct,
    const float* __restrict__ bagg,
    const float* __restrict__ ln_g, const float* __restrict__ ln_b,
    const float* __restrict__ gate_w,
    const float* __restrict__ bn2_g, const float* __restrict__ bn2_b,
    const float* __restrict__ bn2_m, const float* __restrict__ bn2_v,
    u16* __restrict__ f_out)
{
    const int nt   = blockIdx.x;
    const int n    = nt >> 9;
    const int t    = nt & 511;
    const int tid  = threadIdx.x;
    const int lane = tid & 63;
    const int wid  = tid >> 6;
    const int r0   = lane & 15;
    const int g    = lane >> 4;

    __shared__ __align__(16) unsigned char s_raw[LDS_BYTES];

    const float gate = gate_w[0];

    // ---- P0: bn1(x) -> INP f32, INPV bf16 [c][40], INPT bf16 [v][72] ----
    #pragma unroll
    for (int it = 0; it < 7; ++it) {
        int i = tid + it * 256;
        if (i < 1600) {
            int c = i / 25, v = i - c * 25;
            float s1 = bn1_g[c] * rsqrtf(bn1_v[c] + BN_EPS);
            float b1 = bn1_b[c] - bn1_m[c] * s1;
            float f = x[((n * 64 + c) * 512 + t) * 25 + v] * s1 + b1;
            LDSF(OFF_INP)[c * 25 + v] = f;
            u16 hb = f2bf(f);
            LDSH(OFF_INPV)[c * 40 + v] = hb;
            LDSH(OFF_INPT)[v * 72 + c] = hb;
        }
    }
    for (int i = tid; i < 960; i += 256) {     // zero v-pad of INPV (y-GEMM K)
        int c = i / 15, vz = 25 + (i - c * 15);
        LDSH(OFF_INPV)[c * 40 + vz] = 0;
    }
    __syncthreads();

    // ---- Phase A: y-GEMM, k/v projections (MFMA), LN partials ----
    #pragma unroll
    for (int ii = 0; ii < 6; ++ii) {
        int idx = wid * 6 + ii;
        int k = idx >> 3, rem = idx & 7, mt = rem >> 1, ntt = rem & 1;
        bf16x8 a = LDSV8(OFF_INPV + ((mt * 16 + r0) * 40 + g * 8) * 2);
        bf16x8 b = *(const bf16x8*)(&akt[(k * 32 + ntt * 16 + r0) * 40 + g * 8]);
        f32x4 acc = {0.f, 0.f, 0.f, 0.f};
        acc = MFMA(a, b, acc);
        int w = ntt * 16 + r0, cb = mt * 16 + g * 4;
        #pragma unroll
        for (int r = 0; r < 4; ++r)
            LDSH(OFF_YT)[w * 200 + k * 64 + cb + r] = f2bf(acc[r]);
    }
    // k-proj: D[v][j] -> K2[v][jo] bf16
    #pragma unroll
    for (int ii = 0; ii < 2; ++ii) {
        int idx = wid * 2 + ii, mt = idx >> 2, ntt = idx & 3;
        f32x4 acc = {0.f, 0.f, 0.f, 0.f};
        #pragma unroll
        for (int ks = 0; ks < 2; ++ks) {
            bf16x8 a = LDSV8(OFF_INPT + ((mt * 16 + r0) * 72 + ks * 32 + g * 8) * 2);
            bf16x8 b = *(const bf16x8*)(&wkt[(ntt * 16 + r0) * 64 + ks * 32 + g * 8]);
            acc = MFMA(a, b, acc);
        }
        int j = ntt * 16 + r0, jo = (j >> 4) * 32 + (j & 15);
        #pragma unroll
        for (int r = 0; r < 4; ++r) {
            int v = mt * 16 + g * 4 + r;
            if (v < 25) LDSH(OFF_K2)[v * 136 + jo] = f2bf(acc[r]);
        }
    }
    // v-proj: D[v][j] -> VVTF[j][v] f32 (no cvt; E consumes f32)
    #pragma unroll
    for (int ii = 0; ii < 2; ++ii) {
        int idx = wid * 2 + ii, mt = idx >> 2, ntt = idx & 3;
        f32x4 acc = {0.f, 0.f, 0.f, 0.f};
        #pragma unroll
        for (int ks = 0; ks < 2; ++ks) {
            bf16x8 a = LDSV8(OFF_INPT + ((mt * 16 + r0) * 72 + ks * 32 + g * 8) * 2);
            bf16x8 b = *(const bf16x8*)(&wvt[(ntt * 16 + r0) * 64 + ks * 32 + g * 8]);
            acc = MFMA(a, b, acc);
        }
        int j = ntt * 16 + r0;
        #pragma unroll
        for (int r = 0; r < 4; ++r) {
            int v = mt * 16 + g * 4 + r;
            if (v < 25) LDSF(OFF_VVTF)[j * 29 + v] = acc[r];
        }
    }
    // LN partials
    if (tid < 200) {
        int v = tid >> 3, p = tid & 7;
        float s1 = 0.f, s2 = 0.f;
        #pragma unroll
        for (int cc = 0; cc < 8; ++cc) {
            float xv = LDSF(OFF_INP)[(p * 8 + cc) * 25 + v];
            s1 += xv; s2 += xv * xv;
        }
        LDSF(OFF_LNS)[(v * 8 + p) * 2]     = s1;
        LDSF(OFF_LNS)[(v * 8 + p) * 2 + 1] = s2;
    }
    __syncthreads();

    // ---- B0: LN reduce ----
    if (tid < 25) {
        float s1 = 0.f, s2 = 0.f;
        #pragma unroll
        for (int p = 0; p < 8; ++p) {
            s1 += LDSF(OFF_LNS)[(tid * 8 + p) * 2];
            s2 += LDSF(OFF_LNS)[(tid * 8 + p) * 2 + 1];
        }
        float mu = s1 * (1.f / 64.f);
        float var = s2 * (1.f / 64.f) - mu * mu;
        LDSF(OFF_MU)[tid]   = mu;
        LDSF(OFF_RSTD)[tid] = rsqrtf(var + LN_EPS);
    }
    __syncthreads();

    // ---- B1: qn = LN(inp) -> QNT [v][72] ----
    #pragma unroll
    for (int it = 0; it < 7; ++it) {
        int i = tid + it * 256;
        if (i < 1600) {
            int v = i >> 6, c = i & 63;
            float f = LDSF(OFF_INP)[c * 25 + v];
            float q = (f - LDSF(OFF_MU)[v]) * LDSF(OFF_RSTD)[v] * ln_g[c] + ln_b[c];
            LDSH(OFF_QNT)[v * 72 + c] = f2bf(q);
        }
    }
    __syncthreads();

    // ---- Phase C: agg-GEMM (K=192 -> REGISTERS) + q projection ----
    f32x4 agg_reg[2];
    #pragma unroll
    for (int ii = 0; ii < 2; ++ii) {
        int idx = wid * 2 + ii, mt = idx >> 1, ntt = idx & 1;
        f32x4 acc = {0.f, 0.f, 0.f, 0.f};
        #pragma unroll
        for (int ks = 0; ks < 6; ++ks) {
            bf16x8 a = *(const bf16x8*)(&wp2[(mt * 16 + r0) * 192 + ks * 32 + g * 8]);
            bf16x8 b = LDSV8(OFF_YT + ((ntt * 16 + r0) * 200 + ks * 32 + g * 8) * 2);
            acc = MFMA(a, b, acc);
        }
        int w = ntt * 16 + r0, cb = mt * 16 + g * 4;
        if (w < 25) {
            #pragma unroll
            for (int r = 0; r < 4; ++r) acc[r] += bagg[(cb + r) * 25 + w];
        }
        agg_reg[ii] = acc;
    }
    #pragma unroll
    for (int ii = 0; ii < 2; ++ii) {            // q-proj -> Q2 bf16
        int idx = wid * 2 + ii, mt = idx >> 2, ntt = idx & 3;
        f32x4 acc = {0.f, 0.f, 0.f, 0.f};
        #pragma unroll
        for (int ks = 0; ks < 2; ++ks) {
            bf16x8 a = LDSV8(OFF_QNT + ((mt * 16 + r0) * 72 + ks * 32 + g * 8) * 2);
            bf16x8 b = *(const bf16x8*)(&wqt[(ntt * 16 + r0) * 64 + ks * 32 + g * 8]);
            acc = MFMA(a, b, acc);
        }
        int j = ntt * 16 + r0, jo = (j >> 4) * 32 + (j & 15);
        #pragma unroll
        for (int r = 0; r < 4; ++r) {
            int v = mt * 16 + g * 4 + r;
            if (v < 25) LDSH(OFF_Q2)[v * 136 + jo] = f2bf(acc[r]);
        }
    }
    __syncthreads();

    // ---- D1 (VALU, R11-validated): S[h][qv][kv] raw dot -> S f32 ----
    if (tid < 100) {
        int h = tid / 25, qv = tid - h * 25;
        float qf[16];
        #pragma unroll
        for (int d = 0; d < 16; ++d)
            qf[d] = bf2f(LDSH(OFF_Q2)[qv * 136 + h * 32 + d]);
        #pragma unroll
        for (int kv = 0; kv < 25; ++kv) {
            float s = 0.f;
            #pragma unroll
            for (int d = 0; d < 16; ++d)
                s += qf[d] * bf2f(LDSH(OFF_K2)[kv * 136 + h * 32 + d]);
            LDSF(OFF_S)[(h * 25 + qv) * 26 + kv] = s;
        }
    }
    __syncthreads();

    // ---- D2: softmax, write normalized P in-place into S (f32) ----
    if (tid < 100) {
        int h = tid / 25, qv = tid - h * 25;
        float* srow = LDSF(OFF_S) + (h * 25 + qv) * 26;
        float row[25]; float mx = -1e30f;
        #pragma unroll
        for (int kv = 0; kv < 25; ++kv) {
            float s = srow[kv] * 0.25f;
            row[kv] = s; mx = fmaxf(mx, s);
        }
        float sum = 0.f;
        #pragma unroll
        for (int kv = 0; kv < 25; ++kv) { float e = __expf(row[kv] - mx); row[kv] = e; sum += e; }
        float inv = 1.f / sum;
        #pragma unroll
        for (int kv = 0; kv < 25; ++kv) srow[kv] = row[kv] * inv;
    }
    __syncthreads();

    // ---- E (VALU f32, no cvts): xh[v][j] = sum_kv P[h][v][kv]*VVTF[j][kv] ----
    #pragma unroll
    for (int it = 0; it < 7; ++it) {
        int i = tid + it * 256;
        if (i < 1600) {
            int v = i >> 6, j = i & 63, h = j >> 4;
            const float* attp = LDSF(OFF_S) + (h * 25 + v) * 26;
            const float* vp   = LDSF(OFF_VVTF) + j * 29;
            float acc = 0.f;
            #pragma unroll
            for (int kv = 0; kv < 25; ++kv)
                acc += attp[kv] * vp[kv];
            LDSH(OFF_XHT)[v * 72 + j] = f2bf(acc);
        }
    }
    __syncthreads();

    // ---- F: fc-GEMM + fused epilogue -> f bf16, layout [n][t][v][c] ----
    #pragma unroll
    for (int ii = 0; ii < 2; ++ii) {
        int idx = wid * 2 + ii, mt = idx >> 1, ntt = idx & 1;
        f32x4 acc = {0.f, 0.f, 0.f, 0.f};
        #pragma unroll
        for (int ks = 0; ks < 2; ++ks) {
            bf16x8 a = *(const bf16x8*)(&fct[(mt * 16 + r0) * 64 + ks * 32 + g * 8]);
            bf16x8 b = LDSV8(OFF_XHT + ((ntt * 16 + r0) * 72 + ks * 32 + g * 8) * 2);
            acc = MFMA(a, b, acc);
        }
        int v = ntt * 16 + r0;
        if (v < 25) {
            int cb = mt * 16 + g * 4;
            u16 hh[4];
            #pragma unroll
            for (int r = 0; r < 4; ++r) {
                int c = cb + r;
                float fa_out = acc[r] + LDSF(OFF_INP)[c * 25 + v];
                float fv = (fa_out * gate + agg_reg[ii][r]) * 0.5f;
                float s2 = bn2_g[c] * rsqrtf(bn2_v[c] + BN_EPS);
                float b2 = bn2_b[c] - bn2_m[c] * s2;
                fv = fmaxf(fv * s2 + b2, 0.f);
                hh[r] = f2bf(fv);
            }
            u32x2 pk;
            pk[0] = (u32)hh[0] | ((u32)hh[1] << 16);
            pk[1] = (u32)hh[2] | ((u32)hh[3] << 16);
            *(u32x2*)&f_out[((n * 512 + t) * 25 + v) * 64 + cb] = pk;
        }
    }
}

// ---------------------------------------------------------------------------
// tcn_mfma: implicit-GEMM temporal conv (R9-validated math). R12: f layout
// [n][t][v][c] -> staging is bf16x8 loads + ds_write_b128 (8x fewer mem
// instructions). FB_STRIDE=40 keeps 16B alignment; B-read 2-way banks (free).
// ---------------------------------------------------------------------------
#define FB_STRIDE 40

__global__ __launch_bounds__(256) void tcn_mfma(
    const u16* __restrict__ f, const float* __restrict__ x,
    const u16* __restrict__ wtc, const float* __restrict__ tconv_b,
    const float* __restrict__ bn3_g, const float* __restrict__ bn3_b,
    const float* __restrict__ bn3_m, const float* __restrict__ bn3_v,
    float* __restrict__ out)
{
    const int bid  = blockIdx.x;
    const int n    = bid >> 5;
    const int t0   = (bid & 31) * 16;
    const int tid  = threadIdx.x;
    const int lane = tid & 63;
    const int wid  = tid >> 6;
    const int r0   = lane & 15;
    const int g    = lane >> 4;
    const int co_base = wid * 16;

    __shared__ __align__(16) u16 s_fB[24 * 25 * FB_STRIDE];   // 48000 B

    f32x4 acc[25];
    #pragma unroll
    for (int i = 0; i < 25; ++i) acc[i] = (f32x4){0.f, 0.f, 0.f, 0.f};

    for (int ph = 0; ph < 2; ++ph) {
        const int ci0 = ph * 32;
        __syncthreads();
        // stage: s_fB[tp*25+v][ci0..ci0+31] via bf16x8, 2400 units
        for (int u = tid; u < 2400; u += 256) {
            int q = u & 3, rv = u >> 2;          // rv = tp*25+v
            int tp = rv / 25, v = rv - tp * 25;
            int tg = t0 + tp - 4;
            bf16x8 val = {0,0,0,0,0,0,0,0};
            if (tg >= 0 && tg < 512)
                val = *(const bf16x8*)&f[((n * 512 + tg) * 25 + v) * 64 + ci0 + q * 8];
            *(bf16x8*)&s_fB[rv * FB_STRIDE + q * 8] = val;
        }
        __syncthreads();

        bf16x8 aF[9];
        #pragma unroll
        for (int dt = 0; dt < 9; ++dt)
            aF[dt] = *(const bf16x8*)(&wtc[((co_base + r0) * 9 + dt) * 64 + ci0 + g * 8]);

        #pragma unroll
        for (int nt2 = 0; nt2 < 25; ++nt2) {
            int c0 = nt2 * 16 + r0;
            int tb = c0 / 25, v = c0 - tb * 25;
            #pragma unroll
            for (int dt = 0; dt < 9; ++dt) {
                bf16x8 bF = *(const bf16x8*)(&s_fB[((tb + dt) * 25 + v) * FB_STRIDE + g * 8]);
                acc[nt2] = MFMA(aF[dt], bF, acc[nt2]);
            }
        }
    }

    float s3v[4], pre[4];
    #pragma unroll
    for (int r = 0; r < 4; ++r) {
        int co = co_base + g * 4 + r;
        float s3 = bn3_g[co] * rsqrtf(bn3_v[co] + BN_EPS);
        float b3 = bn3_b[co] - bn3_m[co] * s3;
        s3v[r] = s3;
        pre[r] = tconv_b[co] * s3 + b3;
    }
    #pragma unroll
    for (int nt2 = 0; nt2 < 25; ++nt2) {
        int c0 = nt2 * 16 + r0;
        int tb = c0 / 25, v = c0 - tb * 25;
        #pragma unroll
        for (int r = 0; r < 4; ++r) {
            int co = co_base + g * 4 + r;
            int idx = ((n * 64 + co) * 512 + t0 + tb) * 25 + v;
            float y = acc[nt2][r] * s3v[r] + pre[r] + x[idx];
            out[idx] = fmaxf(y, 0.f);
        }
    }
}

extern "C" void kernel_launch(void* const* d_in, const int* in_sizes, int n_in,
                              void* d_out, int out_size, void* d_ws, size_t ws_size,
                              hipStream_t stream) {
    const float* x       = (const float*)d_in[0];
    const float* A       = (const float*)d_in[1];
    const float* bn1_g   = (const float*)d_in[2];
    const float* bn1_b   = (const float*)d_in[3];
    const float* bn1_m   = (const float*)d_in[4];
    const float* bn1_v   = (const float*)d_in[5];
    const float* pconv_w = (const float*)d_in[6];
    const float* pconv_b = (const float*)d_in[7];
    const float* wq      = (const float*)d_in[8];
    const float* wk      = (const float*)d_in[9];
    const float* wv      = (const float*)d_in[10];
    const float* fc_w    = (const float*)d_in[11];
    const float* ln_g    = (const float*)d_in[12];
    const float* ln_b    = (const float*)d_in[13];
    const float* gate_w  = (const float*)d_in[14];
    const float* bn2_g   = (const float*)d_in[15];
    const float* bn2_b   = (const float*)d_in[16];
    const float* bn2_m   = (const float*)d_in[17];
    const float* bn2_v   = (const float*)d_in[18];
    const float* tconv_w = (const float*)d_in[19];
    const float* tconv_b = (const float*)d_in[20];
    const float* bn3_g   = (const float*)d_in[21];
    const float* bn3_b   = (const float*)d_in[22];
    const float* bn3_m   = (const float*)d_in[23];
    const float* bn3_v   = (const float*)d_in[24];

    char* ws = (char*)d_ws;
    u16*   f_bf = (u16*)ws;
    u16*   akt  = (u16*)(ws + WOFF);
    u16*   wp2  = (u16*)(ws + WOFF + 7680);
    u16*   wqt  = (u16*)(ws + WOFF + 32256);
    u16*   wkt  = (u16*)(ws + WOFF + 40448);
    u16*   wvt  = (u16*)(ws + WOFF + 48640);
    u16*   fct  = (u16*)(ws + WOFF + 56832);
    float* bagg = (float*)(ws + WOFF + 65024);
    u16*   wtc  = (u16*)(ws + WOFF + 71424);
    float* outp = (float*)d_out;

    prep_kernel<<<dim3(64), dim3(256), 0, stream>>>(
        A, pconv_w, pconv_b, wq, wk, wv, fc_w, tconv_w,
        akt, wp2, wqt, wkt, wvt, fct, bagg, wtc);
    scn_kernel<<<dim3(NB * T), dim3(256), 0, stream>>>(
        x, bn1_g, bn1_b, bn1_m, bn1_v, akt, wp2, wqt, wkt, wvt, fct, bagg,
        ln_g, ln_b, gate_w, bn2_g, bn2_b, bn2_m, bn2_v, f_bf);
    tcn_mfma<<<dim3(NB * 32), dim3(256), 0, stream>>>(
        f_bf, x, wtc, tconv_b, bn3_g, bn3_b, bn3_m, bn3_v, outp);
}

// Round 14
// 460.704 us; speedup vs baseline: 21.8214x; 1.2338x over previous
//
#include <hip/hip_runtime.h>

#define NB   32
#define C    64
#define T    512
#define V    25
#define KP   3
#define CO   64
#define H    4
#define BN_EPS 1e-5f
#define LN_EPS 1e-6f

typedef float f32x4 __attribute__((ext_vector_type(4)));
typedef short bf16x8 __attribute__((ext_vector_type(8)));
typedef unsigned short u16;
typedef unsigned int u32;
typedef u32 u32x2 __attribute__((ext_vector_type(2)));
#define MFMA(a,b,c) __builtin_amdgcn_mfma_f32_16x16x32_bf16((a),(b),(c),0,0,0)

__device__ __forceinline__ u16 f2bf(float x) {
    union { float f; unsigned u; } v; v.f = x;
    unsigned r = (v.u + 0x7FFFu + ((v.u >> 16) & 1u)) >> 16;
    return (u16)r;
}
__device__ __forceinline__ float bf2f(u16 h) {
    union { unsigned u; float f; } v; v.u = ((unsigned)h) << 16;
    return v.f;
}

// ---------------------------------------------------------------------------
// ws layout (bytes):
//   [0, 52428800)            f intermediate, bf16, layout [n][t][v][c]
//   WOFF = 52428800: prepped weights (unchanged from R9/R11)
// ---------------------------------------------------------------------------
#define WOFF 52428800ull

__global__ __launch_bounds__(256) void prep_kernel(
    const float* __restrict__ A, const float* __restrict__ pconv_w,
    const float* __restrict__ pconv_b,
    const float* __restrict__ wq, const float* __restrict__ wk,
    const float* __restrict__ wv, const float* __restrict__ fc_w,
    const float* __restrict__ tconv_w,
    u16* __restrict__ akt, u16* __restrict__ wp2,
    u16* __restrict__ wqt, u16* __restrict__ wkt, u16* __restrict__ wvt,
    u16* __restrict__ fct, float* __restrict__ bagg, u16* __restrict__ wtc)
{
    const int stride = gridDim.x * 256;
    for (int i = blockIdx.x * 256 + threadIdx.x; i < 70976; i += stride) {
        if (i < 3840) {                       // AkT
            int k = i / 1280, r = i - k * 1280, w = r / 40, v = r - w * 40;
            float val = (w < V && v < V) ? A[k * V * V + v * V + w] : 0.f;
            akt[i] = f2bf(val);
        } else if (i < 16128) {               // Wp2
            int i2 = i - 3840;
            int c = i2 / 192, kk = i2 - c * 192, k = kk / 64, ci = kk - k * 64;
            wp2[i2] = f2bf(pconv_w[(k * 64 + c) * 64 + ci]);
        } else if (i < 20224) {               // WqT
            int i2 = i - 16128; int j = i2 / 64, c = i2 - j * 64;
            wqt[i2] = f2bf(wq[c * 64 + j]);
        } else if (i < 24320) {               // WkT
            int i2 = i - 20224; int j = i2 / 64, c = i2 - j * 64;
            wkt[i2] = f2bf(wk[c * 64 + j]);
        } else if (i < 28416) {               // WvT
            int i2 = i - 24320; int j = i2 / 64, c = i2 - j * 64;
            wvt[i2] = f2bf(wv[c * 64 + j]);
        } else if (i < 32512) {               // FcT
            int i2 = i - 28416; int c = i2 / 64, d = i2 - c * 64;
            fct[i2] = f2bf(fc_w[d * 64 + c]);
        } else if (i < 34112) {               // bias_agg
            int i2 = i - 32512; int c = i2 / 25, w = i2 - c * 25;
            float s = 0.f;
            for (int k = 0; k < KP; ++k) {
                float cs = 0.f;
                for (int v = 0; v < V; ++v) cs += A[k * V * V + v * V + w];
                s += pconv_b[k * 64 + c] * cs;
            }
            bagg[i2] = s;
        } else {                              // Wtc
            int i2 = i - 34112;
            int co = i2 / 576, rem = i2 - co * 576, dt = rem / 64, ci = rem - dt * 64;
            wtc[i2] = f2bf(tconv_w[(co * 64 + ci) * 9 + dt]);
        }
    }
}

// ---------------------------------------------------------------------------
// scn: R12 structure. R14 delta: LNS/MU/RSTD relocated INTO the Q2 region
// (dead until phase C's q-proj writes it; LNS read at B0, MU/RSTD read at B1,
// both before C). LDS 54344 -> 52544 B: R13's 54784-granule broke 3 blocks/CU
// (54784*3 = 164352 > 163840 -> 2 blocks, occupancy 34->23%, scn 426->521us).
// 52544*3 fits -> 3 blocks/CU restored, keeping all R12 VALU savings.
// ---------------------------------------------------------------------------
#define OFF_INP   0        // f32 [64][25]
#define OFF_INPV  6400     // bf16 [64][40]     (P0 -> A) / XHT (E -> F)
#define OFF_XHT   6400     // bf16 [25][72]
#define OFF_INPT  11520    // bf16 [25][72]     (P0 -> A)
#define OFF_QNT   15120    // bf16 [25][72]     (B1 -> C)
#define OFF_Q2    18720    // bf16 [25][136]    (C -> D1); hosts LNS/MU/RSTD before C
#define OFF_LNS   18720    // f32 [25][8][2]    (A -> B0)
#define OFF_MU    20320    // f32 [25]          (B0 -> B1)
#define OFF_RSTD  20420    // f32 [25]          (B0 -> B1)
#define OFF_K2    25520    // bf16 [25][136]    (A -> D1)
#define OFF_VVTF  32320    // f32  [64][29]     (A -> E)
#define OFF_YT    39744    // bf16 [32][200]    (A -> C) / S f32 [4][25][26]
#define OFF_S     39744
#define LDS_BYTES 52544

#define LDSF(off) ((float*)(s_raw + (off)))
#define LDSH(off) ((u16*)(s_raw + (off)))
#define LDSV8(b)  (*(const bf16x8*)(s_raw + (b)))

__global__ __launch_bounds__(256) void scn_kernel(
    const float* __restrict__ x,
    const float* __restrict__ bn1_g, const float* __restrict__ bn1_b,
    const float* __restrict__ bn1_m, const float* __restrict__ bn1_v,
    const u16* __restrict__ akt, const u16* __restrict__ wp2,
    const u16* __restrict__ wqt, const u16* __restrict__ wkt,
    const u16* __restrict__ wvt, const u16* __restrict__ fct,
    const float* __restrict__ bagg,
    const float* __restrict__ ln_g, const float* __restrict__ ln_b,
    const float* __restrict__ gate_w,
    const float* __restrict__ bn2_g, const float* __restrict__ bn2_b,
    const float* __restrict__ bn2_m, const float* __restrict__ bn2_v,
    u16* __restrict__ f_out)
{
    const int nt   = blockIdx.x;
    const int n    = nt >> 9;
    const int t    = nt & 511;
    const int tid  = threadIdx.x;
    const int lane = tid & 63;
    const int wid  = tid >> 6;
    const int r0   = lane & 15;
    const int g    = lane >> 4;

    __shared__ __align__(16) unsigned char s_raw[LDS_BYTES];

    const float gate = gate_w[0];

    // ---- P0: bn1(x) -> INP f32, INPV bf16 [c][40], INPT bf16 [v][72] ----
    #pragma unroll
    for (int it = 0; it < 7; ++it) {
        int i = tid + it * 256;
        if (i < 1600) {
            int c = i / 25, v = i - c * 25;
            float s1 = bn1_g[c] * rsqrtf(bn1_v[c] + BN_EPS);
            float b1 = bn1_b[c] - bn1_m[c] * s1;
            float f = x[((n * 64 + c) * 512 + t) * 25 + v] * s1 + b1;
            LDSF(OFF_INP)[c * 25 + v] = f;
            u16 hb = f2bf(f);
            LDSH(OFF_INPV)[c * 40 + v] = hb;
            LDSH(OFF_INPT)[v * 72 + c] = hb;
        }
    }
    for (int i = tid; i < 960; i += 256) {     // zero v-pad of INPV (y-GEMM K)
        int c = i / 15, vz = 25 + (i - c * 15);
        LDSH(OFF_INPV)[c * 40 + vz] = 0;
    }
    __syncthreads();

    // ---- Phase A: y-GEMM, k/v projections (MFMA), LN partials ----
    #pragma unroll
    for (int ii = 0; ii < 6; ++ii) {
        int idx = wid * 6 + ii;
        int k = idx >> 3, rem = idx & 7, mt = rem >> 1, ntt = rem & 1;
        bf16x8 a = LDSV8(OFF_INPV + ((mt * 16 + r0) * 40 + g * 8) * 2);
        bf16x8 b = *(const bf16x8*)(&akt[(k * 32 + ntt * 16 + r0) * 40 + g * 8]);
        f32x4 acc = {0.f, 0.f, 0.f, 0.f};
        acc = MFMA(a, b, acc);
        int w = ntt * 16 + r0, cb = mt * 16 + g * 4;
        #pragma unroll
        for (int r = 0; r < 4; ++r)
            LDSH(OFF_YT)[w * 200 + k * 64 + cb + r] = f2bf(acc[r]);
    }
    // k-proj: D[v][j] -> K2[v][jo] bf16
    #pragma unroll
    for (int ii = 0; ii < 2; ++ii) {
        int idx = wid * 2 + ii, mt = idx >> 2, ntt = idx & 3;
        f32x4 acc = {0.f, 0.f, 0.f, 0.f};
        #pragma unroll
        for (int ks = 0; ks < 2; ++ks) {
            bf16x8 a = LDSV8(OFF_INPT + ((mt * 16 + r0) * 72 + ks * 32 + g * 8) * 2);
            bf16x8 b = *(const bf16x8*)(&wkt[(ntt * 16 + r0) * 64 + ks * 32 + g * 8]);
            acc = MFMA(a, b, acc);
        }
        int j = ntt * 16 + r0, jo = (j >> 4) * 32 + (j & 15);
        #pragma unroll
        for (int r = 0; r < 4; ++r) {
            int v = mt * 16 + g * 4 + r;
            if (v < 25) LDSH(OFF_K2)[v * 136 + jo] = f2bf(acc[r]);
        }
    }
    // v-proj: D[v][j] -> VVTF[j][v] f32 (no cvt; E consumes f32)
    #pragma unroll
    for (int ii = 0; ii < 2; ++ii) {
        int idx = wid * 2 + ii, mt = idx >> 2, ntt = idx & 3;
        f32x4 acc = {0.f, 0.f, 0.f, 0.f};
        #pragma unroll
        for (int ks = 0; ks < 2; ++ks) {
            bf16x8 a = LDSV8(OFF_INPT + ((mt * 16 + r0) * 72 + ks * 32 + g * 8) * 2);
            bf16x8 b = *(const bf16x8*)(&wvt[(ntt * 16 + r0) * 64 + ks * 32 + g * 8]);
            acc = MFMA(a, b, acc);
        }
        int j = ntt * 16 + r0;
        #pragma unroll
        for (int r = 0; r < 4; ++r) {
            int v = mt * 16 + g * 4 + r;
            if (v < 25) LDSF(OFF_VVTF)[j * 29 + v] = acc[r];
        }
    }
    // LN partials (into Q2-region scratch)
    if (tid < 200) {
        int v = tid >> 3, p = tid & 7;
        float s1 = 0.f, s2 = 0.f;
        #pragma unroll
        for (int cc = 0; cc < 8; ++cc) {
            float xv = LDSF(OFF_INP)[(p * 8 + cc) * 25 + v];
            s1 += xv; s2 += xv * xv;
        }
        LDSF(OFF_LNS)[(v * 8 + p) * 2]     = s1;
        LDSF(OFF_LNS)[(v * 8 + p) * 2 + 1] = s2;
    }
    __syncthreads();

    // ---- B0: LN reduce ----
    if (tid < 25) {
        float s1 = 0.f, s2 = 0.f;
        #pragma unroll
        for (int p = 0; p < 8; ++p) {
            s1 += LDSF(OFF_LNS)[(tid * 8 + p) * 2];
            s2 += LDSF(OFF_LNS)[(tid * 8 + p) * 2 + 1];
        }
        float mu = s1 * (1.f / 64.f);
        float var = s2 * (1.f / 64.f) - mu * mu;
        LDSF(OFF_MU)[tid]   = mu;
        LDSF(OFF_RSTD)[tid] = rsqrtf(var + LN_EPS);
    }
    __syncthreads();

    // ---- B1: qn = LN(inp) -> QNT [v][72] ----
    #pragma unroll
    for (int it = 0; it < 7; ++it) {
        int i = tid + it * 256;
        if (i < 1600) {
            int v = i >> 6, c = i & 63;
            float f = LDSF(OFF_INP)[c * 25 + v];
            float q = (f - LDSF(OFF_MU)[v]) * LDSF(OFF_RSTD)[v] * ln_g[c] + ln_b[c];
            LDSH(OFF_QNT)[v * 72 + c] = f2bf(q);
        }
    }
    __syncthreads();

    // ---- Phase C: agg-GEMM (K=192 -> REGISTERS) + q projection ----
    f32x4 agg_reg[2];
    #pragma unroll
    for (int ii = 0; ii < 2; ++ii) {
        int idx = wid * 2 + ii, mt = idx >> 1, ntt = idx & 1;
        f32x4 acc = {0.f, 0.f, 0.f, 0.f};
        #pragma unroll
        for (int ks = 0; ks < 6; ++ks) {
            bf16x8 a = *(const bf16x8*)(&wp2[(mt * 16 + r0) * 192 + ks * 32 + g * 8]);
            bf16x8 b = LDSV8(OFF_YT + ((ntt * 16 + r0) * 200 + ks * 32 + g * 8) * 2);
            acc = MFMA(a, b, acc);
        }
        int w = ntt * 16 + r0, cb = mt * 16 + g * 4;
        if (w < 25) {
            #pragma unroll
            for (int r = 0; r < 4; ++r) acc[r] += bagg[(cb + r) * 25 + w];
        }
        agg_reg[ii] = acc;
    }
    #pragma unroll
    for (int ii = 0; ii < 2; ++ii) {            // q-proj -> Q2 bf16
        int idx = wid * 2 + ii, mt = idx >> 2, ntt = idx & 3;
        f32x4 acc = {0.f, 0.f, 0.f, 0.f};
        #pragma unroll
        for (int ks = 0; ks < 2; ++ks) {
            bf16x8 a = LDSV8(OFF_QNT + ((mt * 16 + r0) * 72 + ks * 32 + g * 8) * 2);
            bf16x8 b = *(const bf16x8*)(&wqt[(ntt * 16 + r0) * 64 + ks * 32 + g * 8]);
            acc = MFMA(a, b, acc);
        }
        int j = ntt * 16 + r0, jo = (j >> 4) * 32 + (j & 15);
        #pragma unroll
        for (int r = 0; r < 4; ++r) {
            int v = mt * 16 + g * 4 + r;
            if (v < 25) LDSH(OFF_Q2)[v * 136 + jo] = f2bf(acc[r]);
        }
    }
    __syncthreads();

    // ---- D1 (VALU, R11-validated): S[h][qv][kv] raw dot -> S f32 ----
    if (tid < 100) {
        int h = tid / 25, qv = tid - h * 25;
        float qf[16];
        #pragma unroll
        for (int d = 0; d < 16; ++d)
            qf[d] = bf2f(LDSH(OFF_Q2)[qv * 136 + h * 32 + d]);
        #pragma unroll
        for (int kv = 0; kv < 25; ++kv) {
            float s = 0.f;
            #pragma unroll
            for (int d = 0; d < 16; ++d)
                s += qf[d] * bf2f(LDSH(OFF_K2)[kv * 136 + h * 32 + d]);
            LDSF(OFF_S)[(h * 25 + qv) * 26 + kv] = s;
        }
    }
    __syncthreads();

    // ---- D2: softmax, write normalized P in-place into S (f32) ----
    if (tid < 100) {
        int h = tid / 25, qv = tid - h * 25;
        float* srow = LDSF(OFF_S) + (h * 25 + qv) * 26;
        float row[25]; float mx = -1e30f;
        #pragma unroll
        for (int kv = 0; kv < 25; ++kv) {
            float s = srow[kv] * 0.25f;
            row[kv] = s; mx = fmaxf(mx, s);
        }
        float sum = 0.f;
        #pragma unroll
        for (int kv = 0; kv < 25; ++kv) { float e = __expf(row[kv] - mx); row[kv] = e; sum += e; }
        float inv = 1.f / sum;
        #pragma unroll
        for (int kv = 0; kv < 25; ++kv) srow[kv] = row[kv] * inv;
    }
    __syncthreads();

    // ---- E (VALU f32, no cvts): xh[v][j] = sum_kv P[h][v][kv]*VVTF[j][kv] ----
    #pragma unroll
    for (int it = 0; it < 7; ++it) {
        int i = tid + it * 256;
        if (i < 1600) {
            int v = i >> 6, j = i & 63, h = j >> 4;
            const float* attp = LDSF(OFF_S) + (h * 25 + v) * 26;
            const float* vp   = LDSF(OFF_VVTF) + j * 29;
            float acc = 0.f;
            #pragma unroll
            for (int kv = 0; kv < 25; ++kv)
                acc += attp[kv] * vp[kv];
            LDSH(OFF_XHT)[v * 72 + j] = f2bf(acc);
        }
    }
    __syncthreads();

    // ---- F: fc-GEMM + fused epilogue -> f bf16, layout [n][t][v][c] ----
    #pragma unroll
    for (int ii = 0; ii < 2; ++ii) {
        int idx = wid * 2 + ii, mt = idx >> 1, ntt = idx & 1;
        f32x4 acc = {0.f, 0.f, 0.f, 0.f};
        #pragma unroll
        for (int ks = 0; ks < 2; ++ks) {
            bf16x8 a = *(const bf16x8*)(&fct[(mt * 16 + r0) * 64 + ks * 32 + g * 8]);
            bf16x8 b = LDSV8(OFF_XHT + ((ntt * 16 + r0) * 72 + ks * 32 + g * 8) * 2);
            acc = MFMA(a, b, acc);
        }
        int v = ntt * 16 + r0;
        if (v < 25) {
            int cb = mt * 16 + g * 4;
            u16 hh[4];
            #pragma unroll
            for (int r = 0; r < 4; ++r) {
                int c = cb + r;
                float fa_out = acc[r] + LDSF(OFF_INP)[c * 25 + v];
                float fv = (fa_out * gate + agg_reg[ii][r]) * 0.5f;
                float s2 = bn2_g[c] * rsqrtf(bn2_v[c] + BN_EPS);
                float b2 = bn2_b[c] - bn2_m[c] * s2;
                fv = fmaxf(fv * s2 + b2, 0.f);
                hh[r] = f2bf(fv);
            }
            u32x2 pk;
            pk[0] = (u32)hh[0] | ((u32)hh[1] << 16);
            pk[1] = (u32)hh[2] | ((u32)hh[3] << 16);
            *(u32x2*)&f_out[((n * 512 + t) * 25 + v) * 64 + cb] = pk;
        }
    }
}

// ---------------------------------------------------------------------------
// tcn_mfma: implicit-GEMM temporal conv, vectorized staging (R13-validated,
// ~40us ~= its 44us memory floor). Unchanged.
// ---------------------------------------------------------------------------
#define FB_STRIDE 40

__global__ __launch_bounds__(256) void tcn_mfma(
    const u16* __restrict__ f, const float* __restrict__ x,
    const u16* __restrict__ wtc, const float* __restrict__ tconv_b,
    const float* __restrict__ bn3_g, const float* __restrict__ bn3_b,
    const float* __restrict__ bn3_m, const float* __restrict__ bn3_v,
    float* __restrict__ out)
{
    const int bid  = blockIdx.x;
    const int n    = bid >> 5;
    const int t0   = (bid & 31) * 16;
    const int tid  = threadIdx.x;
    const int lane = tid & 63;
    const int wid  = tid >> 6;
    const int r0   = lane & 15;
    const int g    = lane >> 4;
    const int co_base = wid * 16;

    __shared__ __align__(16) u16 s_fB[24 * 25 * FB_STRIDE];   // 48000 B

    f32x4 acc[25];
    #pragma unroll
    for (int i = 0; i < 25; ++i) acc[i] = (f32x4){0.f, 0.f, 0.f, 0.f};

    for (int ph = 0; ph < 2; ++ph) {
        const int ci0 = ph * 32;
        __syncthreads();
        for (int u = tid; u < 2400; u += 256) {
            int q = u & 3, rv = u >> 2;          // rv = tp*25+v
            int tp = rv / 25, v = rv - tp * 25;
            int tg = t0 + tp - 4;
            bf16x8 val = {0,0,0,0,0,0,0,0};
            if (tg >= 0 && tg < 512)
                val = *(const bf16x8*)&f[((n * 512 + tg) * 25 + v) * 64 + ci0 + q * 8];
            *(bf16x8*)&s_fB[rv * FB_STRIDE + q * 8] = val;
        }
        __syncthreads();

        bf16x8 aF[9];
        #pragma unroll
        for (int dt = 0; dt < 9; ++dt)
            aF[dt] = *(const bf16x8*)(&wtc[((co_base + r0) * 9 + dt) * 64 + ci0 + g * 8]);

        #pragma unroll
        for (int nt2 = 0; nt2 < 25; ++nt2) {
            int c0 = nt2 * 16 + r0;
            int tb = c0 / 25, v = c0 - tb * 25;
            #pragma unroll
            for (int dt = 0; dt < 9; ++dt) {
                bf16x8 bF = *(const bf16x8*)(&s_fB[((tb + dt) * 25 + v) * FB_STRIDE + g * 8]);
                acc[nt2] = MFMA(aF[dt], bF, acc[nt2]);
            }
        }
    }

    float s3v[4], pre[4];
    #pragma unroll
    for (int r = 0; r < 4; ++r) {
        int co = co_base + g * 4 + r;
        float s3 = bn3_g[co] * rsqrtf(bn3_v[co] + BN_EPS);
        float b3 = bn3_b[co] - bn3_m[co] * s3;
        s3v[r] = s3;
        pre[r] = tconv_b[co] * s3 + b3;
    }
    #pragma unroll
    for (int nt2 = 0; nt2 < 25; ++nt2) {
        int c0 = nt2 * 16 + r0;
        int tb = c0 / 25, v = c0 - tb * 25;
        #pragma unroll
        for (int r = 0; r < 4; ++r) {
            int co = co_base + g * 4 + r;
            int idx = ((n * 64 + co) * 512 + t0 + tb) * 25 + v;
            float y = acc[nt2][r] * s3v[r] + pre[r] + x[idx];
            out[idx] = fmaxf(y, 0.f);
        }
    }
}

extern "C" void kernel_launch(void* const* d_in, const int* in_sizes, int n_in,
                              void* d_out, int out_size, void* d_ws, size_t ws_size,
                              hipStream_t stream) {
    const float* x       = (const float*)d_in[0];
    const float* A       = (const float*)d_in[1];
    const float* bn1_g   = (const float*)d_in[2];
    const float* bn1_b   = (const float*)d_in[3];
    const float* bn1_m   = (const float*)d_in[4];
    const float* bn1_v   = (const float*)d_in[5];
    const float* pconv_w = (const float*)d_in[6];
    const float* pconv_b = (const float*)d_in[7];
    const float* wq      = (const float*)d_in[8];
    const float* wk      = (const float*)d_in[9];
    const float* wv      = (const float*)d_in[10];
    const float* fc_w    = (const float*)d_in[11];
    const float* ln_g    = (const float*)d_in[12];
    const float* ln_b    = (const float*)d_in[13];
    const float* gate_w  = (const float*)d_in[14];
    const float* bn2_g   = (const float*)d_in[15];
    const float* bn2_b   = (const float*)d_in[16];
    const float* bn2_m   = (const float*)d_in[17];
    const float* bn2_v   = (const float*)d_in[18];
    const float* tconv_w = (const float*)d_in[19];
    const float* tconv_b = (const float*)d_in[20];
    const float* bn3_g   = (const float*)d_in[21];
    const float* bn3_b   = (const float*)d_in[22];
    const float* bn3_m   = (const float*)d_in[23];
    const float* bn3_v   = (const float*)d_in[24];

    char* ws = (char*)d_ws;
    u16*   f_bf = (u16*)ws;
    u16*   akt  = (u16*)(ws + WOFF);
    u16*   wp2  = (u16*)(ws + WOFF + 7680);
    u16*   wqt  = (u16*)(ws + WOFF + 32256);
    u16*   wkt  = (u16*)(ws + WOFF + 40448);
    u16*   wvt  = (u16*)(ws + WOFF + 48640);
    u16*   fct  = (u16*)(ws + WOFF + 56832);
    float* bagg = (float*)(ws + WOFF + 65024);
    u16*   wtc  = (u16*)(ws + WOFF + 71424);
    float* outp = (float*)d_out;

    prep_kernel<<<dim3(64), dim3(256), 0, stream>>>(
        A, pconv_w, pconv_b, wq, wk, wv, fc_w, tconv_w,
        akt, wp2, wqt, wkt, wvt, fct, bagg, wtc);
    scn_kernel<<<dim3(NB * T), dim3(256), 0, stream>>>(
        x, bn1_g, bn1_b, bn1_m, bn1_v, akt, wp2, wqt, wkt, wvt, fct, bagg,
        ln_g, ln_b, gate_w, bn2_g, bn2_b, bn2_m, bn2_v, f_bf);
    tcn_mfma<<<dim3(NB * 32), dim3(256), 0, stream>>>(
        f_bf, x, wtc, tconv_b, bn3_g, bn3_b, bn3_m, bn3_v, outp);
}

// Round 15
// 399.346 us; speedup vs baseline: 25.1742x; 1.1536x over previous
//
#include <hip/hip_runtime.h>

#define NB   32
#define C    64
#define T    512
#define V    25
#define KP   3
#define CO   64
#define H    4
#define BN_EPS 1e-5f
#define LN_EPS 1e-6f

typedef float f32x4 __attribute__((ext_vector_type(4)));
typedef short bf16x8 __attribute__((ext_vector_type(8)));
typedef unsigned short u16;
typedef unsigned int u32;
typedef u32 u32x2 __attribute__((ext_vector_type(2)));
#define MFMA(a,b,c) __builtin_amdgcn_mfma_f32_16x16x32_bf16((a),(b),(c),0,0,0)

__device__ __forceinline__ u16 f2bf(float x) {
    union { float f; unsigned u; } v; v.f = x;
    unsigned r = (v.u + 0x7FFFu + ((v.u >> 16) & 1u)) >> 16;
    return (u16)r;
}
__device__ __forceinline__ float bf2f(u16 h) {
    union { unsigned u; float f; } v; v.u = ((unsigned)h) << 16;
    return v.f;
}

#define WOFF 52428800ull

__global__ __launch_bounds__(256) void prep_kernel(
    const float* __restrict__ A, const float* __restrict__ pconv_w,
    const float* __restrict__ pconv_b,
    const float* __restrict__ wq, const float* __restrict__ wk,
    const float* __restrict__ wv, const float* __restrict__ fc_w,
    const float* __restrict__ tconv_w,
    u16* __restrict__ akt, u16* __restrict__ wp2,
    u16* __restrict__ wqt, u16* __restrict__ wkt, u16* __restrict__ wvt,
    u16* __restrict__ fct, float* __restrict__ bagg, u16* __restrict__ wtc)
{
    const int stride = gridDim.x * 256;
    for (int i = blockIdx.x * 256 + threadIdx.x; i < 70976; i += stride) {
        if (i < 3840) {                       // AkT
            int k = i / 1280, r = i - k * 1280, w = r / 40, v = r - w * 40;
            float val = (w < V && v < V) ? A[k * V * V + v * V + w] : 0.f;
            akt[i] = f2bf(val);
        } else if (i < 16128) {               // Wp2
            int i2 = i - 3840;
            int c = i2 / 192, kk = i2 - c * 192, k = kk / 64, ci = kk - k * 64;
            wp2[i2] = f2bf(pconv_w[(k * 64 + c) * 64 + ci]);
        } else if (i < 20224) {               // WqT
            int i2 = i - 16128; int j = i2 / 64, c = i2 - j * 64;
            wqt[i2] = f2bf(wq[c * 64 + j]);
        } else if (i < 24320) {               // WkT
            int i2 = i - 20224; int j = i2 / 64, c = i2 - j * 64;
            wkt[i2] = f2bf(wk[c * 64 + j]);
        } else if (i < 28416) {               // WvT
            int i2 = i - 24320; int j = i2 / 64, c = i2 - j * 64;
            wvt[i2] = f2bf(wv[c * 64 + j]);
        } else if (i < 32512) {               // FcT
            int i2 = i - 28416; int c = i2 / 64, d = i2 - c * 64;
            fct[i2] = f2bf(fc_w[d * 64 + c]);
        } else if (i < 34112) {               // bias_agg
            int i2 = i - 32512; int c = i2 / 25, w = i2 - c * 25;
            float s = 0.f;
            for (int k = 0; k < KP; ++k) {
                float cs = 0.f;
                for (int v = 0; v < V; ++v) cs += A[k * V * V + v * V + w];
                s += pconv_b[k * 64 + c] * cs;
            }
            bagg[i2] = s;
        } else {                              // Wtc
            int i2 = i - 34112;
            int co = i2 / 576, rem = i2 - co * 576, dt = rem / 64, ci = rem - dt * 64;
            wtc[i2] = f2bf(tconv_w[(co * 64 + ci) * 9 + dt]);
        }
    }
}

// ---------------------------------------------------------------------------
// scn R15: FULL-MFMA attention restored with the R10 root-cause fixed:
//  * R10's E-MFMA B-operand stride was 36 bf16 = 72 B (NOT 16-aligned) ->
//    misaligned ds_read_b128 -> garbage fragments. All MFMA-read strides are
//    now 16B-aligned: VVT [64][40] (80B), ATT [4][32][40] (80B), Q2/K2 [25][136]
//    (272B = 16*17).
//  * LNS/MU/RSTD moved OUT of Q2 (raw f32 bits = NaN-able bf16 patterns would
//    poison Q2 K-pads under K=32 MFMA) into the 37440..39744 gap.
//  * Q2/K2/VVT zero-filled at P0 (pads exact); D2 zeroes ATT cols 25..31.
//  OOB-row reads in D1/E (A rows 25..31) land in K2/VVT/Q2 regions = finite
//  bf16; their outputs are guarded (qv/kv < 25). LDS 52544 B -> 3 blocks/CU.
// ---------------------------------------------------------------------------
#define OFF_INP   0        // f32 [64][25]
#define OFF_INPV  6400     // bf16 [64][40]  (P0->A)  / XHT bf16 [25][72] (E->F)
#define OFF_XHT   6400
#define OFF_ATT   11520    // bf16 [4][32][40] (D2->E), overlays INPT/QNT (dead)
#define OFF_INPT  11520    // bf16 [25][72]  (P0->A)
#define OFF_QNT   15120    // bf16 [25][72]  (B1->C)
#define OFF_Q2    18720    // bf16 [25][136] (C->D1), pads zeroed at P0
#define OFF_K2    25520    // bf16 [25][136] (A->D1), pads zeroed at P0
#define OFF_VVT   32320    // bf16 [64][40]  (A->E),  pads zeroed at P0
#define OFF_LNS   37440    // f32 [25][8][2] (A->B0)
#define OFF_MU    39040    // f32 [25]       (B0->B1)
#define OFF_RSTD  39140    // f32 [25]       (B0->B1)
#define OFF_YT    39744    // bf16 [32][200] (A->C) / S f32 [4][25][26] (D1->D2)
#define OFF_S     39744
#define LDS_BYTES 52544

#define LDSF(off) ((float*)(s_raw + (off)))
#define LDSH(off) ((u16*)(s_raw + (off)))
#define LDSV8(b)  (*(const bf16x8*)(s_raw + (b)))

__global__ __launch_bounds__(256) void scn_kernel(
    const float* __restrict__ x,
    const float* __restrict__ bn1_g, const float* __restrict__ bn1_b,
    const float* __restrict__ bn1_m, const float* __restrict__ bn1_v,
    const u16* __restrict__ akt, const u16* __restrict__ wp2,
    const u16* __restrict__ wqt, const u16* __restrict__ wkt,
    const u16* __restrict__ wvt, const u16* __restrict__ fct,
    const float* __restrict__ bagg,
    const float* __restrict__ ln_g, const float* __restrict__ ln_b,
    const float* __restrict__ gate_w,
    const float* __restrict__ bn2_g, const float* __restrict__ bn2_b,
    const float* __restrict__ bn2_m, const float* __restrict__ bn2_v,
    u16* __restrict__ f_out)
{
    const int nt   = blockIdx.x;
    const int n    = nt >> 9;
    const int t    = nt & 511;
    const int tid  = threadIdx.x;
    const int lane = tid & 63;
    const int wid  = tid >> 6;
    const int r0   = lane & 15;
    const int g    = lane >> 4;

    __shared__ __align__(16) unsigned char s_raw[LDS_BYTES];

    const float gate = gate_w[0];

    // ---- P0: bn1(x) -> INP f32, INPV bf16 [c][40], INPT bf16 [v][72];
    //      zero INPV v-pads and the whole Q2+K2+VVT span (18720..37440) ----
    #pragma unroll
    for (int it = 0; it < 7; ++it) {
        int i = tid + it * 256;
        if (i < 1600) {
            int c = i / 25, v = i - c * 25;
            float s1 = bn1_g[c] * rsqrtf(bn1_v[c] + BN_EPS);
            float b1 = bn1_b[c] - bn1_m[c] * s1;
            float f = x[((n * 64 + c) * 512 + t) * 25 + v] * s1 + b1;
            LDSF(OFF_INP)[c * 25 + v] = f;
            u16 hb = f2bf(f);
            LDSH(OFF_INPV)[c * 40 + v] = hb;
            LDSH(OFF_INPT)[v * 72 + c] = hb;
        }
    }
    for (int i = tid; i < 960; i += 256) {
        int c = i / 15, vz = 25 + (i - c * 15);
        LDSH(OFF_INPV)[c * 40 + vz] = 0;
    }
    {
        bf16x8 z = {0,0,0,0,0,0,0,0};
        for (int i = tid; i < 1170; i += 256)       // 18720 B = Q2+K2+VVT
            *(bf16x8*)(s_raw + OFF_Q2 + i * 16) = z;
    }
    __syncthreads();

    // ---- Phase A: y-GEMM, k/v projections (MFMA), LN partials ----
    #pragma unroll
    for (int ii = 0; ii < 6; ++ii) {
        int idx = wid * 6 + ii;
        int k = idx >> 3, rem = idx & 7, mt = rem >> 1, ntt = rem & 1;
        bf16x8 a = LDSV8(OFF_INPV + ((mt * 16 + r0) * 40 + g * 8) * 2);
        bf16x8 b = *(const bf16x8*)(&akt[(k * 32 + ntt * 16 + r0) * 40 + g * 8]);
        f32x4 acc = {0.f, 0.f, 0.f, 0.f};
        acc = MFMA(a, b, acc);
        int w = ntt * 16 + r0, cb = mt * 16 + g * 4;
        #pragma unroll
        for (int r = 0; r < 4; ++r)
            LDSH(OFF_YT)[w * 200 + k * 64 + cb + r] = f2bf(acc[r]);
    }
    // k-proj: D[v][j] -> K2[v][jo]
    #pragma unroll
    for (int ii = 0; ii < 2; ++ii) {
        int idx = wid * 2 + ii, mt = idx >> 2, ntt = idx & 3;
        f32x4 acc = {0.f, 0.f, 0.f, 0.f};
        #pragma unroll
        for (int ks = 0; ks < 2; ++ks) {
            bf16x8 a = LDSV8(OFF_INPT + ((mt * 16 + r0) * 72 + ks * 32 + g * 8) * 2);
            bf16x8 b = *(const bf16x8*)(&wkt[(ntt * 16 + r0) * 64 + ks * 32 + g * 8]);
            acc = MFMA(a, b, acc);
        }
        int j = ntt * 16 + r0, jo = (j >> 4) * 32 + (j & 15);
        #pragma unroll
        for (int r = 0; r < 4; ++r) {
            int v = mt * 16 + g * 4 + r;
            if (v < 25) LDSH(OFF_K2)[v * 136 + jo] = f2bf(acc[r]);
        }
    }
    // v-proj: D[v][j] -> VVT[j][v] bf16 (stride 40 -> 80B, 16B-aligned reads)
    #pragma unroll
    for (int ii = 0; ii < 2; ++ii) {
        int idx = wid * 2 + ii, mt = idx >> 2, ntt = idx & 3;
        f32x4 acc = {0.f, 0.f, 0.f, 0.f};
        #pragma unroll
        for (int ks = 0; ks < 2; ++ks) {
            bf16x8 a = LDSV8(OFF_INPT + ((mt * 16 + r0) * 72 + ks * 32 + g * 8) * 2);
            bf16x8 b = *(const bf16x8*)(&wvt[(ntt * 16 + r0) * 64 + ks * 32 + g * 8]);
            acc = MFMA(a, b, acc);
        }
        int j = ntt * 16 + r0;
        #pragma unroll
        for (int r = 0; r < 4; ++r) {
            int v = mt * 16 + g * 4 + r;
            if (v < 25) LDSH(OFF_VVT)[j * 40 + v] = f2bf(acc[r]);
        }
    }
    // LN partials
    if (tid < 200) {
        int v = tid >> 3, p = tid & 7;
        float s1 = 0.f, s2 = 0.f;
        #pragma unroll
        for (int cc = 0; cc < 8; ++cc) {
            float xv = LDSF(OFF_INP)[(p * 8 + cc) * 25 + v];
            s1 += xv; s2 += xv * xv;
        }
        LDSF(OFF_LNS)[(v * 8 + p) * 2]     = s1;
        LDSF(OFF_LNS)[(v * 8 + p) * 2 + 1] = s2;
    }
    __syncthreads();

    // ---- B0: LN reduce ----
    if (tid < 25) {
        float s1 = 0.f, s2 = 0.f;
        #pragma unroll
        for (int p = 0; p < 8; ++p) {
            s1 += LDSF(OFF_LNS)[(tid * 8 + p) * 2];
            s2 += LDSF(OFF_LNS)[(tid * 8 + p) * 2 + 1];
        }
        float mu = s1 * (1.f / 64.f);
        float var = s2 * (1.f / 64.f) - mu * mu;
        LDSF(OFF_MU)[tid]   = mu;
        LDSF(OFF_RSTD)[tid] = rsqrtf(var + LN_EPS);
    }
    __syncthreads();

    // ---- B1: qn = LN(inp) -> QNT [v][72] ----
    #pragma unroll
    for (int it = 0; it < 7; ++it) {
        int i = tid + it * 256;
        if (i < 1600) {
            int v = i >> 6, c = i & 63;
            float f = LDSF(OFF_INP)[c * 25 + v];
            float q = (f - LDSF(OFF_MU)[v]) * LDSF(OFF_RSTD)[v] * ln_g[c] + ln_b[c];
            LDSH(OFF_QNT)[v * 72 + c] = f2bf(q);
        }
    }
    __syncthreads();

    // ---- Phase C: agg-GEMM (K=192 -> REGISTERS) + q projection ----
    f32x4 agg_reg[2];
    #pragma unroll
    for (int ii = 0; ii < 2; ++ii) {
        int idx = wid * 2 + ii, mt = idx >> 1, ntt = idx & 1;
        f32x4 acc = {0.f, 0.f, 0.f, 0.f};
        #pragma unroll
        for (int ks = 0; ks < 6; ++ks) {
            bf16x8 a = *(const bf16x8*)(&wp2[(mt * 16 + r0) * 192 + ks * 32 + g * 8]);
            bf16x8 b = LDSV8(OFF_YT + ((ntt * 16 + r0) * 200 + ks * 32 + g * 8) * 2);
            acc = MFMA(a, b, acc);
        }
        int w = ntt * 16 + r0, cb = mt * 16 + g * 4;
        if (w < 25) {
            #pragma unroll
            for (int r = 0; r < 4; ++r) acc[r] += bagg[(cb + r) * 25 + w];
        }
        agg_reg[ii] = acc;
    }
    #pragma unroll
    for (int ii = 0; ii < 2; ++ii) {            // q-proj -> Q2
        int idx = wid * 2 + ii, mt = idx >> 2, ntt = idx & 3;
        f32x4 acc = {0.f, 0.f, 0.f, 0.f};
        #pragma unroll
        for (int ks = 0; ks < 2; ++ks) {
            bf16x8 a = LDSV8(OFF_QNT + ((mt * 16 + r0) * 72 + ks * 32 + g * 8) * 2);
            bf16x8 b = *(const bf16x8*)(&wqt[(ntt * 16 + r0) * 64 + ks * 32 + g * 8]);
            acc = MFMA(a, b, acc);
        }
        int j = ntt * 16 + r0, jo = (j >> 4) * 32 + (j & 15);
        #pragma unroll
        for (int r = 0; r < 4; ++r) {
            int v = mt * 16 + g * 4 + r;
            if (v < 25) LDSH(OFF_Q2)[v * 136 + jo] = f2bf(acc[r]);
        }
    }
    __syncthreads();

    // ---- D1 (MFMA): S = Q@K^T per head, K=32 (d-pads zero) -> S f32 ----
    #pragma unroll
    for (int ii = 0; ii < 4; ++ii) {
        int idx = wid * 4 + ii;
        int h = idx >> 2, mt = (idx >> 1) & 1, ntc = idx & 1;
        bf16x8 a = LDSV8(OFF_Q2 + ((mt * 16 + r0) * 136 + h * 32 + g * 8) * 2);
        bf16x8 b = LDSV8(OFF_K2 + ((ntc * 16 + r0) * 136 + h * 32 + g * 8) * 2);
        f32x4 acc = {0.f, 0.f, 0.f, 0.f};
        acc = MFMA(a, b, acc);
        int kv = ntc * 16 + r0;
        if (kv < 25) {
            #pragma unroll
            for (int r = 0; r < 4; ++r) {
                int qv = mt * 16 + g * 4 + r;
                if (qv < 25)
                    LDSF(OFF_S)[(h * 25 + qv) * 26 + kv] = acc[r];
            }
        }
    }
    __syncthreads();

    // ---- D2: softmax -> ATT bf16 [4][32][40], zero k-pad cols 25..31 ----
    if (tid < 100) {
        int h = tid / 25, qv = tid - h * 25;
        const float* srow = LDSF(OFF_S) + (h * 25 + qv) * 26;
        float row[25]; float mx = -1e30f;
        #pragma unroll
        for (int kv = 0; kv < 25; ++kv) {
            float s = srow[kv] * 0.25f;
            row[kv] = s; mx = fmaxf(mx, s);
        }
        float sum = 0.f;
        #pragma unroll
        for (int kv = 0; kv < 25; ++kv) { float e = __expf(row[kv] - mx); row[kv] = e; sum += e; }
        float inv = 1.f / sum;
        u16* arow = LDSH(OFF_ATT) + (h * 32 + qv) * 40;
        #pragma unroll
        for (int kv = 0; kv < 25; ++kv) arow[kv] = f2bf(row[kv] * inv);
        #pragma unroll
        for (int kv = 25; kv < 32; ++kv) arow[kv] = 0;
    }
    __syncthreads();

    // ---- E (MFMA): xh = P@V per head, K=32 (ATT cols+VVT pads zero) ----
    #pragma unroll
    for (int ii = 0; ii < 2; ++ii) {
        int idx = wid * 2 + ii, h = idx >> 1, mt = idx & 1;
        bf16x8 a = LDSV8(OFF_ATT + ((h * 32 + mt * 16 + r0) * 40 + g * 8) * 2);
        bf16x8 b = LDSV8(OFF_VVT + ((h * 16 + r0) * 40 + g * 8) * 2);
        f32x4 acc = {0.f, 0.f, 0.f, 0.f};
        acc = MFMA(a, b, acc);
        #pragma unroll
        for (int r = 0; r < 4; ++r) {
            int v = mt * 16 + g * 4 + r;
            if (v < 25)
                LDSH(OFF_XHT)[v * 72 + h * 16 + r0] = f2bf(acc[r]);
        }
    }
    __syncthreads();

    // ---- F: fc-GEMM + fused epilogue -> f bf16, layout [n][t][v][c] ----
    #pragma unroll
    for (int ii = 0; ii < 2; ++ii) {
        int idx = wid * 2 + ii, mt = idx >> 1, ntt = idx & 1;
        f32x4 acc = {0.f, 0.f, 0.f, 0.f};
        #pragma unroll
        for (int ks = 0; ks < 2; ++ks) {
            bf16x8 a = *(const bf16x8*)(&fct[(mt * 16 + r0) * 64 + ks * 32 + g * 8]);
            bf16x8 b = LDSV8(OFF_XHT + ((ntt * 16 + r0) * 72 + ks * 32 + g * 8) * 2);
            acc = MFMA(a, b, acc);
        }
        int v = ntt * 16 + r0;
        if (v < 25) {
            int cb = mt * 16 + g * 4;
            u16 hh[4];
            #pragma unroll
            for (int r = 0; r < 4; ++r) {
                int c = cb + r;
                float fa_out = acc[r] + LDSF(OFF_INP)[c * 25 + v];
                float fv = (fa_out * gate + agg_reg[ii][r]) * 0.5f;
                float s2 = bn2_g[c] * rsqrtf(bn2_v[c] + BN_EPS);
                float b2 = bn2_b[c] - bn2_m[c] * s2;
                fv = fmaxf(fv * s2 + b2, 0.f);
                hh[r] = f2bf(fv);
            }
            u32x2 pk;
            pk[0] = (u32)hh[0] | ((u32)hh[1] << 16);
            pk[1] = (u32)hh[2] | ((u32)hh[3] << 16);
            *(u32x2*)&f_out[((n * 512 + t) * 25 + v) * 64 + cb] = pk;
        }
    }
}

// ---------------------------------------------------------------------------
// tcn_mfma: implicit-GEMM temporal conv, vectorized staging (R13-validated,
// ~40us ~= memory floor). Unchanged.
// ---------------------------------------------------------------------------
#define FB_STRIDE 40

__global__ __launch_bounds__(256) void tcn_mfma(
    const u16* __restrict__ f, const float* __restrict__ x,
    const u16* __restrict__ wtc, const float* __restrict__ tconv_b,
    const float* __restrict__ bn3_g, const float* __restrict__ bn3_b,
    const float* __restrict__ bn3_m, const float* __restrict__ bn3_v,
    float* __restrict__ out)
{
    const int bid  = blockIdx.x;
    const int n    = bid >> 5;
    const int t0   = (bid & 31) * 16;
    const int tid  = threadIdx.x;
    const int lane = tid & 63;
    const int wid  = tid >> 6;
    const int r0   = lane & 15;
    const int g    = lane >> 4;
    const int co_base = wid * 16;

    __shared__ __align__(16) u16 s_fB[24 * 25 * FB_STRIDE];   // 48000 B

    f32x4 acc[25];
    #pragma unroll
    for (int i = 0; i < 25; ++i) acc[i] = (f32x4){0.f, 0.f, 0.f, 0.f};

    for (int ph = 0; ph < 2; ++ph) {
        const int ci0 = ph * 32;
        __syncthreads();
        for (int u = tid; u < 2400; u += 256) {
            int q = u & 3, rv = u >> 2;          // rv = tp*25+v
            int tp = rv / 25, v = rv - tp * 25;
            int tg = t0 + tp - 4;
            bf16x8 val = {0,0,0,0,0,0,0,0};
            if (tg >= 0 && tg < 512)
                val = *(const bf16x8*)&f[((n * 512 + tg) * 25 + v) * 64 + ci0 + q * 8];
            *(bf16x8*)&s_fB[rv * FB_STRIDE + q * 8] = val;
        }
        __syncthreads();

        bf16x8 aF[9];
        #pragma unroll
        for (int dt = 0; dt < 9; ++dt)
            aF[dt] = *(const bf16x8*)(&wtc[((co_base + r0) * 9 + dt) * 64 + ci0 + g * 8]);

        #pragma unroll
        for (int nt2 = 0; nt2 < 25; ++nt2) {
            int c0 = nt2 * 16 + r0;
            int tb = c0 / 25, v = c0 - tb * 25;
            #pragma unroll
            for (int dt = 0; dt < 9; ++dt) {
                bf16x8 bF = *(const bf16x8*)(&s_fB[((tb + dt) * 25 + v) * FB_STRIDE + g * 8]);
                acc[nt2] = MFMA(aF[dt], bF, acc[nt2]);
            }
        }
    }

    float s3v[4], pre[4];
    #pragma unroll
    for (int r = 0; r < 4; ++r) {
        int co = co_base + g * 4 + r;
        float s3 = bn3_g[co] * rsqrtf(bn3_v[co] + BN_EPS);
        float b3 = bn3_b[co] - bn3_m[co] * s3;
        s3v[r] = s3;
        pre[r] = tconv_b[co] * s3 + b3;
    }
    #pragma unroll
    for (int nt2 = 0; nt2 < 25; ++nt2) {
        int c0 = nt2 * 16 + r0;
        int tb = c0 / 25, v = c0 - tb * 25;
        #pragma unroll
        for (int r = 0; r < 4; ++r) {
            int co = co_base + g * 4 + r;
            int idx = ((n * 64 + co) * 512 + t0 + tb) * 25 + v;
            float y = acc[nt2][r] * s3v[r] + pre[r] + x[idx];
            out[idx] = fmaxf(y, 0.f);
        }
    }
}

extern "C" void kernel_launch(void* const* d_in, const int* in_sizes, int n_in,
                              void* d_out, int out_size, void* d_ws, size_t ws_size,
                              hipStream_t stream) {
    const float* x       = (const float*)d_in[0];
    const float* A       = (const float*)d_in[1];
    const float* bn1_g   = (const float*)d_in[2];
    const float* bn1_b   = (const float*)d_in[3];
    const float* bn1_m   = (const float*)d_in[4];
    const float* bn1_v   = (const float*)d_in[5];
    const float* pconv_w = (const float*)d_in[6];
    const float* pconv_b = (const float*)d_in[7];
    const float* wq      = (const float*)d_in[8];
    const float* wk      = (const float*)d_in[9];
    const float* wv      = (const float*)d_in[10];
    const float* fc_w    = (const float*)d_in[11];
    const float* ln_g    = (const float*)d_in[12];
    const float* ln_b    = (const float*)d_in[13];
    const float* gate_w  = (const float*)d_in[14];
    const float* bn2_g   = (const float*)d_in[15];
    const float* bn2_b   = (const float*)d_in[16];
    const float* bn2_m   = (const float*)d_in[17];
    const float* bn2_v   = (const float*)d_in[18];
    const float* tconv_w = (const float*)d_in[19];
    const float* tconv_b = (const float*)d_in[20];
    const float* bn3_g   = (const float*)d_in[21];
    const float* bn3_b   = (const float*)d_in[22];
    const float* bn3_m   = (const float*)d_in[23];
    const float* bn3_v   = (const float*)d_in[24];

    char* ws = (char*)d_ws;
    u16*   f_bf = (u16*)ws;
    u16*   akt  = (u16*)(ws + WOFF);
    u16*   wp2  = (u16*)(ws + WOFF + 7680);
    u16*   wqt  = (u16*)(ws + WOFF + 32256);
    u16*   wkt  = (u16*)(ws + WOFF + 40448);
    u16*   wvt  = (u16*)(ws + WOFF + 48640);
    u16*   fct  = (u16*)(ws + WOFF + 56832);
    float* bagg = (float*)(ws + WOFF + 65024);
    u16*   wtc  = (u16*)(ws + WOFF + 71424);
    float* outp = (float*)d_out;

    prep_kernel<<<dim3(64), dim3(256), 0, stream>>>(
        A, pconv_w, pconv_b, wq, wk, wv, fc_w, tconv_w,
        akt, wp2, wqt, wkt, wvt, fct, bagg, wtc);
    scn_kernel<<<dim3(NB * T), dim3(256), 0, stream>>>(
        x, bn1_g, bn1_b, bn1_m, bn1_v, akt, wp2, wqt, wkt, wvt, fct, bagg,
        ln_g, ln_b, gate_w, bn2_g, bn2_b, bn2_m, bn2_v, f_bf);
    tcn_mfma<<<dim3(NB * 32), dim3(256), 0, stream>>>(
        f_bf, x, wtc, tconv_b, bn3_g, bn3_b, bn3_m, bn3_v, outp);
}

// Round 18
// 364.795 us; speedup vs baseline: 27.5585x; 1.0947x over previous
//
#include <hip/hip_runtime.h>

#define NB   32
#define C    64
#define T    512
#define V    25
#define KP   3
#define CO   64
#define H    4
#define BN_EPS 1e-5f
#define LN_EPS 1e-6f

typedef float f32x4 __attribute__((ext_vector_type(4)));
typedef short bf16x8 __attribute__((ext_vector_type(8)));
typedef unsigned short u16;
typedef unsigned int u32;
typedef u32 u32x2 __attribute__((ext_vector_type(2)));
#define MFMA(a,b,c) __builtin_amdgcn_mfma_f32_16x16x32_bf16((a),(b),(c),0,0,0)

__device__ __forceinline__ u16 f2bf(float x) {
    union { float f; unsigned u; } v; v.f = x;
    unsigned r = (v.u + 0x7FFFu + ((v.u >> 16) & 1u)) >> 16;
    return (u16)r;
}
__device__ __forceinline__ float bf2f(u16 h) {
    union { unsigned u; float f; } v; v.u = ((unsigned)h) << 16;
    return v.f;
}

#define WOFF 52428800ull

// prep: adds (vs R15) ln_g-scaled wqt, and u[j]=sum_c g*wq, w0[j]=sum_c b*wq
__global__ __launch_bounds__(256) void prep_kernel(
    const float* __restrict__ A, const float* __restrict__ pconv_w,
    const float* __restrict__ pconv_b,
    const float* __restrict__ wq, const float* __restrict__ wk,
    const float* __restrict__ wv, const float* __restrict__ fc_w,
    const float* __restrict__ tconv_w,
    const float* __restrict__ ln_g, const float* __restrict__ ln_b,
    u16* __restrict__ akt, u16* __restrict__ wp2,
    u16* __restrict__ wqt, u16* __restrict__ wkt, u16* __restrict__ wvt,
    u16* __restrict__ fct, float* __restrict__ bagg, u16* __restrict__ wtc,
    float* __restrict__ uvec, float* __restrict__ w0vec)
{
    const int stride = gridDim.x * 256;
    for (int i = blockIdx.x * 256 + threadIdx.x; i < 71104; i += stride) {
        if (i < 3840) {                       // AkT
            int k = i / 1280, r = i - k * 1280, w = r / 40, v = r - w * 40;
            float val = (w < V && v < V) ? A[k * V * V + v * V + w] : 0.f;
            akt[i] = f2bf(val);
        } else if (i < 16128) {               // Wp2
            int i2 = i - 3840;
            int c = i2 / 192, kk = i2 - c * 192, k = kk / 64, ci = kk - k * 64;
            wp2[i2] = f2bf(pconv_w[(k * 64 + c) * 64 + ci]);
        } else if (i < 20224) {               // WqT (ln_g-scaled)
            int i2 = i - 16128; int j = i2 / 64, c = i2 - j * 64;
            wqt[i2] = f2bf(wq[c * 64 + j] * ln_g[c]);
        } else if (i < 24320) {               // WkT
            int i2 = i - 20224; int j = i2 / 64, c = i2 - j * 64;
            wkt[i2] = f2bf(wk[c * 64 + j]);
        } else if (i < 28416) {               // WvT
            int i2 = i - 24320; int j = i2 / 64, c = i2 - j * 64;
            wvt[i2] = f2bf(wv[c * 64 + j]);
        } else if (i < 32512) {               // FcT
            int i2 = i - 28416; int c = i2 / 64, d = i2 - c * 64;
            fct[i2] = f2bf(fc_w[d * 64 + c]);
        } else if (i < 34112) {               // bias_agg
            int i2 = i - 32512; int c = i2 / 25, w = i2 - c * 25;
            float s = 0.f;
            for (int k = 0; k < KP; ++k) {
                float cs = 0.f;
                for (int v = 0; v < V; ++v) cs += A[k * V * V + v * V + w];
                s += pconv_b[k * 64 + c] * cs;
            }
            bagg[i2] = s;
        } else if (i < 70976) {               // Wtc
            int i2 = i - 34112;
            int co = i2 / 576, rem = i2 - co * 576, dt = rem / 64, ci = rem - dt * 64;
            wtc[i2] = f2bf(tconv_w[(co * 64 + ci) * 9 + dt]);
        } else if (i < 71040) {               // uvec[j]
            int j = i - 70976; float s = 0.f;
            for (int c = 0; c < 64; ++c) s += ln_g[c] * wq[c * 64 + j];
            uvec[j] = s;
        } else {                              // w0vec[j]
            int j = i - 71040; float s = 0.f;
            for (int c = 0; c < 64; ++c) s += ln_b[c] * wq[c * 64 + j];
            w0vec[j] = s;
        }
    }
}

// ---------------------------------------------------------------------------
// scn R16: LDS squeezed 52544 -> 39640 B => 4 blocks/CU (R15: 3, 57% idle).
//  * f32 INP dropped: LN stats / residual read INPT bf16.
//  * LN folded into q-proj: q = rstd*(inp @ (g.*wq)) - rstd*mu*u + w0.
//    q-proj moves to Phase A (A-operand INPT, like k/v); QNT + B1 deleted;
//    1600-elem affine fixup merged into C's barrier interval.
//  * YT trimmed to 25 rows (B-reads row-clamped to 24, outputs guarded).
//  * ATT overlays Q2+K2-head (dead after D1); XHT overlays INPV.
//  All MFMA-read strides 16B-aligned (R15 root-cause rule).
// ---------------------------------------------------------------------------
#define OFF_INPV  0        // bf16 [64][40] (P0->A)  / XHT bf16 [25][72] (E->F)
#define OFF_XHT   0
#define OFF_INPT  5120     // bf16 [25][72] (P0->F: LN src + residual)
#define OFF_Q2    8720     // bf16 [25][136] (A raw -> fixup -> D1)
#define OFF_ATT   8720     // bf16 [4][32][40] (D2->E) overlays Q2+K2 head
#define OFF_K2    15520    // bf16 [25][136] (A->D1)
#define OFF_VVT   22320    // bf16 [64][40]  (A->E)
#define OFF_LNS   27440    // f32 [25][8][2] (A->B0)
#define OFF_MU    29040    // f32 [25]       (B0->fixup)
#define OFF_RSTD  29140    // f32 [25]       (B0->fixup)
#define OFF_YT    29240    // bf16 [25][200] (A->C) / S f32 [4][25][26] (D1->D2)
#define OFF_S     29240
#define LDS_BYTES 39640

#define LDSF(off) ((float*)(s_raw + (off)))
#define LDSH(off) ((u16*)(s_raw + (off)))
#define LDSV8(b)  (*(const bf16x8*)(s_raw + (b)))

__global__ __launch_bounds__(256) void scn_kernel(
    const float* __restrict__ x,
    const float* __restrict__ bn1_g, const float* __restrict__ bn1_b,
    const float* __restrict__ bn1_m, const float* __restrict__ bn1_v,
    const u16* __restrict__ akt, const u16* __restrict__ wp2,
    const u16* __restrict__ wqt, const u16* __restrict__ wkt,
    const u16* __restrict__ wvt, const u16* __restrict__ fct,
    const float* __restrict__ bagg,
    const float* __restrict__ uvec, const float* __restrict__ w0vec,
    const float* __restrict__ gate_w,
    const float* __restrict__ bn2_g, const float* __restrict__ bn2_b,
    const float* __restrict__ bn2_m, const float* __restrict__ bn2_v,
    u16* __restrict__ f_out)
{
    const int nt   = blockIdx.x;
    const int n    = nt >> 9;
    const int t    = nt & 511;
    const int tid  = threadIdx.x;
    const int lane = tid & 63;
    const int wid  = tid >> 6;
    const int r0   = lane & 15;
    const int g    = lane >> 4;

    __shared__ __align__(16) unsigned char s_raw[LDS_BYTES];

    const float gate = gate_w[0];

    // ---- P0: bn1(x) -> INPV bf16 [c][40], INPT bf16 [v][72];
    //      zero INPV v-pads and Q2+K2+VVT span (8720..27440) ----
    #pragma unroll
    for (int it = 0; it < 7; ++it) {
        int i = tid + it * 256;
        if (i < 1600) {
            int c = i / 25, v = i - c * 25;
            float s1 = bn1_g[c] * rsqrtf(bn1_v[c] + BN_EPS);
            float b1 = bn1_b[c] - bn1_m[c] * s1;
            float f = x[((n * 64 + c) * 512 + t) * 25 + v] * s1 + b1;
            u16 hb = f2bf(f);
            LDSH(OFF_INPV)[c * 40 + v] = hb;
            LDSH(OFF_INPT)[v * 72 + c] = hb;
        }
    }
    for (int i = tid; i < 960; i += 256) {
        int c = i / 15, vz = 25 + (i - c * 15);
        LDSH(OFF_INPV)[c * 40 + vz] = 0;
    }
    {
        bf16x8 z = {0,0,0,0,0,0,0,0};
        for (int i = tid; i < 1170; i += 256)
            *(bf16x8*)(s_raw + OFF_Q2 + i * 16) = z;
    }
    __syncthreads();

    // ---- Phase A: y-GEMM, k/v/q projections (MFMA), LN partials ----
    #pragma unroll
    for (int ii = 0; ii < 6; ++ii) {
        int idx = wid * 6 + ii;
        int k = idx >> 3, rem = idx & 7, mt = rem >> 1, ntt = rem & 1;
        bf16x8 a = LDSV8(OFF_INPV + ((mt * 16 + r0) * 40 + g * 8) * 2);
        bf16x8 b = *(const bf16x8*)(&akt[(k * 32 + ntt * 16 + r0) * 40 + g * 8]);
        f32x4 acc = {0.f, 0.f, 0.f, 0.f};
        acc = MFMA(a, b, acc);
        int w = ntt * 16 + r0, cb = mt * 16 + g * 4;
        if (w < 25) {
            #pragma unroll
            for (int r = 0; r < 4; ++r)
                LDSH(OFF_YT)[w * 200 + k * 64 + cb + r] = f2bf(acc[r]);
        }
    }
    // k-proj -> K2[v][jo]
    #pragma unroll
    for (int ii = 0; ii < 2; ++ii) {
        int idx = wid * 2 + ii, mt = idx >> 2, ntt = idx & 3;
        f32x4 acc = {0.f, 0.f, 0.f, 0.f};
        #pragma unroll
        for (int ks = 0; ks < 2; ++ks) {
            bf16x8 a = LDSV8(OFF_INPT + ((mt * 16 + r0) * 72 + ks * 32 + g * 8) * 2);
            bf16x8 b = *(const bf16x8*)(&wkt[(ntt * 16 + r0) * 64 + ks * 32 + g * 8]);
            acc = MFMA(a, b, acc);
        }
        int j = ntt * 16 + r0, jo = (j >> 4) * 32 + (j & 15);
        #pragma unroll
        for (int r = 0; r < 4; ++r) {
            int v = mt * 16 + g * 4 + r;
            if (v < 25) LDSH(OFF_K2)[v * 136 + jo] = f2bf(acc[r]);
        }
    }
    // v-proj -> VVT[j][v]
    #pragma unroll
    for (int ii = 0; ii < 2; ++ii) {
        int idx = wid * 2 + ii, mt = idx >> 2, ntt = idx & 3;
        f32x4 acc = {0.f, 0.f, 0.f, 0.f};
        #pragma unroll
        for (int ks = 0; ks < 2; ++ks) {
            bf16x8 a = LDSV8(OFF_INPT + ((mt * 16 + r0) * 72 + ks * 32 + g * 8) * 2);
            bf16x8 b = *(const bf16x8*)(&wvt[(ntt * 16 + r0) * 64 + ks * 32 + g * 8]);
            acc = MFMA(a, b, acc);
        }
        int j = ntt * 16 + r0;
        #pragma unroll
        for (int r = 0; r < 4; ++r) {
            int v = mt * 16 + g * 4 + r;
            if (v < 25) LDSH(OFF_VVT)[j * 40 + v] = f2bf(acc[r]);
        }
    }
    // q-proj (raw, g-scaled weights) -> Q2[v][jo]
    #pragma unroll
    for (int ii = 0; ii < 2; ++ii) {
        int idx = wid * 2 + ii, mt = idx >> 2, ntt = idx & 3;
        f32x4 acc = {0.f, 0.f, 0.f, 0.f};
        #pragma unroll
        for (int ks = 0; ks < 2; ++ks) {
            bf16x8 a = LDSV8(OFF_INPT + ((mt * 16 + r0) * 72 + ks * 32 + g * 8) * 2);
            bf16x8 b = *(const bf16x8*)(&wqt[(ntt * 16 + r0) * 64 + ks * 32 + g * 8]);
            acc = MFMA(a, b, acc);
        }
        int j = ntt * 16 + r0, jo = (j >> 4) * 32 + (j & 15);
        #pragma unroll
        for (int r = 0; r < 4; ++r) {
            int v = mt * 16 + g * 4 + r;
            if (v < 25) LDSH(OFF_Q2)[v * 136 + jo] = f2bf(acc[r]);
        }
    }
    // LN partials (from INPT bf16)
    if (tid < 200) {
        int v = tid >> 3, p = tid & 7;
        const u16* row = LDSH(OFF_INPT) + v * 72 + p * 8;
        float s1 = 0.f, s2 = 0.f;
        #pragma unroll
        for (int cc = 0; cc < 8; ++cc) {
            float xv = bf2f(row[cc]);
            s1 += xv; s2 += xv * xv;
        }
        LDSF(OFF_LNS)[(v * 8 + p) * 2]     = s1;
        LDSF(OFF_LNS)[(v * 8 + p) * 2 + 1] = s2;
    }
    __syncthreads();

    // ---- B0: LN reduce ----
    if (tid < 25) {
        float s1 = 0.f, s2 = 0.f;
        #pragma unroll
        for (int p = 0; p < 8; ++p) {
            s1 += LDSF(OFF_LNS)[(tid * 8 + p) * 2];
            s2 += LDSF(OFF_LNS)[(tid * 8 + p) * 2 + 1];
        }
        float mu = s1 * (1.f / 64.f);
        float var = s2 * (1.f / 64.f) - mu * mu;
        LDSF(OFF_MU)[tid]   = mu;
        LDSF(OFF_RSTD)[tid] = rsqrtf(var + LN_EPS);
    }
    __syncthreads();

    // ---- B1C: Q2 LN-fixup (q = rstd*raw - rstd*mu*u + w0) + agg-GEMM ----
    #pragma unroll
    for (int it = 0; it < 7; ++it) {
        int i = tid + it * 256;
        if (i < 1600) {
            int v = i >> 6, j = i & 63;
            int jo = (j >> 4) * 32 + (j & 15);
            float raw = bf2f(LDSH(OFF_Q2)[v * 136 + jo]);
            float rs = LDSF(OFF_RSTD)[v], m = LDSF(OFF_MU)[v];
            LDSH(OFF_Q2)[v * 136 + jo] =
                f2bf(rs * raw - rs * m * uvec[j] + w0vec[j]);
        }
    }
    f32x4 agg_reg[2];
    #pragma unroll
    for (int ii = 0; ii < 2; ++ii) {
        int idx = wid * 2 + ii, mt = idx >> 1, ntt = idx & 1;
        f32x4 acc = {0.f, 0.f, 0.f, 0.f};
        #pragma unroll
        for (int ks = 0; ks < 6; ++ks) {
            bf16x8 a = *(const bf16x8*)(&wp2[(mt * 16 + r0) * 192 + ks * 32 + g * 8]);
            int brow = ntt * 16 + r0; if (brow > 24) brow = 24;   // YT row clamp
            bf16x8 b = LDSV8(OFF_YT + (brow * 200 + ks * 32 + g * 8) * 2);
            acc = MFMA(a, b, acc);
        }
        int w = ntt * 16 + r0, cb = mt * 16 + g * 4;
        if (w < 25) {
            #pragma unroll
            for (int r = 0; r < 4; ++r) acc[r] += bagg[(cb + r) * 25 + w];
        }
        agg_reg[ii] = acc;
    }
    __syncthreads();

    // ---- D1 (MFMA): S = Q@K^T per head, K=32 (pads zero) -> S f32 ----
    #pragma unroll
    for (int ii = 0; ii < 4; ++ii) {
        int idx = wid * 4 + ii;
        int h = idx >> 2, mt = (idx >> 1) & 1, ntc = idx & 1;
        bf16x8 a = LDSV8(OFF_Q2 + ((mt * 16 + r0) * 136 + h * 32 + g * 8) * 2);
        bf16x8 b = LDSV8(OFF_K2 + ((ntc * 16 + r0) * 136 + h * 32 + g * 8) * 2);
        f32x4 acc = {0.f, 0.f, 0.f, 0.f};
        acc = MFMA(a, b, acc);
        int kv = ntc * 16 + r0;
        if (kv < 25) {
            #pragma unroll
            for (int r = 0; r < 4; ++r) {
                int qv = mt * 16 + g * 4 + r;
                if (qv < 25)
                    LDSF(OFF_S)[(h * 25 + qv) * 26 + kv] = acc[r];
            }
        }
    }
    __syncthreads();

    // ---- D2: softmax -> ATT bf16 [4][32][40], zero k-pad cols ----
    if (tid < 100) {
        int h = tid / 25, qv = tid - h * 25;
        const float* srow = LDSF(OFF_S) + (h * 25 + qv) * 26;
        float row[25]; float mx = -1e30f;
        #pragma unroll
        for (int kv = 0; kv < 25; ++kv) {
            float s = srow[kv] * 0.25f;
            row[kv] = s; mx = fmaxf(mx, s);
        }
        float sum = 0.f;
        #pragma unroll
        for (int kv = 0; kv < 25; ++kv) { float e = __expf(row[kv] - mx); row[kv] = e; sum += e; }
        float inv = 1.f / sum;
        u16* arow = LDSH(OFF_ATT) + (h * 32 + qv) * 40;
        #pragma unroll
        for (int kv = 0; kv < 25; ++kv) arow[kv] = f2bf(row[kv] * inv);
        #pragma unroll
        for (int kv = 25; kv < 32; ++kv) arow[kv] = 0;
    }
    __syncthreads();

    // ---- E (MFMA): xh = P@V per head -> XHT ----
    #pragma unroll
    for (int ii = 0; ii < 2; ++ii) {
        int idx = wid * 2 + ii, h = idx >> 1, mt = idx & 1;
        bf16x8 a = LDSV8(OFF_ATT + ((h * 32 + mt * 16 + r0) * 40 + g * 8) * 2);
        bf16x8 b = LDSV8(OFF_VVT + ((h * 16 + r0) * 40 + g * 8) * 2);
        f32x4 acc = {0.f, 0.f, 0.f, 0.f};
        acc = MFMA(a, b, acc);
        #pragma unroll
        for (int r = 0; r < 4; ++r) {
            int v = mt * 16 + g * 4 + r;
            if (v < 25)
                LDSH(OFF_XHT)[v * 72 + h * 16 + r0] = f2bf(acc[r]);
        }
    }
    __syncthreads();

    // ---- F: fc-GEMM + fused epilogue (residual from INPT) -> f bf16 ----
    #pragma unroll
    for (int ii = 0; ii < 2; ++ii) {
        int idx = wid * 2 + ii, mt = idx >> 1, ntt = idx & 1;
        f32x4 acc = {0.f, 0.f, 0.f, 0.f};
        #pragma unroll
        for (int ks = 0; ks < 2; ++ks) {
            bf16x8 a = *(const bf16x8*)(&fct[(mt * 16 + r0) * 64 + ks * 32 + g * 8]);
            bf16x8 b = LDSV8(OFF_XHT + ((ntt * 16 + r0) * 72 + ks * 32 + g * 8) * 2);
            acc = MFMA(a, b, acc);
        }
        int v = ntt * 16 + r0;
        if (v < 25) {
            int cb = mt * 16 + g * 4;
            u16 hh[4];
            #pragma unroll
            for (int r = 0; r < 4; ++r) {
                int c = cb + r;
                float fa_out = acc[r] + bf2f(LDSH(OFF_INPT)[v * 72 + c]);
                float fv = (fa_out * gate + agg_reg[ii][r]) * 0.5f;
                float s2 = bn2_g[c] * rsqrtf(bn2_v[c] + BN_EPS);
                float b2 = bn2_b[c] - bn2_m[c] * s2;
                fv = fmaxf(fv * s2 + b2, 0.f);
                hh[r] = f2bf(fv);
            }
            u32x2 pk;
            pk[0] = (u32)hh[0] | ((u32)hh[1] << 16);
            pk[1] = (u32)hh[2] | ((u32)hh[3] << 16);
            *(u32x2*)&f_out[((n * 512 + t) * 25 + v) * 64 + cb] = pk;
        }
    }
}

// ---------------------------------------------------------------------------
// tcn_mfma: implicit-GEMM temporal conv, vectorized staging (R13-validated,
// ~40us ~= memory floor). Unchanged.
// ---------------------------------------------------------------------------
#define FB_STRIDE 40

__global__ __launch_bounds__(256) void tcn_mfma(
    const u16* __restrict__ f, const float* __restrict__ x,
    const u16* __restrict__ wtc, const float* __restrict__ tconv_b,
    const float* __restrict__ bn3_g, const float* __restrict__ bn3_b,
    const float* __restrict__ bn3_m, const float* __restrict__ bn3_v,
    float* __restrict__ out)
{
    const int bid  = blockIdx.x;
    const int n    = bid >> 5;
    const int t0   = (bid & 31) * 16;
    const int tid  = threadIdx.x;
    const int lane = tid & 63;
    const int wid  = tid >> 6;
    const int r0   = lane & 15;
    const int g    = lane >> 4;
    const int co_base = wid * 16;

    __shared__ __align__(16) u16 s_fB[24 * 25 * FB_STRIDE];   // 48000 B

    f32x4 acc[25];
    #pragma unroll
    for (int i = 0; i < 25; ++i) acc[i] = (f32x4){0.f, 0.f, 0.f, 0.f};

    for (int ph = 0; ph < 2; ++ph) {
        const int ci0 = ph * 32;
        __syncthreads();
        for (int u = tid; u < 2400; u += 256) {
            int q = u & 3, rv = u >> 2;          // rv = tp*25+v
            int tp = rv / 25, v = rv - tp * 25;
            int tg = t0 + tp - 4;
            bf16x8 val = {0,0,0,0,0,0,0,0};
            if (tg >= 0 && tg < 512)
                val = *(const bf16x8*)&f[((n * 512 + tg) * 25 + v) * 64 + ci0 + q * 8];
            *(bf16x8*)&s_fB[rv * FB_STRIDE + q * 8] = val;
        }
        __syncthreads();

        bf16x8 aF[9];
        #pragma unroll
        for (int dt = 0; dt < 9; ++dt)
            aF[dt] = *(const bf16x8*)(&wtc[((co_base + r0) * 9 + dt) * 64 + ci0 + g * 8]);

        #pragma unroll
        for (int nt2 = 0; nt2 < 25; ++nt2) {
            int c0 = nt2 * 16 + r0;
            int tb = c0 / 25, v = c0 - tb * 25;
            #pragma unroll
            for (int dt = 0; dt < 9; ++dt) {
                bf16x8 bF = *(const bf16x8*)(&s_fB[((tb + dt) * 25 + v) * FB_STRIDE + g * 8]);
                acc[nt2] = MFMA(aF[dt], bF, acc[nt2]);
            }
        }
    }

    float s3v[4], pre[4];
    #pragma unroll
    for (int r = 0; r < 4; ++r) {
        int co = co_base + g * 4 + r;
        float s3 = bn3_g[co] * rsqrtf(bn3_v[co] + BN_EPS);
        float b3 = bn3_b[co] - bn3_m[co] * s3;
        s3v[r] = s3;
        pre[r] = tconv_b[co] * s3 + b3;
    }
    #pragma unroll
    for (int nt2 = 0; nt2 < 25; ++nt2) {
        int c0 = nt2 * 16 + r0;
        int tb = c0 / 25, v = c0 - tb * 25;
        #pragma unroll
        for (int r = 0; r < 4; ++r) {
            int co = co_base + g * 4 + r;
            int idx = ((n * 64 + co) * 512 + t0 + tb) * 25 + v;
            float y = acc[nt2][r] * s3v[r] + pre[r] + x[idx];
            out[idx] = fmaxf(y, 0.f);
        }
    }
}

extern "C" void kernel_launch(void* const* d_in, const int* in_sizes, int n_in,
                              void* d_out, int out_size, void* d_ws, size_t ws_size,
                              hipStream_t stream) {
    const float* x       = (const float*)d_in[0];
    const float* A       = (const float*)d_in[1];
    const float* bn1_g   = (const float*)d_in[2];
    const float* bn1_b   = (const float*)d_in[3];
    const float* bn1_m   = (const float*)d_in[4];
    const float* bn1_v   = (const float*)d_in[5];
    const float* pconv_w = (const float*)d_in[6];
    const float* pconv_b = (const float*)d_in[7];
    const float* wq      = (const float*)d_in[8];
    const float* wk      = (const float*)d_in[9];
    const float* wv      = (const float*)d_in[10];
    const float* fc_w    = (const float*)d_in[11];
    const float* ln_g    = (const float*)d_in[12];
    const float* ln_b    = (const float*)d_in[13];
    const float* gate_w  = (const float*)d_in[14];
    const float* bn2_g   = (const float*)d_in[15];
    const float* bn2_b   = (const float*)d_in[16];
    const float* bn2_m   = (const float*)d_in[17];
    const float* bn2_v   = (const float*)d_in[18];
    const float* tconv_w = (const float*)d_in[19];
    const float* tconv_b = (const float*)d_in[20];
    const float* bn3_g   = (const float*)d_in[21];
    const float* bn3_b   = (const float*)d_in[22];
    const float* bn3_m   = (const float*)d_in[23];
    const float* bn3_v   = (const float*)d_in[24];

    char* ws = (char*)d_ws;
    u16*   f_bf  = (u16*)ws;
    u16*   akt   = (u16*)(ws + WOFF);
    u16*   wp2   = (u16*)(ws + WOFF + 7680);
    u16*   wqt   = (u16*)(ws + WOFF + 32256);
    u16*   wkt   = (u16*)(ws + WOFF + 40448);
    u16*   wvt   = (u16*)(ws + WOFF + 48640);
    u16*   fct   = (u16*)(ws + WOFF + 56832);
    float* bagg  = (float*)(ws + WOFF + 65024);
    u16*   wtc   = (u16*)(ws + WOFF + 71424);
    float* uvec  = (float*)(ws + WOFF + 145152);
    float* w0vec = (float*)(ws + WOFF + 145408);
    float* outp  = (float*)d_out;

    prep_kernel<<<dim3(64), dim3(256), 0, stream>>>(
        A, pconv_w, pconv_b, wq, wk, wv, fc_w, tconv_w, ln_g, ln_b,
        akt, wp2, wqt, wkt, wvt, fct, bagg, wtc, uvec, w0vec);
    scn_kernel<<<dim3(NB * T), dim3(256), 0, stream>>>(
        x, bn1_g, bn1_b, bn1_m, bn1_v, akt, wp2, wqt, wkt, wvt, fct, bagg,
        uvec, w0vec, gate_w, bn2_g, bn2_b, bn2_m, bn2_v, f_bf);
    tcn_mfma<<<dim3(NB * 32), dim3(256), 0, stream>>>(
        f_bf, x, wtc, tconv_b, bn3_g, bn3_b, bn3_m, bn3_v, outp);
}

// Round 19
// 345.628 us; speedup vs baseline: 29.0868x; 1.0555x over previous
//
#include <hip/hip_runtime.h>

#define NB   32
#define C    64
#define T    512
#define V    25
#define KP   3
#define CO   64
#define H    4
#define BN_EPS 1e-5f
#define LN_EPS 1e-6f

typedef float f32x4 __attribute__((ext_vector_type(4)));
typedef short bf16x8 __attribute__((ext_vector_type(8)));
typedef unsigned short u16;
typedef unsigned int u32;
typedef u32 u32x2 __attribute__((ext_vector_type(2)));
#define MFMA(a,b,c) __builtin_amdgcn_mfma_f32_16x16x32_bf16((a),(b),(c),0,0,0)

__device__ __forceinline__ u16 f2bf(float x) {
    union { float f; unsigned u; } v; v.f = x;
    unsigned r = (v.u + 0x7FFFu + ((v.u >> 16) & 1u)) >> 16;
    return (u16)r;
}
__device__ __forceinline__ float bf2f(u16 h) {
    union { unsigned u; float f; } v; v.u = ((unsigned)h) << 16;
    return v.f;
}
__device__ __forceinline__ u32x2 pack4(const f32x4& a) {
    u32x2 p;
    p[0] = (u32)f2bf(a[0]) | ((u32)f2bf(a[1]) << 16);
    p[1] = (u32)f2bf(a[2]) | ((u32)f2bf(a[3]) << 16);
    return p;
}

#define WOFF 52428800ull

// prep: ln_g-scaled wqt; u[j]=sum_c g*wq, w0[j]=sum_c b*wq (R16-validated)
__global__ __launch_bounds__(256) void prep_kernel(
    const float* __restrict__ A, const float* __restrict__ pconv_w,
    const float* __restrict__ pconv_b,
    const float* __restrict__ wq, const float* __restrict__ wk,
    const float* __restrict__ wv, const float* __restrict__ fc_w,
    const float* __restrict__ tconv_w,
    const float* __restrict__ ln_g, const float* __restrict__ ln_b,
    u16* __restrict__ akt, u16* __restrict__ wp2,
    u16* __restrict__ wqt, u16* __restrict__ wkt, u16* __restrict__ wvt,
    u16* __restrict__ fct, float* __restrict__ bagg, u16* __restrict__ wtc,
    float* __restrict__ uvec, float* __restrict__ w0vec)
{
    const int stride = gridDim.x * 256;
    for (int i = blockIdx.x * 256 + threadIdx.x; i < 71104; i += stride) {
        if (i < 3840) {                       // AkT
            int k = i / 1280, r = i - k * 1280, w = r / 40, v = r - w * 40;
            float val = (w < V && v < V) ? A[k * V * V + v * V + w] : 0.f;
            akt[i] = f2bf(val);
        } else if (i < 16128) {               // Wp2
            int i2 = i - 3840;
            int c = i2 / 192, kk = i2 - c * 192, k = kk / 64, ci = kk - k * 64;
            wp2[i2] = f2bf(pconv_w[(k * 64 + c) * 64 + ci]);
        } else if (i < 20224) {               // WqT (ln_g-scaled)
            int i2 = i - 16128; int j = i2 / 64, c = i2 - j * 64;
            wqt[i2] = f2bf(wq[c * 64 + j] * ln_g[c]);
        } else if (i < 24320) {               // WkT
            int i2 = i - 20224; int j = i2 / 64, c = i2 - j * 64;
            wkt[i2] = f2bf(wk[c * 64 + j]);
        } else if (i < 28416) {               // WvT
            int i2 = i - 24320; int j = i2 / 64, c = i2 - j * 64;
            wvt[i2] = f2bf(wv[c * 64 + j]);
        } else if (i < 32512) {               // FcT
            int i2 = i - 28416; int c = i2 / 64, d = i2 - c * 64;
            fct[i2] = f2bf(fc_w[d * 64 + c]);
        } else if (i < 34112) {               // bias_agg
            int i2 = i - 32512; int c = i2 / 25, w = i2 - c * 25;
            float s = 0.f;
            for (int k = 0; k < KP; ++k) {
                float cs = 0.f;
                for (int v = 0; v < V; ++v) cs += A[k * V * V + v * V + w];
                s += pconv_b[k * 64 + c] * cs;
            }
            bagg[i2] = s;
        } else if (i < 70976) {               // Wtc
            int i2 = i - 34112;
            int co = i2 / 576, rem = i2 - co * 576, dt = rem / 64, ci = rem - dt * 64;
            wtc[i2] = f2bf(tconv_w[(co * 64 + ci) * 9 + dt]);
        } else if (i < 71040) {               // uvec[j]
            int j = i - 70976; float s = 0.f;
            for (int c = 0; c < 64; ++c) s += ln_g[c] * wq[c * 64 + j];
            uvec[j] = s;
        } else {                              // w0vec[j]
            int j = i - 71040; float s = 0.f;
            for (int c = 0; c < 64; ++c) s += ln_b[c] * wq[c * 64 + j];
            w0vec[j] = s;
        }
    }
}

// ---------------------------------------------------------------------------
// scn R19 = R18-validated structure + packed D-stores:
//  * k/q projections use SWAPPED MFMA operands (A=W[j][c], B=INPT[v][c] ->
//    D[m=j][n=v]): reg-dim r now walks consecutive jo columns -> one 8B
//    packed store replaces 4 scalar guarded u16 stores.
//  * y-GEMM D-store likewise packed (cb+r consecutive).
//  * v-proj / D1 / D2 / E / F byte-identical to R18 (validated).
//  Garbage-read audit (swapped proj B rows 25..31 overflow INPT into Q2
//  region): always finite bf16 (projection outputs / prior-block data);
//  affects only D cols v>=25 -> stores guarded. LDS unchanged 39640 B,
//  4 blocks/CU.
// ---------------------------------------------------------------------------
#define OFF_INPV  0        // bf16 [64][40] (P0->A)  / XHT bf16 [25][72] (E->F)
#define OFF_XHT   0
#define OFF_INPT  5120     // bf16 [25][72] (P0->F: LN src + residual)
#define OFF_Q2    8720     // bf16 [25][136] (A raw -> fixup -> D1)
#define OFF_ATT   8720     // bf16 [4][32][40] (D2->E) overlays Q2+K2 head
#define OFF_K2    15520    // bf16 [25][136] (A->D1)
#define OFF_VVT   22320    // bf16 [64][40]  (A->E)
#define OFF_LNS   27440    // f32 [25][8][2] (A->B0)
#define OFF_MU    29040    // f32 [25]       (B0->fixup)
#define OFF_RSTD  29140    // f32 [25]       (B0->fixup)
#define OFF_YT    29240    // bf16 [25][200] (A->C) / S f32 [4][25][26] (D1->D2)
#define OFF_S     29240
#define LDS_BYTES 39640

#define LDSF(off) ((float*)(s_raw + (off)))
#define LDSH(off) ((u16*)(s_raw + (off)))
#define LDSV8(b)  (*(const bf16x8*)(s_raw + (b)))

__global__ __launch_bounds__(256) void scn_kernel(
    const float* __restrict__ x,
    const float* __restrict__ bn1_g, const float* __restrict__ bn1_b,
    const float* __restrict__ bn1_m, const float* __restrict__ bn1_v,
    const u16* __restrict__ akt, const u16* __restrict__ wp2,
    const u16* __restrict__ wqt, const u16* __restrict__ wkt,
    const u16* __restrict__ wvt, const u16* __restrict__ fct,
    const float* __restrict__ bagg,
    const float* __restrict__ uvec, const float* __restrict__ w0vec,
    const float* __restrict__ gate_w,
    const float* __restrict__ bn2_g, const float* __restrict__ bn2_b,
    const float* __restrict__ bn2_m, const float* __restrict__ bn2_v,
    u16* __restrict__ f_out)
{
    const int nt   = blockIdx.x;
    const int n    = nt >> 9;
    const int t    = nt & 511;
    const int tid  = threadIdx.x;
    const int lane = tid & 63;
    const int wid  = tid >> 6;
    const int r0   = lane & 15;
    const int g    = lane >> 4;

    __shared__ __align__(16) unsigned char s_raw[LDS_BYTES];

    const float gate = gate_w[0];

    // ---- P0: bn1(x) -> INPV bf16 [c][40], INPT bf16 [v][72];
    //      zero INPV v-pads and Q2+K2+VVT span ----
    #pragma unroll
    for (int it = 0; it < 7; ++it) {
        int i = tid + it * 256;
        if (i < 1600) {
            int c = i / 25, v = i - c * 25;
            float s1 = bn1_g[c] * rsqrtf(bn1_v[c] + BN_EPS);
            float b1 = bn1_b[c] - bn1_m[c] * s1;
            float f = x[((n * 64 + c) * 512 + t) * 25 + v] * s1 + b1;
            u16 hb = f2bf(f);
            LDSH(OFF_INPV)[c * 40 + v] = hb;
            LDSH(OFF_INPT)[v * 72 + c] = hb;
        }
    }
    for (int i = tid; i < 960; i += 256) {
        int c = i / 15, vz = 25 + (i - c * 15);
        LDSH(OFF_INPV)[c * 40 + vz] = 0;
    }
    {
        bf16x8 z = {0,0,0,0,0,0,0,0};
        for (int i = tid; i < 1170; i += 256)
            *(bf16x8*)(s_raw + OFF_Q2 + i * 16) = z;
    }
    __syncthreads();

    // ---- Phase A: y-GEMM, k/v/q projections (MFMA), LN partials ----
    // y-GEMM: packed D-store (cb..cb+3 consecutive)
    #pragma unroll
    for (int ii = 0; ii < 6; ++ii) {
        int idx = wid * 6 + ii;
        int k = idx >> 3, rem = idx & 7, mt = rem >> 1, ntt = rem & 1;
        bf16x8 a = LDSV8(OFF_INPV + ((mt * 16 + r0) * 40 + g * 8) * 2);
        bf16x8 b = *(const bf16x8*)(&akt[(k * 32 + ntt * 16 + r0) * 40 + g * 8]);
        f32x4 acc = {0.f, 0.f, 0.f, 0.f};
        acc = MFMA(a, b, acc);
        int w = ntt * 16 + r0, cb = mt * 16 + g * 4;
        if (w < 25)
            *(u32x2*)&LDSH(OFF_YT)[w * 200 + k * 64 + cb] = pack4(acc);
    }
    // k-proj (SWAPPED): D[j][v]; packed store K2[v][jo..jo+3]
    #pragma unroll
    for (int ii = 0; ii < 2; ++ii) {
        int idx = wid * 2 + ii, mtj = idx >> 1, ntv = idx & 1;
        f32x4 acc = {0.f, 0.f, 0.f, 0.f};
        #pragma unroll
        for (int ks = 0; ks < 2; ++ks) {
            bf16x8 a = *(const bf16x8*)(&wkt[(mtj * 16 + r0) * 64 + ks * 32 + g * 8]);
            bf16x8 b = LDSV8(OFF_INPT + ((ntv * 16 + r0) * 72 + ks * 32 + g * 8) * 2);
            acc = MFMA(a, b, acc);
        }
        int v = ntv * 16 + r0;
        if (v < 25)
            *(u32x2*)&LDSH(OFF_K2)[v * 136 + mtj * 32 + g * 4] = pack4(acc);
    }
    // v-proj (original orientation, R18-validated): D[v][j] -> VVT[j][v]
    #pragma unroll
    for (int ii = 0; ii < 2; ++ii) {
        int idx = wid * 2 + ii, mt = idx >> 2, ntt = idx & 3;
        f32x4 acc = {0.f, 0.f, 0.f, 0.f};
        #pragma unroll
        for (int ks = 0; ks < 2; ++ks) {
            bf16x8 a = LDSV8(OFF_INPT + ((mt * 16 + r0) * 72 + ks * 32 + g * 8) * 2);
            bf16x8 b = *(const bf16x8*)(&wvt[(ntt * 16 + r0) * 64 + ks * 32 + g * 8]);
            acc = MFMA(a, b, acc);
        }
        int j = ntt * 16 + r0;
        #pragma unroll
        for (int r = 0; r < 4; ++r) {
            int v = mt * 16 + g * 4 + r;
            if (v < 25) LDSH(OFF_VVT)[j * 40 + v] = f2bf(acc[r]);
        }
    }
    // q-proj (SWAPPED, g-scaled weights): packed store Q2[v][jo..jo+3]
    #pragma unroll
    for (int ii = 0; ii < 2; ++ii) {
        int idx = wid * 2 + ii, mtj = idx >> 1, ntv = idx & 1;
        f32x4 acc = {0.f, 0.f, 0.f, 0.f};
        #pragma unroll
        for (int ks = 0; ks < 2; ++ks) {
            bf16x8 a = *(const bf16x8*)(&wqt[(mtj * 16 + r0) * 64 + ks * 32 + g * 8]);
            bf16x8 b = LDSV8(OFF_INPT + ((ntv * 16 + r0) * 72 + ks * 32 + g * 8) * 2);
            acc = MFMA(a, b, acc);
        }
        int v = ntv * 16 + r0;
        if (v < 25)
            *(u32x2*)&LDSH(OFF_Q2)[v * 136 + mtj * 32 + g * 4] = pack4(acc);
    }
    // LN partials (from INPT bf16)
    if (tid < 200) {
        int v = tid >> 3, p = tid & 7;
        const u16* row = LDSH(OFF_INPT) + v * 72 + p * 8;
        float s1 = 0.f, s2 = 0.f;
        #pragma unroll
        for (int cc = 0; cc < 8; ++cc) {
            float xv = bf2f(row[cc]);
            s1 += xv; s2 += xv * xv;
        }
        LDSF(OFF_LNS)[(v * 8 + p) * 2]     = s1;
        LDSF(OFF_LNS)[(v * 8 + p) * 2 + 1] = s2;
    }
    __syncthreads();

    // ---- B0: LN reduce ----
    if (tid < 25) {
        float s1 = 0.f, s2 = 0.f;
        #pragma unroll
        for (int p = 0; p < 8; ++p) {
            s1 += LDSF(OFF_LNS)[(tid * 8 + p) * 2];
            s2 += LDSF(OFF_LNS)[(tid * 8 + p) * 2 + 1];
        }
        float mu = s1 * (1.f / 64.f);
        float var = s2 * (1.f / 64.f) - mu * mu;
        LDSF(OFF_MU)[tid]   = mu;
        LDSF(OFF_RSTD)[tid] = rsqrtf(var + LN_EPS);
    }
    __syncthreads();

    // ---- B1C: Q2 LN-fixup (q = rstd*raw - rstd*mu*u + w0) + agg-GEMM ----
    #pragma unroll
    for (int it = 0; it < 7; ++it) {
        int i = tid + it * 256;
        if (i < 1600) {
            int v = i >> 6, j = i & 63;
            int jo = (j >> 4) * 32 + (j & 15);
            float raw = bf2f(LDSH(OFF_Q2)[v * 136 + jo]);
            float rs = LDSF(OFF_RSTD)[v], m = LDSF(OFF_MU)[v];
            LDSH(OFF_Q2)[v * 136 + jo] =
                f2bf(rs * raw - rs * m * uvec[j] + w0vec[j]);
        }
    }
    f32x4 agg_reg[2];
    #pragma unroll
    for (int ii = 0; ii < 2; ++ii) {
        int idx = wid * 2 + ii, mt = idx >> 1, ntt = idx & 1;
        f32x4 acc = {0.f, 0.f, 0.f, 0.f};
        #pragma unroll
        for (int ks = 0; ks < 6; ++ks) {
            bf16x8 a = *(const bf16x8*)(&wp2[(mt * 16 + r0) * 192 + ks * 32 + g * 8]);
            int brow = ntt * 16 + r0; if (brow > 24) brow = 24;   // YT row clamp
            bf16x8 b = LDSV8(OFF_YT + (brow * 200 + ks * 32 + g * 8) * 2);
            acc = MFMA(a, b, acc);
        }
        int w = ntt * 16 + r0, cb = mt * 16 + g * 4;
        if (w < 25) {
            #pragma unroll
            for (int r = 0; r < 4; ++r) acc[r] += bagg[(cb + r) * 25 + w];
        }
        agg_reg[ii] = acc;
    }
    __syncthreads();

    // ---- D1 (MFMA): S = Q@K^T per head, K=32 (pads zero) -> S f32 ----
    #pragma unroll
    for (int ii = 0; ii < 4; ++ii) {
        int idx = wid * 4 + ii;
        int h = idx >> 2, mt = (idx >> 1) & 1, ntc = idx & 1;
        bf16x8 a = LDSV8(OFF_Q2 + ((mt * 16 + r0) * 136 + h * 32 + g * 8) * 2);
        bf16x8 b = LDSV8(OFF_K2 + ((ntc * 16 + r0) * 136 + h * 32 + g * 8) * 2);
        f32x4 acc = {0.f, 0.f, 0.f, 0.f};
        acc = MFMA(a, b, acc);
        int kv = ntc * 16 + r0;
        if (kv < 25) {
            #pragma unroll
            for (int r = 0; r < 4; ++r) {
                int qv = mt * 16 + g * 4 + r;
                if (qv < 25)
                    LDSF(OFF_S)[(h * 25 + qv) * 26 + kv] = acc[r];
            }
        }
    }
    __syncthreads();

    // ---- D2: softmax -> ATT bf16 [4][32][40], zero k-pad cols ----
    if (tid < 100) {
        int h = tid / 25, qv = tid - h * 25;
        const float* srow = LDSF(OFF_S) + (h * 25 + qv) * 26;
        float row[25]; float mx = -1e30f;
        #pragma unroll
        for (int kv = 0; kv < 25; ++kv) {
            float s = srow[kv] * 0.25f;
            row[kv] = s; mx = fmaxf(mx, s);
        }
        float sum = 0.f;
        #pragma unroll
        for (int kv = 0; kv < 25; ++kv) { float e = __expf(row[kv] - mx); row[kv] = e; sum += e; }
        float inv = 1.f / sum;
        u16* arow = LDSH(OFF_ATT) + (h * 32 + qv) * 40;
        #pragma unroll
        for (int kv = 0; kv < 25; ++kv) arow[kv] = f2bf(row[kv] * inv);
        #pragma unroll
        for (int kv = 25; kv < 32; ++kv) arow[kv] = 0;
    }
    __syncthreads();

    // ---- E (MFMA): xh = P@V per head -> XHT ----
    #pragma unroll
    for (int ii = 0; ii < 2; ++ii) {
        int idx = wid * 2 + ii, h = idx >> 1, mt = idx & 1;
        bf16x8 a = LDSV8(OFF_ATT + ((h * 32 + mt * 16 + r0) * 40 + g * 8) * 2);
        bf16x8 b = LDSV8(OFF_VVT + ((h * 16 + r0) * 40 + g * 8) * 2);
        f32x4 acc = {0.f, 0.f, 0.f, 0.f};
        acc = MFMA(a, b, acc);
        #pragma unroll
        for (int r = 0; r < 4; ++r) {
            int v = mt * 16 + g * 4 + r;
            if (v < 25)
                LDSH(OFF_XHT)[v * 72 + h * 16 + r0] = f2bf(acc[r]);
        }
    }
    __syncthreads();

    // ---- F: fc-GEMM + fused epilogue (residual from INPT) -> f bf16 ----
    #pragma unroll
    for (int ii = 0; ii < 2; ++ii) {
        int idx = wid * 2 + ii, mt = idx >> 1, ntt = idx & 1;
        f32x4 acc = {0.f, 0.f, 0.f, 0.f};
        #pragma unroll
        for (int ks = 0; ks < 2; ++ks) {
            bf16x8 a = *(const bf16x8*)(&fct[(mt * 16 + r0) * 64 + ks * 32 + g * 8]);
            bf16x8 b = LDSV8(OFF_XHT + ((ntt * 16 + r0) * 72 + ks * 32 + g * 8) * 2);
            acc = MFMA(a, b, acc);
        }
        int v = ntt * 16 + r0;
        if (v < 25) {
            int cb = mt * 16 + g * 4;
            u16 hh[4];
            #pragma unroll
            for (int r = 0; r < 4; ++r) {
                int c = cb + r;
                float fa_out = acc[r] + bf2f(LDSH(OFF_INPT)[v * 72 + c]);
                float fv = (fa_out * gate + agg_reg[ii][r]) * 0.5f;
                float s2 = bn2_g[c] * rsqrtf(bn2_v[c] + BN_EPS);
                float b2 = bn2_b[c] - bn2_m[c] * s2;
                fv = fmaxf(fv * s2 + b2, 0.f);
                hh[r] = f2bf(fv);
            }
            u32x2 pk;
            pk[0] = (u32)hh[0] | ((u32)hh[1] << 16);
            pk[1] = (u32)hh[2] | ((u32)hh[3] << 16);
            *(u32x2*)&f_out[((n * 512 + t) * 25 + v) * 64 + cb] = pk;
        }
    }
}

// ---------------------------------------------------------------------------
// tcn_mfma: implicit-GEMM temporal conv, vectorized staging (R13-validated,
// ~40us ~= memory floor). Unchanged.
// ---------------------------------------------------------------------------
#define FB_STRIDE 40

__global__ __launch_bounds__(256) void tcn_mfma(
    const u16* __restrict__ f, const float* __restrict__ x,
    const u16* __restrict__ wtc, const float* __restrict__ tconv_b,
    const float* __restrict__ bn3_g, const float* __restrict__ bn3_b,
    const float* __restrict__ bn3_m, const float* __restrict__ bn3_v,
    float* __restrict__ out)
{
    const int bid  = blockIdx.x;
    const int n    = bid >> 5;
    const int t0   = (bid & 31) * 16;
    const int tid  = threadIdx.x;
    const int lane = tid & 63;
    const int wid  = tid >> 6;
    const int r0   = lane & 15;
    const int g    = lane >> 4;
    const int co_base = wid * 16;

    __shared__ __align__(16) u16 s_fB[24 * 25 * FB_STRIDE];   // 48000 B

    f32x4 acc[25];
    #pragma unroll
    for (int i = 0; i < 25; ++i) acc[i] = (f32x4){0.f, 0.f, 0.f, 0.f};

    for (int ph = 0; ph < 2; ++ph) {
        const int ci0 = ph * 32;
        __syncthreads();
        for (int u = tid; u < 2400; u += 256) {
            int q = u & 3, rv = u >> 2;          // rv = tp*25+v
            int tp = rv / 25, v = rv - tp * 25;
            int tg = t0 + tp - 4;
            bf16x8 val = {0,0,0,0,0,0,0,0};
            if (tg >= 0 && tg < 512)
                val = *(const bf16x8*)&f[((n * 512 + tg) * 25 + v) * 64 + ci0 + q * 8];
            *(bf16x8*)&s_fB[rv * FB_STRIDE + q * 8] = val;
        }
        __syncthreads();

        bf16x8 aF[9];
        #pragma unroll
        for (int dt = 0; dt < 9; ++dt)
            aF[dt] = *(const bf16x8*)(&wtc[((co_base + r0) * 9 + dt) * 64 + ci0 + g * 8]);

        #pragma unroll
        for (int nt2 = 0; nt2 < 25; ++nt2) {
            int c0 = nt2 * 16 + r0;
            int tb = c0 / 25, v = c0 - tb * 25;
            #pragma unroll
            for (int dt = 0; dt < 9; ++dt) {
                bf16x8 bF = *(const bf16x8*)(&s_fB[((tb + dt) * 25 + v) * FB_STRIDE + g * 8]);
                acc[nt2] = MFMA(aF[dt], bF, acc[nt2]);
            }
        }
    }

    float s3v[4], pre[4];
    #pragma unroll
    for (int r = 0; r < 4; ++r) {
        int co = co_base + g * 4 + r;
        float s3 = bn3_g[co] * rsqrtf(bn3_v[co] + BN_EPS);
        float b3 = bn3_b[co] - bn3_m[co] * s3;
        s3v[r] = s3;
        pre[r] = tconv_b[co] * s3 + b3;
    }
    #pragma unroll
    for (int nt2 = 0; nt2 < 25; ++nt2) {
        int c0 = nt2 * 16 + r0;
        int tb = c0 / 25, v = c0 - tb * 25;
        #pragma unroll
        for (int r = 0; r < 4; ++r) {
            int co = co_base + g * 4 + r;
            int idx = ((n * 64 + co) * 512 + t0 + tb) * 25 + v;
            float y = acc[nt2][r] * s3v[r] + pre[r] + x[idx];
            out[idx] = fmaxf(y, 0.f);
        }
    }
}

extern "C" void kernel_launch(void* const* d_in, const int* in_sizes, int n_in,
                              void* d_out, int out_size, void* d_ws, size_t ws_size,
                              hipStream_t stream) {
    const float* x       = (const float*)d_in[0];
    const float* A       = (const float*)d_in[1];
    const float* bn1_g   = (const float*)d_in[2];
    const float* bn1_b   = (const float*)d_in[3];
    const float* bn1_m   = (const float*)d_in[4];
    const float* bn1_v   = (const float*)d_in[5];
    const float* pconv_w = (const float*)d_in[6];
    const float* pconv_b = (const float*)d_in[7];
    const float* wq      = (const float*)d_in[8];
    const float* wk      = (const float*)d_in[9];
    const float* wv      = (const float*)d_in[10];
    const float* fc_w    = (const float*)d_in[11];
    const float* ln_g    = (const float*)d_in[12];
    const float* ln_b    = (const float*)d_in[13];
    const float* gate_w  = (const float*)d_in[14];
    const float* bn2_g   = (const float*)d_in[15];
    const float* bn2_b   = (const float*)d_in[16];
    const float* bn2_m   = (const float*)d_in[17];
    const float* bn2_v   = (const float*)d_in[18];
    const float* tconv_w = (const float*)d_in[19];
    const float* tconv_b = (const float*)d_in[20];
    const float* bn3_g   = (const float*)d_in[21];
    const float* bn3_b   = (const float*)d_in[22];
    const float* bn3_m   = (const float*)d_in[23];
    const float* bn3_v   = (const float*)d_in[24];

    char* ws = (char*)d_ws;
    u16*   f_bf  = (u16*)ws;
    u16*   akt   = (u16*)(ws + WOFF);
    u16*   wp2   = (u16*)(ws + WOFF + 7680);
    u16*   wqt   = (u16*)(ws + WOFF + 32256);
    u16*   wkt   = (u16*)(ws + WOFF + 40448);
    u16*   wvt   = (u16*)(ws + WOFF + 48640);
    u16*   fct   = (u16*)(ws + WOFF + 56832);
    float* bagg  = (float*)(ws + WOFF + 65024);
    u16*   wtc   = (u16*)(ws + WOFF + 71424);
    float* uvec  = (float*)(ws + WOFF + 145152);
    float* w0vec = (float*)(ws + WOFF + 145408);
    float* outp  = (float*)d_out;

    prep_kernel<<<dim3(64), dim3(256), 0, stream>>>(
        A, pconv_w, pconv_b, wq, wk, wv, fc_w, tconv_w, ln_g, ln_b,
        akt, wp2, wqt, wkt, wvt, fct, bagg, wtc, uvec, w0vec);
    scn_kernel<<<dim3(NB * T), dim3(256), 0, stream>>>(
        x, bn1_g, bn1_b, bn1_m, bn1_v, akt, wp2, wqt, wkt, wvt, fct, bagg,
        uvec, w0vec, gate_w, bn2_g, bn2_b, bn2_m, bn2_v, f_bf);
    tcn_mfma<<<dim3(NB * 32), dim3(256), 0, stream>>>(
        f_bf, x, wtc, tconv_b, bn3_g, bn3_b, bn3_m, bn3_v, outp);
}

// Round 20
// 324.855 us; speedup vs baseline: 30.9468x; 1.0639x over previous
//
#include <hip/hip_runtime.h>

#define NB   32
#define C    64
#define T    512
#define V    25
#define KP   3
#define CO   64
#define H    4
#define BN_EPS 1e-5f
#define LN_EPS 1e-6f

typedef float f32x4 __attribute__((ext_vector_type(4)));
typedef short bf16x8 __attribute__((ext_vector_type(8)));
typedef unsigned short u16;
typedef unsigned int u32;
typedef u32 u32x2 __attribute__((ext_vector_type(2)));
#define MFMA(a,b,c) __builtin_amdgcn_mfma_f32_16x16x32_bf16((a),(b),(c),0,0,0)

__device__ __forceinline__ u16 f2bf(float x) {
    union { float f; unsigned u; } v; v.f = x;
    unsigned r = (v.u + 0x7FFFu + ((v.u >> 16) & 1u)) >> 16;
    return (u16)r;
}
__device__ __forceinline__ float bf2f(u16 h) {
    union { unsigned u; float f; } v; v.u = ((unsigned)h) << 16;
    return v.f;
}
__device__ __forceinline__ u32x2 pack4(const f32x4& a) {
    u32x2 p;
    p[0] = (u32)f2bf(a[0]) | ((u32)f2bf(a[1]) << 16);
    p[1] = (u32)f2bf(a[2]) | ((u32)f2bf(a[3]) << 16);
    return p;
}

#define WOFF 52428800ull

// prep R20: + precomputed BN affine constants (bn1s/bn1b, bn2s/bn2b, s3/pre3)
// so the hot kernels never run rsqrtf.
__global__ __launch_bounds__(256) void prep_kernel(
    const float* __restrict__ A, const float* __restrict__ pconv_w,
    const float* __restrict__ pconv_b,
    const float* __restrict__ wq, const float* __restrict__ wk,
    const float* __restrict__ wv, const float* __restrict__ fc_w,
    const float* __restrict__ tconv_w, const float* __restrict__ tconv_b,
    const float* __restrict__ ln_g, const float* __restrict__ ln_b,
    const float* __restrict__ bn1_g, const float* __restrict__ bn1_b,
    const float* __restrict__ bn1_m, const float* __restrict__ bn1_v,
    const float* __restrict__ bn2_g, const float* __restrict__ bn2_b,
    const float* __restrict__ bn2_m, const float* __restrict__ bn2_v,
    const float* __restrict__ bn3_g, const float* __restrict__ bn3_b,
    const float* __restrict__ bn3_m, const float* __restrict__ bn3_v,
    u16* __restrict__ akt, u16* __restrict__ wp2,
    u16* __restrict__ wqt, u16* __restrict__ wkt, u16* __restrict__ wvt,
    u16* __restrict__ fct, float* __restrict__ bagg, u16* __restrict__ wtc,
    float* __restrict__ uvec, float* __restrict__ w0vec,
    float* __restrict__ bnc)   // bnc: [6][64] = bn1s,bn1b,bn2s,bn2b,s3,pre3
{
    const int stride = gridDim.x * 256;
    for (int i = blockIdx.x * 256 + threadIdx.x; i < 71296; i += stride) {
        if (i < 3840) {                       // AkT
            int k = i / 1280, r = i - k * 1280, w = r / 40, v = r - w * 40;
            float val = (w < V && v < V) ? A[k * V * V + v * V + w] : 0.f;
            akt[i] = f2bf(val);
        } else if (i < 16128) {               // Wp2
            int i2 = i - 3840;
            int c = i2 / 192, kk = i2 - c * 192, k = kk / 64, ci = kk - k * 64;
            wp2[i2] = f2bf(pconv_w[(k * 64 + c) * 64 + ci]);
        } else if (i < 20224) {               // WqT (ln_g-scaled)
            int i2 = i - 16128; int j = i2 / 64, c = i2 - j * 64;
            wqt[i2] = f2bf(wq[c * 64 + j] * ln_g[c]);
        } else if (i < 24320) {               // WkT
            int i2 = i - 20224; int j = i2 / 64, c = i2 - j * 64;
            wkt[i2] = f2bf(wk[c * 64 + j]);
        } else if (i < 28416) {               // WvT
            int i2 = i - 24320; int j = i2 / 64, c = i2 - j * 64;
            wvt[i2] = f2bf(wv[c * 64 + j]);
        } else if (i < 32512) {               // FcT
            int i2 = i - 28416; int c = i2 / 64, d = i2 - c * 64;
            fct[i2] = f2bf(fc_w[d * 64 + c]);
        } else if (i < 34112) {               // bias_agg
            int i2 = i - 32512; int c = i2 / 25, w = i2 - c * 25;
            float s = 0.f;
            for (int k = 0; k < KP; ++k) {
                float cs = 0.f;
                for (int v = 0; v < V; ++v) cs += A[k * V * V + v * V + w];
                s += pconv_b[k * 64 + c] * cs;
            }
            bagg[i2] = s;
        } else if (i < 70976) {               // Wtc
            int i2 = i - 34112;
            int co = i2 / 576, rem = i2 - co * 576, dt = rem / 64, ci = rem - dt * 64;
            wtc[i2] = f2bf(tconv_w[(co * 64 + ci) * 9 + dt]);
        } else if (i < 71040) {               // uvec[j]
            int j = i - 70976; float s = 0.f;
            for (int c = 0; c < 64; ++c) s += ln_g[c] * wq[c * 64 + j];
            uvec[j] = s;
        } else if (i < 71104) {               // w0vec[j]
            int j = i - 71040; float s = 0.f;
            for (int c = 0; c < 64; ++c) s += ln_b[c] * wq[c * 64 + j];
            w0vec[j] = s;
        } else if (i < 71168) {               // bn1 s/b
            int c = i - 71104;
            float s1 = bn1_g[c] * rsqrtf(bn1_v[c] + BN_EPS);
            bnc[c]      = s1;
            bnc[64 + c] = bn1_b[c] - bn1_m[c] * s1;
        } else if (i < 71232) {               // bn2 s/b
            int c = i - 71168;
            float s2 = bn2_g[c] * rsqrtf(bn2_v[c] + BN_EPS);
            bnc[128 + c] = s2;
            bnc[192 + c] = bn2_b[c] - bn2_m[c] * s2;
        } else {                              // bn3 s / pre (incl tconv bias)
            int c = i - 71232;
            float s3 = bn3_g[c] * rsqrtf(bn3_v[c] + BN_EPS);
            bnc[256 + c] = s3;
            bnc[320 + c] = tconv_b[c] * s3 + (bn3_b[c] - bn3_m[c] * s3);
        }
    }
}

// ---------------------------------------------------------------------------
// scn R20 = R19-validated structure + (a) BN constants from bnc[] (no rsqrtf
// in hot path), (b) 1/sqrt(DK)=0.25 folded into Q2 LN-fixup so D2 softmax
// drops its per-element multiply. LDS 39640 B, 4 blocks/CU (R18-validated).
// ---------------------------------------------------------------------------
#define OFF_INPV  0
#define OFF_XHT   0
#define OFF_INPT  5120
#define OFF_Q2    8720
#define OFF_ATT   8720
#define OFF_K2    15520
#define OFF_VVT   22320
#define OFF_LNS   27440
#define OFF_MU    29040
#define OFF_RSTD  29140
#define OFF_YT    29240
#define OFF_S     29240
#define LDS_BYTES 39640

#define LDSF(off) ((float*)(s_raw + (off)))
#define LDSH(off) ((u16*)(s_raw + (off)))
#define LDSV8(b)  (*(const bf16x8*)(s_raw + (b)))

__global__ __launch_bounds__(256) void scn_kernel(
    const float* __restrict__ x,
    const u16* __restrict__ akt, const u16* __restrict__ wp2,
    const u16* __restrict__ wqt, const u16* __restrict__ wkt,
    const u16* __restrict__ wvt, const u16* __restrict__ fct,
    const float* __restrict__ bagg,
    const float* __restrict__ uvec, const float* __restrict__ w0vec,
    const float* __restrict__ gate_w, const float* __restrict__ bnc,
    u16* __restrict__ f_out)
{
    const int nt   = blockIdx.x;
    const int n    = nt >> 9;
    const int t    = nt & 511;
    const int tid  = threadIdx.x;
    const int lane = tid & 63;
    const int wid  = tid >> 6;
    const int r0   = lane & 15;
    const int g    = lane >> 4;

    __shared__ __align__(16) unsigned char s_raw[LDS_BYTES];

    const float gate = gate_w[0];

    // ---- P0: bn1(x) -> INPV bf16 [c][40], INPT bf16 [v][72] ----
    #pragma unroll
    for (int it = 0; it < 7; ++it) {
        int i = tid + it * 256;
        if (i < 1600) {
            int c = i / 25, v = i - c * 25;
            float f = x[((n * 64 + c) * 512 + t) * 25 + v] * bnc[c] + bnc[64 + c];
            u16 hb = f2bf(f);
            LDSH(OFF_INPV)[c * 40 + v] = hb;
            LDSH(OFF_INPT)[v * 72 + c] = hb;
        }
    }
    for (int i = tid; i < 960; i += 256) {
        int c = i / 15, vz = 25 + (i - c * 15);
        LDSH(OFF_INPV)[c * 40 + vz] = 0;
    }
    {
        bf16x8 z = {0,0,0,0,0,0,0,0};
        for (int i = tid; i < 1170; i += 256)
            *(bf16x8*)(s_raw + OFF_Q2 + i * 16) = z;
    }
    __syncthreads();

    // ---- Phase A: y-GEMM, k/v/q projections (MFMA), LN partials ----
    #pragma unroll
    for (int ii = 0; ii < 6; ++ii) {
        int idx = wid * 6 + ii;
        int k = idx >> 3, rem = idx & 7, mt = rem >> 1, ntt = rem & 1;
        bf16x8 a = LDSV8(OFF_INPV + ((mt * 16 + r0) * 40 + g * 8) * 2);
        bf16x8 b = *(const bf16x8*)(&akt[(k * 32 + ntt * 16 + r0) * 40 + g * 8]);
        f32x4 acc = {0.f, 0.f, 0.f, 0.f};
        acc = MFMA(a, b, acc);
        int w = ntt * 16 + r0, cb = mt * 16 + g * 4;
        if (w < 25)
            *(u32x2*)&LDSH(OFF_YT)[w * 200 + k * 64 + cb] = pack4(acc);
    }
    // k-proj (swapped): packed store K2[v][jo..jo+3]
    #pragma unroll
    for (int ii = 0; ii < 2; ++ii) {
        int idx = wid * 2 + ii, mtj = idx >> 1, ntv = idx & 1;
        f32x4 acc = {0.f, 0.f, 0.f, 0.f};
        #pragma unroll
        for (int ks = 0; ks < 2; ++ks) {
            bf16x8 a = *(const bf16x8*)(&wkt[(mtj * 16 + r0) * 64 + ks * 32 + g * 8]);
            bf16x8 b = LDSV8(OFF_INPT + ((ntv * 16 + r0) * 72 + ks * 32 + g * 8) * 2);
            acc = MFMA(a, b, acc);
        }
        int v = ntv * 16 + r0;
        if (v < 25)
            *(u32x2*)&LDSH(OFF_K2)[v * 136 + mtj * 32 + g * 4] = pack4(acc);
    }
    // v-proj (original orientation): D[v][j] -> VVT[j][v]
    #pragma unroll
    for (int ii = 0; ii < 2; ++ii) {
        int idx = wid * 2 + ii, mt = idx >> 2, ntt = idx & 3;
        f32x4 acc = {0.f, 0.f, 0.f, 0.f};
        #pragma unroll
        for (int ks = 0; ks < 2; ++ks) {
            bf16x8 a = LDSV8(OFF_INPT + ((mt * 16 + r0) * 72 + ks * 32 + g * 8) * 2);
            bf16x8 b = *(const bf16x8*)(&wvt[(ntt * 16 + r0) * 64 + ks * 32 + g * 8]);
            acc = MFMA(a, b, acc);
        }
        int j = ntt * 16 + r0;
        #pragma unroll
        for (int r = 0; r < 4; ++r) {
            int v = mt * 16 + g * 4 + r;
            if (v < 25) LDSH(OFF_VVT)[j * 40 + v] = f2bf(acc[r]);
        }
    }
    // q-proj (swapped, g-scaled weights): packed store Q2[v][jo..jo+3]
    #pragma unroll
    for (int ii = 0; ii < 2; ++ii) {
        int idx = wid * 2 + ii, mtj = idx >> 1, ntv = idx & 1;
        f32x4 acc = {0.f, 0.f, 0.f, 0.f};
        #pragma unroll
        for (int ks = 0; ks < 2; ++ks) {
            bf16x8 a = *(const bf16x8*)(&wqt[(mtj * 16 + r0) * 64 + ks * 32 + g * 8]);
            bf16x8 b = LDSV8(OFF_INPT + ((ntv * 16 + r0) * 72 + ks * 32 + g * 8) * 2);
            acc = MFMA(a, b, acc);
        }
        int v = ntv * 16 + r0;
        if (v < 25)
            *(u32x2*)&LDSH(OFF_Q2)[v * 136 + mtj * 32 + g * 4] = pack4(acc);
    }
    // LN partials (from INPT bf16)
    if (tid < 200) {
        int v = tid >> 3, p = tid & 7;
        const u16* row = LDSH(OFF_INPT) + v * 72 + p * 8;
        float s1 = 0.f, s2 = 0.f;
        #pragma unroll
        for (int cc = 0; cc < 8; ++cc) {
            float xv = bf2f(row[cc]);
            s1 += xv; s2 += xv * xv;
        }
        LDSF(OFF_LNS)[(v * 8 + p) * 2]     = s1;
        LDSF(OFF_LNS)[(v * 8 + p) * 2 + 1] = s2;
    }
    __syncthreads();

    // ---- B0: LN reduce ----
    if (tid < 25) {
        float s1 = 0.f, s2 = 0.f;
        #pragma unroll
        for (int p = 0; p < 8; ++p) {
            s1 += LDSF(OFF_LNS)[(tid * 8 + p) * 2];
            s2 += LDSF(OFF_LNS)[(tid * 8 + p) * 2 + 1];
        }
        float mu = s1 * (1.f / 64.f);
        float var = s2 * (1.f / 64.f) - mu * mu;
        LDSF(OFF_MU)[tid]   = mu;
        LDSF(OFF_RSTD)[tid] = rsqrtf(var + LN_EPS);
    }
    __syncthreads();

    // ---- B1C: Q2 fixup, 0.25 attn-scale folded in ----
    #pragma unroll
    for (int it = 0; it < 7; ++it) {
        int i = tid + it * 256;
        if (i < 1600) {
            int v = i >> 6, j = i & 63;
            int jo = (j >> 4) * 32 + (j & 15);
            float raw = bf2f(LDSH(OFF_Q2)[v * 136 + jo]);
            float rs = LDSF(OFF_RSTD)[v], m = LDSF(OFF_MU)[v];
            LDSH(OFF_Q2)[v * 136 + jo] =
                f2bf(0.25f * (rs * raw - rs * m * uvec[j] + w0vec[j]));
        }
    }
    f32x4 agg_reg[2];
    #pragma unroll
    for (int ii = 0; ii < 2; ++ii) {
        int idx = wid * 2 + ii, mt = idx >> 1, ntt = idx & 1;
        f32x4 acc = {0.f, 0.f, 0.f, 0.f};
        #pragma unroll
        for (int ks = 0; ks < 6; ++ks) {
            bf16x8 a = *(const bf16x8*)(&wp2[(mt * 16 + r0) * 192 + ks * 32 + g * 8]);
            int brow = ntt * 16 + r0; if (brow > 24) brow = 24;
            bf16x8 b = LDSV8(OFF_YT + (brow * 200 + ks * 32 + g * 8) * 2);
            acc = MFMA(a, b, acc);
        }
        int w = ntt * 16 + r0, cb = mt * 16 + g * 4;
        if (w < 25) {
            #pragma unroll
            for (int r = 0; r < 4; ++r) acc[r] += bagg[(cb + r) * 25 + w];
        }
        agg_reg[ii] = acc;
    }
    __syncthreads();

    // ---- D1 (MFMA): S = Q@K^T per head (q pre-scaled) -> S f32 ----
    #pragma unroll
    for (int ii = 0; ii < 4; ++ii) {
        int idx = wid * 4 + ii;
        int h = idx >> 2, mt = (idx >> 1) & 1, ntc = idx & 1;
        bf16x8 a = LDSV8(OFF_Q2 + ((mt * 16 + r0) * 136 + h * 32 + g * 8) * 2);
        bf16x8 b = LDSV8(OFF_K2 + ((ntc * 16 + r0) * 136 + h * 32 + g * 8) * 2);
        f32x4 acc = {0.f, 0.f, 0.f, 0.f};
        acc = MFMA(a, b, acc);
        int kv = ntc * 16 + r0;
        if (kv < 25) {
            #pragma unroll
            for (int r = 0; r < 4; ++r) {
                int qv = mt * 16 + g * 4 + r;
                if (qv < 25)
                    LDSF(OFF_S)[(h * 25 + qv) * 26 + kv] = acc[r];
            }
        }
    }
    __syncthreads();

    // ---- D2: softmax (no scale mul) -> ATT bf16, zero k-pad cols ----
    if (tid < 100) {
        int h = tid / 25, qv = tid - h * 25;
        const float* srow = LDSF(OFF_S) + (h * 25 + qv) * 26;
        float row[25]; float mx = -1e30f;
        #pragma unroll
        for (int kv = 0; kv < 25; ++kv) {
            float s = srow[kv];
            row[kv] = s; mx = fmaxf(mx, s);
        }
        float sum = 0.f;
        #pragma unroll
        for (int kv = 0; kv < 25; ++kv) { float e = __expf(row[kv] - mx); row[kv] = e; sum += e; }
        float inv = 1.f / sum;
        u16* arow = LDSH(OFF_ATT) + (h * 32 + qv) * 40;
        #pragma unroll
        for (int kv = 0; kv < 25; ++kv) arow[kv] = f2bf(row[kv] * inv);
        #pragma unroll
        for (int kv = 25; kv < 32; ++kv) arow[kv] = 0;
    }
    __syncthreads();

    // ---- E (MFMA): xh = P@V per head -> XHT ----
    #pragma unroll
    for (int ii = 0; ii < 2; ++ii) {
        int idx = wid * 2 + ii, h = idx >> 1, mt = idx & 1;
        bf16x8 a = LDSV8(OFF_ATT + ((h * 32 + mt * 16 + r0) * 40 + g * 8) * 2);
        bf16x8 b = LDSV8(OFF_VVT + ((h * 16 + r0) * 40 + g * 8) * 2);
        f32x4 acc = {0.f, 0.f, 0.f, 0.f};
        acc = MFMA(a, b, acc);
        #pragma unroll
        for (int r = 0; r < 4; ++r) {
            int v = mt * 16 + g * 4 + r;
            if (v < 25)
                LDSH(OFF_XHT)[v * 72 + h * 16 + r0] = f2bf(acc[r]);
        }
    }
    __syncthreads();

    // ---- F: fc-GEMM + fused epilogue (bnc-based bn2) -> f bf16 ----
    #pragma unroll
    for (int ii = 0; ii < 2; ++ii) {
        int idx = wid * 2 + ii, mt = idx >> 1, ntt = idx & 1;
        f32x4 acc = {0.f, 0.f, 0.f, 0.f};
        #pragma unroll
        for (int ks = 0; ks < 2; ++ks) {
            bf16x8 a = *(const bf16x8*)(&fct[(mt * 16 + r0) * 64 + ks * 32 + g * 8]);
            bf16x8 b = LDSV8(OFF_XHT + ((ntt * 16 + r0) * 72 + ks * 32 + g * 8) * 2);
            acc = MFMA(a, b, acc);
        }
        int v = ntt * 16 + r0;
        if (v < 25) {
            int cb = mt * 16 + g * 4;
            u16 hh[4];
            #pragma unroll
            for (int r = 0; r < 4; ++r) {
                int c = cb + r;
                float fa_out = acc[r] + bf2f(LDSH(OFF_INPT)[v * 72 + c]);
                float fv = (fa_out * gate + agg_reg[ii][r]) * 0.5f;
                fv = fmaxf(fv * bnc[128 + c] + bnc[192 + c], 0.f);
                hh[r] = f2bf(fv);
            }
            u32x2 pk;
            pk[0] = (u32)hh[0] | ((u32)hh[1] << 16);
            pk[1] = (u32)hh[2] | ((u32)hh[3] << 16);
            *(u32x2*)&f_out[((n * 512 + t) * 25 + v) * 64 + cb] = pk;
        }
    }
}

// ---------------------------------------------------------------------------
// tcn_mfma: implicit-GEMM temporal conv (R13-validated). R20: epilogue
// constants from bnc (no rsqrtf).
// ---------------------------------------------------------------------------
#define FB_STRIDE 40

__global__ __launch_bounds__(256) void tcn_mfma(
    const u16* __restrict__ f, const float* __restrict__ x,
    const u16* __restrict__ wtc, const float* __restrict__ bnc,
    float* __restrict__ out)
{
    const int bid  = blockIdx.x;
    const int n    = bid >> 5;
    const int t0   = (bid & 31) * 16;
    const int tid  = threadIdx.x;
    const int lane = tid & 63;
    const int wid  = tid >> 6;
    const int r0   = lane & 15;
    const int g    = lane >> 4;
    const int co_base = wid * 16;

    __shared__ __align__(16) u16 s_fB[24 * 25 * FB_STRIDE];   // 48000 B

    f32x4 acc[25];
    #pragma unroll
    for (int i = 0; i < 25; ++i) acc[i] = (f32x4){0.f, 0.f, 0.f, 0.f};

    for (int ph = 0; ph < 2; ++ph) {
        const int ci0 = ph * 32;
        __syncthreads();
        for (int u = tid; u < 2400; u += 256) {
            int q = u & 3, rv = u >> 2;
            int tp = rv / 25, v = rv - tp * 25;
            int tg = t0 + tp - 4;
            bf16x8 val = {0,0,0,0,0,0,0,0};
            if (tg >= 0 && tg < 512)
                val = *(const bf16x8*)&f[((n * 512 + tg) * 25 + v) * 64 + ci0 + q * 8];
            *(bf16x8*)&s_fB[rv * FB_STRIDE + q * 8] = val;
        }
        __syncthreads();

        bf16x8 aF[9];
        #pragma unroll
        for (int dt = 0; dt < 9; ++dt)
            aF[dt] = *(const bf16x8*)(&wtc[((co_base + r0) * 9 + dt) * 64 + ci0 + g * 8]);

        #pragma unroll
        for (int nt2 = 0; nt2 < 25; ++nt2) {
            int c0 = nt2 * 16 + r0;
            int tb = c0 / 25, v = c0 - tb * 25;
            #pragma unroll
            for (int dt = 0; dt < 9; ++dt) {
                bf16x8 bF = *(const bf16x8*)(&s_fB[((tb + dt) * 25 + v) * FB_STRIDE + g * 8]);
                acc[nt2] = MFMA(aF[dt], bF, acc[nt2]);
            }
        }
    }

    float s3v[4], pre[4];
    #pragma unroll
    for (int r = 0; r < 4; ++r) {
        int co = co_base + g * 4 + r;
        s3v[r] = bnc[256 + co];
        pre[r] = bnc[320 + co];
    }
    #pragma unroll
    for (int nt2 = 0; nt2 < 25; ++nt2) {
        int c0 = nt2 * 16 + r0;
        int tb = c0 / 25, v = c0 - tb * 25;
        #pragma unroll
        for (int r = 0; r < 4; ++r) {
            int co = co_base + g * 4 + r;
            int idx = ((n * 64 + co) * 512 + t0 + tb) * 25 + v;
            float y = acc[nt2][r] * s3v[r] + pre[r] + x[idx];
            out[idx] = fmaxf(y, 0.f);
        }
    }
}

extern "C" void kernel_launch(void* const* d_in, const int* in_sizes, int n_in,
                              void* d_out, int out_size, void* d_ws, size_t ws_size,
                              hipStream_t stream) {
    const float* x       = (const float*)d_in[0];
    const float* A       = (const float*)d_in[1];
    const float* bn1_g   = (const float*)d_in[2];
    const float* bn1_b   = (const float*)d_in[3];
    const float* bn1_m   = (const float*)d_in[4];
    const float* bn1_v   = (const float*)d_in[5];
    const float* pconv_w = (const float*)d_in[6];
    const float* pconv_b = (const float*)d_in[7];
    const float* wq      = (const float*)d_in[8];
    const float* wk      = (const float*)d_in[9];
    const float* wv      = (const float*)d_in[10];
    const float* fc_w    = (const float*)d_in[11];
    const float* ln_g    = (const float*)d_in[12];
    const float* ln_b    = (const float*)d_in[13];
    const float* gate_w  = (const float*)d_in[14];
    const float* bn2_g   = (const float*)d_in[15];
    const float* bn2_b   = (const float*)d_in[16];
    const float* bn2_m   = (const float*)d_in[17];
    const float* bn2_v   = (const float*)d_in[18];
    const float* tconv_w = (const float*)d_in[19];
    const float* tconv_b = (const float*)d_in[20];
    const float* bn3_g   = (const float*)d_in[21];
    const float* bn3_b   = (const float*)d_in[22];
    const float* bn3_m   = (const float*)d_in[23];
    const float* bn3_v   = (const float*)d_in[24];

    char* ws = (char*)d_ws;
    u16*   f_bf  = (u16*)ws;
    u16*   akt   = (u16*)(ws + WOFF);
    u16*   wp2   = (u16*)(ws + WOFF + 7680);
    u16*   wqt   = (u16*)(ws + WOFF + 32256);
    u16*   wkt   = (u16*)(ws + WOFF + 40448);
    u16*   wvt   = (u16*)(ws + WOFF + 48640);
    u16*   fct   = (u16*)(ws + WOFF + 56832);
    float* bagg  = (float*)(ws + WOFF + 65024);
    u16*   wtc   = (u16*)(ws + WOFF + 71424);
    float* uvec  = (float*)(ws + WOFF + 145152);
    float* w0vec = (float*)(ws + WOFF + 145408);
    float* bnc   = (float*)(ws + WOFF + 145664);   // 6*64 f32
    float* outp  = (float*)d_out;

    prep_kernel<<<dim3(64), dim3(256), 0, stream>>>(
        A, pconv_w, pconv_b, wq, wk, wv, fc_w, tconv_w, tconv_b, ln_g, ln_b,
        bn1_g, bn1_b, bn1_m, bn1_v, bn2_g, bn2_b, bn2_m, bn2_v,
        bn3_g, bn3_b, bn3_m, bn3_v,
        akt, wp2, wqt, wkt, wvt, fct, bagg, wtc, uvec, w0vec, bnc);
    scn_kernel<<<dim3(NB * T), dim3(256), 0, stream>>>(
        x, akt, wp2, wqt, wkt, wvt, fct, bagg, uvec, w0vec, gate_w, bnc, f_bf);
    tcn_mfma<<<dim3(NB * 32), dim3(256), 0, stream>>>(
        f_bf, x, wtc, bnc, outp);
}